// Round 1
// baseline (4746.158 us; speedup 1.0000x reference)
//
#include <hip/hip_runtime.h>
#include <hip/hip_bf16.h>

#define N_ 128
#define C_ 64
#define T_ 128
#define V_ 25
#define S_ 3
#define IG 16
#define IH 8
#define H_ 8
#define D_ 200   // IH*V
#define CV 1600  // C_*V_
#define TV 3200  // T_*V_
#define EPSB 1e-5f

__device__ __forceinline__ float sigm(float x){ return 1.f/(1.f+expf(-x)); }
__device__ __forceinline__ float b2f(__hip_bfloat16 b){ return __bfloat162float(b); }
__device__ __forceinline__ __hip_bfloat16 f2b(float f){ return __float2bfloat16(f); }

// ---------------- K1: adaptive graph attention Aad[n,s,v,w] ----------------
__global__ __launch_bounds__(256) void k_gcn_att(
    const float* __restrict__ x, const float* __restrict__ A,
    const float* __restrict__ alphap,
    const float* __restrict__ Wq, const float* __restrict__ bq,
    const float* __restrict__ Wk, const float* __restrict__ bk,
    float* __restrict__ Aad)
{
  const int ns = blockIdx.x, n = ns / S_, s = ns % S_;
  const int tid = threadIdx.x;
  __shared__ float xt[CV];
  __shared__ float wq_l[IG*C_], wk_l[IG*C_];
  __shared__ float qv[IG*V_], kv[IG*V_];
  __shared__ float att[V_*V_];
  for (int i=tid;i<IG*C_;i+=256){ wq_l[i]=Wq[s*IG*C_+i]; wk_l[i]=Wk[s*IG*C_+i]; }
  for (int i=tid;i<V_*V_;i+=256) att[i]=0.f;
  __syncthreads();
  const float* xn = x + (size_t)n*C_*T_*V_;
  for (int t=0;t<T_;++t){
    for (int i=tid;i<CV;i+=256) xt[i]=xn[(size_t)(i/V_)*T_*V_ + t*V_ + (i%V_)];
    __syncthreads();
    for (int i=tid;i<2*IG*V_;i+=256){
      int half=i/(IG*V_), r=i%(IG*V_), ii=r/V_, v=r%V_;
      const float* w = half?wk_l:wq_l;
      float acc = half? bk[s*IG+ii] : bq[s*IG+ii];
      #pragma unroll 8
      for (int c=0;c<C_;++c) acc += w[ii*C_+c]*xt[c*V_+v];
      (half?kv:qv)[r]=acc;
    }
    __syncthreads();
    for (int i=tid;i<V_*V_;i+=256){
      int v=i/V_, w=i%V_;
      float acc=0.f;
      #pragma unroll
      for (int ii=0;ii<IG;++ii) acc += qv[ii*V_+v]*kv[ii*V_+w];
      att[i]+=acc;
    }
    __syncthreads();
  }
  // softmax over v (axis -2) per column w, then Aad = A + alpha*att
  if (tid<V_){
    const int w=tid; const float inv=1.f/(IG*T_);
    float mx=-1e30f;
    for (int v=0;v<V_;++v) mx=fmaxf(mx, att[v*V_+w]*inv);
    float sum=0.f;
    for (int v=0;v<V_;++v){ float e=expf(att[v*V_+w]*inv-mx); att[v*V_+w]=e; sum+=e; }
    float rs=1.f/sum;
    for (int v=0;v<V_;++v) att[v*V_+w]*=rs;
  }
  __syncthreads();
  const float alpha=alphap[0];
  float* Ao = Aad + (size_t)ns*V_*V_;
  for (int i=tid;i<V_*V_;i+=256) Ao[i]=A[s*V_*V_+i]+alpha*att[i];
}

// ---------------- K2: graph conv + Wf + bn + residual + relu -> y1 (bf16) ----------------
__global__ __launch_bounds__(256) void k_gcn_y(
    const float* __restrict__ x, const float* __restrict__ Aad,
    const float* __restrict__ Wf, const float* __restrict__ bfp,
    const float* __restrict__ g_gamma, const float* __restrict__ g_beta,
    __hip_bfloat16* __restrict__ y1)
{
  const int t=blockIdx.x, n=blockIdx.y, tid=threadIdx.x;
  __shared__ float xt[CV], tmp[CV], yacc[CV];
  __shared__ float Al[S_*V_*V_];
  const float* xn = x + (size_t)n*C_*T_*V_;
  for (int i=tid;i<CV;i+=256){ xt[i]=xn[(size_t)(i/V_)*T_*V_+t*V_+(i%V_)]; yacc[i]=0.f; }
  for (int i=tid;i<S_*V_*V_;i+=256) Al[i]=Aad[(size_t)n*S_*V_*V_+i];
  __syncthreads();
  for (int s=0;s<S_;++s){
    const float* As = Al + s*V_*V_;
    for (int i=tid;i<CV;i+=256){
      int c=i/V_, w=i%V_;
      float acc=0.f;
      #pragma unroll
      for (int v=0;v<V_;++v) acc += xt[c*V_+v]*As[v*V_+w];
      tmp[i]=acc;
    }
    __syncthreads();
    for (int i=tid;i<CV;i+=256){
      int o=i/V_, w=i%V_;
      const float* wr = Wf + (size_t)(s*C_+o)*C_;
      float acc=0.f;
      #pragma unroll 8
      for (int c=0;c<C_;++c) acc += wr[c]*tmp[c*V_+w];
      yacc[i]+=acc;
    }
    __syncthreads();
  }
  const float invs = rsqrtf(1.f+EPSB);
  __hip_bfloat16* yo = y1 + (size_t)n*C_*T_*V_;
  for (int i=tid;i<CV;i+=256){
    int o=i/V_, w=i%V_;
    float b = bfp[o]+bfp[C_+o]+bfp[2*C_+o];
    float val = (yacc[i]+b)*(g_gamma[o]*invs)+g_beta[o]+xn[(size_t)o*T_*V_+t*V_+w];
    yo[(size_t)o*T_*V_+t*V_+w]=f2b(fmaxf(val,0.f));
  }
}

// ---------------- K3a: seT[n,c,v] = mean_t y1 ----------------
__global__ __launch_bounds__(256) void k_seT(const __hip_bfloat16* __restrict__ y1,
    float* __restrict__ seT)
{
  const int c=blockIdx.x, n=blockIdx.y, tid=threadIdx.x;
  __shared__ float sv[V_];
  if (tid<V_) sv[tid]=0.f;
  __syncthreads();
  const __hip_bfloat16* yp = y1 + ((size_t)n*C_+c)*T_*V_;
  for (int i=tid;i<TV;i+=256) atomicAdd(&sv[i%V_], b2f(yp[i]));
  __syncthreads();
  if (tid<V_) seT[((size_t)n*C_+c)*V_+tid]=sv[tid]*(1.f/T_);
}

// ---------------- K3b: sa[n,v] spatial gate ----------------
__global__ __launch_bounds__(64) void k_sa(const float* __restrict__ seT,
    const float* __restrict__ W_sa, const float* __restrict__ b_sa,
    float* __restrict__ sa)
{
  const int n=blockIdx.x, tid=threadIdx.x;
  if (tid>=V_) return;
  const float* se = seT + (size_t)n*C_*V_;
  float acc=b_sa[0];
  for (int c=0;c<C_;++c){
    #pragma unroll
    for (int k=0;k<V_;++k){
      int vv=tid+k-12;  // pad = (V-1)/2 = 12
      if (vv>=0&&vv<V_) acc+=se[c*V_+vv]*W_sa[c*V_+k];
    }
  }
  sa[n*V_+tid]=sigm(acc);
}

// ---------------- K3c: seV[n,c,t] = mean_v y1*(1+sa) ----------------
__global__ __launch_bounds__(256) void k_seV(const __hip_bfloat16* __restrict__ y1,
    const float* __restrict__ sa, float* __restrict__ seV)
{
  const int c=blockIdx.x, n=blockIdx.y, tid=threadIdx.x;
  __shared__ float st[T_];
  __shared__ float sal[V_];
  if (tid<T_) st[tid]=0.f;
  if (tid<V_) sal[tid]=1.f+sa[n*V_+tid];
  __syncthreads();
  const __hip_bfloat16* yp = y1 + ((size_t)n*C_+c)*T_*V_;
  for (int i=tid;i<TV;i+=256) atomicAdd(&st[i/V_], b2f(yp[i])*sal[i%V_]);
  __syncthreads();
  if (tid<T_) seV[((size_t)n*C_+c)*T_+tid]=st[tid]*(1.f/V_);
}

// ---------------- K3d: ta[n,t] temporal gate + ca[n,c] channel gate ----------------
__global__ __launch_bounds__(128) void k_ta_ca(const float* __restrict__ seV,
    const float* __restrict__ W_ta, const float* __restrict__ b_ta,
    const float* __restrict__ W_fc1, const float* __restrict__ b_fc1,
    const float* __restrict__ W_fc2, const float* __restrict__ b_fc2,
    float* __restrict__ ta, float* __restrict__ ca)
{
  const int n=blockIdx.x, tid=threadIdx.x;
  __shared__ float tal[T_];
  __shared__ float scl[C_];
  __shared__ float h1[32];
  const float* sv = seV + (size_t)n*C_*T_;
  {
    float acc=b_ta[0];
    for (int c=0;c<C_;++c){
      #pragma unroll
      for (int k=0;k<9;++k){
        int tt=tid+k-4;
        if (tt>=0&&tt<T_) acc+=sv[c*T_+tt]*W_ta[c*9+k];
      }
    }
    float s=sigm(acc);
    tal[tid]=s; ta[n*T_+tid]=s;
  }
  __syncthreads();
  if (tid<C_){
    float acc=0.f;
    for (int t=0;t<T_;++t) acc += sv[tid*T_+t]*(1.f+tal[t]);
    scl[tid]=acc*(1.f/T_);
  }
  __syncthreads();
  if (tid<32){
    float acc=b_fc1[tid];
    for (int c=0;c<C_;++c) acc += scl[c]*W_fc1[tid*C_+c];
    h1[tid]=fmaxf(acc,0.f);
  }
  __syncthreads();
  if (tid<C_){
    float acc=b_fc2[tid];
    for (int j=0;j<32;++j) acc += h1[j]*W_fc2[tid*32+j];
    ca[n*C_+tid]=sigm(acc);
  }
}

// ---------------- K4: xa = y1*gates + pe (bf16), plus q/k/v projections (bf16) ----------------
__global__ __launch_bounds__(256) void k_xa_qkv(
    const __hip_bfloat16* __restrict__ y1, const float* __restrict__ pos_emb,
    const float* __restrict__ sa, const float* __restrict__ ta, const float* __restrict__ ca,
    const float* __restrict__ Wq_h, const float* __restrict__ bq_h,
    const float* __restrict__ Wk_h, const float* __restrict__ bk_h,
    const float* __restrict__ Wv_h, const float* __restrict__ bv_h,
    __hip_bfloat16* __restrict__ xa, __hip_bfloat16* __restrict__ qb,
    __hip_bfloat16* __restrict__ kb, __hip_bfloat16* __restrict__ vb)
{
  const int t=blockIdx.x, n=blockIdx.y, tid=threadIdx.x;
  __shared__ float xal[CV];
  const float tg = 1.f + ta[n*T_+t];
  const __hip_bfloat16* y1n = y1 + (size_t)n*C_*T_*V_;
  __hip_bfloat16* xan = xa + (size_t)n*C_*T_*V_;
  for (int i=tid;i<CV;i+=256){
    int c=i/V_, v=i%V_;
    float val = b2f(y1n[(size_t)c*T_*V_+t*V_+v]) * (1.f+sa[n*V_+v]) * tg * (1.f+ca[n*C_+c])
              + pos_emb[(size_t)t*CV + i];
    xal[i]=val;
    xan[(size_t)c*T_*V_+t*V_+v]=f2b(val);
  }
  __syncthreads();
  for (int i=tid;i<3*CV;i+=256){
    int which=i/CV, r=i%CV, ho=r/V_, v=r%V_;   // ho = h*IH + o
    const float* W = which==0?Wq_h:(which==1?Wk_h:Wv_h);
    const float* B = which==0?bq_h:(which==1?bk_h:bv_h);
    float acc = B[ho];
    const float* wrow = W + (size_t)ho*C_;
    #pragma unroll 8
    for (int c=0;c<C_;++c) acc += wrow[c]*xal[c*V_+v];
    int h=ho/IH, o=ho%IH;
    size_t idx = (((size_t)n*H_+h)*T_+t)*D_ + o*V_ + v;
    __hip_bfloat16 bv16=f2b(acc);
    if (which==0) qb[idx]=bv16; else if (which==1) kb[idx]=bv16; else vb[idx]=bv16;
  }
}

// ---------------- K5: causal MHA, one block per (n,h); oh (bf16, reuses y1 region) ----------------
__global__ __launch_bounds__(256) void k_attn(
    const __hip_bfloat16* __restrict__ qb, const __hip_bfloat16* __restrict__ kb,
    const __hip_bfloat16* __restrict__ vb, __hip_bfloat16* __restrict__ oh)
{
  const int nh = blockIdx.x, tid = threadIdx.x;
  __shared__ __hip_bfloat16 kl[T_*202];   // row stride 202 bf16 = 404B -> conflict-free
  __shared__ float ql[D_];
  __shared__ float p[T_];
  __shared__ float red[4];
  const __hip_bfloat16* kg = kb + (size_t)nh*T_*D_;
  const __hip_bfloat16* qg = qb + (size_t)nh*T_*D_;
  const __hip_bfloat16* vg = vb + (size_t)nh*T_*D_;
  __hip_bfloat16* og = oh + (size_t)nh*T_*D_;
  for (int i=tid;i<T_*D_;i+=256){ int tt=i/D_, d=i%D_; kl[tt*202+d]=kg[i]; }
  __syncthreads();
  const float scale = 0.0707106781f;  // 1/sqrt(200)
  for (int t=0;t<T_;++t){
    if (tid<D_) ql[tid]=b2f(qg[(size_t)t*D_+tid]);
    __syncthreads();
    float sc=-1e30f;
    if (tid<=t && tid<T_){
      const unsigned int* kr=(const unsigned int*)(kl + tid*202);
      float acc=0.f;
      #pragma unroll 4
      for (int dd=0;dd<D_/2;++dd){
        unsigned int u=kr[dd];
        float k0=__uint_as_float(u<<16);
        float k1=__uint_as_float(u&0xffff0000u);
        acc += ql[2*dd]*k0 + ql[2*dd+1]*k1;
      }
      sc=acc*scale;
    }
    // wave-level max reduce (2 active waves)
    float m=(tid<T_)?sc:-1e30f;
    #pragma unroll
    for (int off=32;off;off>>=1) m=fmaxf(m,__shfl_down(m,off));
    if ((tid&63)==0 && tid<T_) red[tid>>6]=m;
    __syncthreads();
    const float mx=fmaxf(red[0],red[1]);
    float e=0.f;
    if (tid<=t && tid<T_) e=expf(sc-mx);
    if (tid<T_) p[tid]=e;
    float ssum=e;
    #pragma unroll
    for (int off=32;off;off>>=1) ssum+=__shfl_down(ssum,off);
    if ((tid&63)==0 && tid<T_) red[2+(tid>>6)]=ssum;
    __syncthreads();
    const float rdenom=1.f/(red[2]+red[3]);
    if (tid<D_){
      float acc=0.f;
      int j=0;
      for (; j+1<=t; j+=2){
        acc += p[j]*b2f(vg[(size_t)j*D_+tid]);
        acc += p[j+1]*b2f(vg[(size_t)(j+1)*D_+tid]);
      }
      if (j<=t) acc += p[j]*b2f(vg[(size_t)j*D_+tid]);
      og[(size_t)t*D_+tid]=f2b(acc*rdenom);
    }
    __syncthreads();
  }
}

// ---------------- K7: z=bn(oh)+xa; ffn; z2=relu+xa; z3=bn; out=relu(z3+x) ----------------
__global__ __launch_bounds__(256) void k_out(
    const __hip_bfloat16* __restrict__ oh, const __hip_bfloat16* __restrict__ xa,
    const float* __restrict__ x, const float* __restrict__ W_ffn,
    const float* __restrict__ b_ffn, const float* __restrict__ m_gamma,
    const float* __restrict__ m_beta, float* __restrict__ out)
{
  const int t=blockIdx.x, n=blockIdx.y, tid=threadIdx.x;
  __shared__ float zl[CV], xal[CV];
  const float invs=rsqrtf(1.f+EPSB);
  const __hip_bfloat16* xan = xa + (size_t)n*C_*T_*V_;
  for (int i=tid;i<CV;i+=256){
    int c=i/V_, v=i%V_;
    float xav=b2f(xan[(size_t)c*T_*V_+t*V_+v]);
    xal[i]=xav;
    int h=c/IH, o=c%IH;
    float ov=b2f(oh[(((size_t)n*H_+h)*T_+t)*D_ + o*V_ + v]);
    zl[i]=m_gamma[c]*invs*ov + m_beta[c] + xav;
  }
  __syncthreads();
  const float* xn = x + (size_t)n*C_*T_*V_;
  float* outn = out + (size_t)n*C_*T_*V_;
  for (int i=tid;i<CV;i+=256){
    int o=i/V_, v=i%V_;
    float acc=b_ffn[o];
    const float* wr = W_ffn + (size_t)o*C_;
    #pragma unroll 8
    for (int c=0;c<C_;++c) acc += wr[c]*zl[c*V_+v];
    float z2=fmaxf(acc,0.f)+xal[i];
    float z3=m_gamma[o]*invs*z2 + m_beta[o];
    outn[(size_t)o*T_*V_+t*V_+v]=fmaxf(z3 + xn[(size_t)o*T_*V_+t*V_+v], 0.f);
  }
}

extern "C" void kernel_launch(void* const* d_in, const int* in_sizes, int n_in,
                              void* d_out, int out_size, void* d_ws, size_t ws_size,
                              hipStream_t stream) {
  const float* x      = (const float*)d_in[0];
  const float* A      = (const float*)d_in[1];
  const float* alphap = (const float*)d_in[2];
  const float* Wq     = (const float*)d_in[3];
  const float* bq     = (const float*)d_in[4];
  const float* Wk     = (const float*)d_in[5];
  const float* bk     = (const float*)d_in[6];
  const float* Wf     = (const float*)d_in[7];
  const float* bfp    = (const float*)d_in[8];
  const float* g_gamma= (const float*)d_in[9];
  const float* g_beta = (const float*)d_in[10];
  const float* W_sa   = (const float*)d_in[11];
  const float* b_sa   = (const float*)d_in[12];
  const float* W_ta   = (const float*)d_in[13];
  const float* b_ta   = (const float*)d_in[14];
  const float* W_fc1  = (const float*)d_in[15];
  const float* b_fc1  = (const float*)d_in[16];
  const float* W_fc2  = (const float*)d_in[17];
  const float* b_fc2  = (const float*)d_in[18];
  const float* pos_emb= (const float*)d_in[19];
  const float* Wq_h   = (const float*)d_in[20];
  const float* bq_h   = (const float*)d_in[21];
  const float* Wk_h   = (const float*)d_in[22];
  const float* bk_h   = (const float*)d_in[23];
  const float* Wv_h   = (const float*)d_in[24];
  const float* bv_h   = (const float*)d_in[25];
  const float* W_ffn  = (const float*)d_in[26];
  const float* b_ffn  = (const float*)d_in[27];
  const float* m_gamma= (const float*)d_in[28];
  const float* m_beta = (const float*)d_in[29];
  float* out = (float*)d_out;

  // workspace layout (f32 region then bf16 region) — ~268 MB total
  float* ws   = (float*)d_ws;
  float* Aad  = ws;                    // 128*3*625   = 240000
  float* seT  = Aad + 240000;          // 128*64*25   = 204800
  float* seV  = seT + 204800;          // 128*64*128  = 1048576
  float* sa   = seV + 1048576;         // 128*25      = 3200
  float* ta   = sa  + 3200;            // 128*128     = 16384
  float* ca   = ta  + 16384;           // 128*64      = 8192
  __hip_bfloat16* y1 = (__hip_bfloat16*)(ca + 8192);  // 26214400 elems (reused as oh)
  __hip_bfloat16* xa = y1 + (size_t)26214400;
  __hip_bfloat16* qb = xa + (size_t)26214400;
  __hip_bfloat16* kb = qb + (size_t)26214400;
  __hip_bfloat16* vb = kb + (size_t)26214400;
  __hip_bfloat16* oh = y1;  // reuse: y1 dead after k_xa_qkv

  k_gcn_att<<<N_*S_, 256, 0, stream>>>(x, A, alphap, Wq, bq, Wk, bk, Aad);
  k_gcn_y<<<dim3(T_, N_), 256, 0, stream>>>(x, Aad, Wf, bfp, g_gamma, g_beta, y1);
  k_seT<<<dim3(C_, N_), 256, 0, stream>>>(y1, seT);
  k_sa<<<N_, 64, 0, stream>>>(seT, W_sa, b_sa, sa);
  k_seV<<<dim3(C_, N_), 256, 0, stream>>>(y1, sa, seV);
  k_ta_ca<<<N_, 128, 0, stream>>>(seV, W_ta, b_ta, W_fc1, b_fc1, W_fc2, b_fc2, ta, ca);
  k_xa_qkv<<<dim3(T_, N_), 256, 0, stream>>>(y1, pos_emb, sa, ta, ca,
      Wq_h, bq_h, Wk_h, bk_h, Wv_h, bv_h, xa, qb, kb, vb);
  k_attn<<<N_*H_, 256, 0, stream>>>(qb, kb, vb, oh);
  k_out<<<dim3(T_, N_), 256, 0, stream>>>(oh, xa, x, W_ffn, b_ffn, m_gamma, m_beta, out);
}

// Round 2
// 3771.026 us; speedup vs baseline: 1.2586x; 1.2586x over previous
//
#include <hip/hip_runtime.h>
#include <hip/hip_bf16.h>

#define N_ 128
#define C_ 64
#define T_ 128
#define V_ 25
#define S_ 3
#define IG 16
#define IH 8
#define H_ 8
#define D_ 200   // IH*V
#define CV 1600  // C_*V_
#define TV 3200  // T_*V_
#define EPSB 1e-5f

__device__ __forceinline__ float sigm(float x){ return 1.f/(1.f+expf(-x)); }
__device__ __forceinline__ float b2f(__hip_bfloat16 b){ return __bfloat162float(b); }
__device__ __forceinline__ __hip_bfloat16 f2b(float f){ return __float2bfloat16(f); }

// ---------------- K1a: adaptive graph attention partials, chunked over t ----------------
// grid (8, N_*S_): blockIdx.x = t-chunk (16 t's), blockIdx.y = n*S+s
__global__ __launch_bounds__(256) void k_gcn_att1(
    const float* __restrict__ x,
    const float* __restrict__ Wq, const float* __restrict__ bq,
    const float* __restrict__ Wk, const float* __restrict__ bk,
    float* __restrict__ attg)
{
  const int tc = blockIdx.x, ns = blockIdx.y, n = ns / S_, s = ns % S_;
  const int tid = threadIdx.x;
  __shared__ float xt[CV];
  __shared__ float wq_l[IG*C_], wk_l[IG*C_];
  __shared__ float qv[IG*V_], kv[IG*V_];
  __shared__ float att[V_*V_];
  for (int i=tid;i<IG*C_;i+=256){ wq_l[i]=Wq[s*IG*C_+i]; wk_l[i]=Wk[s*IG*C_+i]; }
  for (int i=tid;i<V_*V_;i+=256) att[i]=0.f;
  __syncthreads();
  const float* xn = x + (size_t)n*C_*T_*V_;
  const int t0 = tc*16;
  for (int t=t0;t<t0+16;++t){
    for (int i=tid;i<CV;i+=256) xt[i]=xn[(size_t)(i/V_)*T_*V_ + t*V_ + (i%V_)];
    __syncthreads();
    for (int i=tid;i<2*IG*V_;i+=256){
      int half=i/(IG*V_), r=i%(IG*V_), ii=r/V_, v=r%V_;
      const float* w = half?wk_l:wq_l;
      float acc = half? bk[s*IG+ii] : bq[s*IG+ii];
      #pragma unroll 8
      for (int c=0;c<C_;++c) acc += w[ii*C_+c]*xt[c*V_+v];
      (half?kv:qv)[r]=acc;
    }
    __syncthreads();
    for (int i=tid;i<V_*V_;i+=256){
      int v=i/V_, w=i%V_;
      float acc=0.f;
      #pragma unroll
      for (int ii=0;ii<IG;++ii) acc += qv[ii*V_+v]*kv[ii*V_+w];
      att[i]+=acc;
    }
    __syncthreads();
  }
  float* Ao = attg + ((size_t)tc*(N_*S_) + ns)*(V_*V_);
  for (int i=tid;i<V_*V_;i+=256) Ao[i]=att[i];
}

// ---------------- K1b: reduce chunks + softmax(dim=-2) + Aad ----------------
__global__ __launch_bounds__(256) void k_gcn_att2(
    const float* __restrict__ attg, const float* __restrict__ A,
    const float* __restrict__ alphap, float* __restrict__ Aad)
{
  const int ns = blockIdx.x, s = ns % S_, tid = threadIdx.x;
  __shared__ float att[V_*V_];
  for (int i=tid;i<V_*V_;i+=256){
    float acc=0.f;
    #pragma unroll
    for (int tc=0;tc<8;++tc) acc += attg[((size_t)tc*(N_*S_) + ns)*(V_*V_) + i];
    att[i]=acc;
  }
  __syncthreads();
  if (tid<V_){
    const int w=tid; const float inv=1.f/(IG*T_);
    float mx=-1e30f;
    for (int v=0;v<V_;++v) mx=fmaxf(mx, att[v*V_+w]*inv);
    float sum=0.f;
    for (int v=0;v<V_;++v){ float e=expf(att[v*V_+w]*inv-mx); att[v*V_+w]=e; sum+=e; }
    float rs=1.f/sum;
    for (int v=0;v<V_;++v) att[v*V_+w]*=rs;
  }
  __syncthreads();
  const float alpha=alphap[0];
  float* Ao = Aad + (size_t)ns*V_*V_;
  for (int i=tid;i<V_*V_;i+=256) Ao[i]=A[s*V_*V_+i]+alpha*att[i];
}

// ---------------- K2: graph conv + Wf + bn + residual + relu -> y1 (bf16) ----------------
__global__ __launch_bounds__(256) void k_gcn_y(
    const float* __restrict__ x, const float* __restrict__ Aad,
    const float* __restrict__ Wf, const float* __restrict__ bfp,
    const float* __restrict__ g_gamma, const float* __restrict__ g_beta,
    __hip_bfloat16* __restrict__ y1)
{
  const int t=blockIdx.x, n=blockIdx.y, tid=threadIdx.x;
  __shared__ float xt[CV], tmp[CV], yacc[CV];
  __shared__ float Al[S_*V_*V_];
  const float* xn = x + (size_t)n*C_*T_*V_;
  for (int i=tid;i<CV;i+=256){ xt[i]=xn[(size_t)(i/V_)*T_*V_+t*V_+(i%V_)]; yacc[i]=0.f; }
  for (int i=tid;i<S_*V_*V_;i+=256) Al[i]=Aad[(size_t)n*S_*V_*V_+i];
  __syncthreads();
  for (int s=0;s<S_;++s){
    const float* As = Al + s*V_*V_;
    for (int i=tid;i<CV;i+=256){
      int c=i/V_, w=i%V_;
      float acc=0.f;
      #pragma unroll
      for (int v=0;v<V_;++v) acc += xt[c*V_+v]*As[v*V_+w];
      tmp[i]=acc;
    }
    __syncthreads();
    for (int i=tid;i<CV;i+=256){
      int o=i/V_, w=i%V_;
      const float* wr = Wf + (size_t)(s*C_+o)*C_;
      float acc=0.f;
      #pragma unroll 8
      for (int c=0;c<C_;++c) acc += wr[c]*tmp[c*V_+w];
      yacc[i]+=acc;
    }
    __syncthreads();
  }
  const float invs = rsqrtf(1.f+EPSB);
  __hip_bfloat16* yo = y1 + (size_t)n*C_*T_*V_;
  for (int i=tid;i<CV;i+=256){
    int o=i/V_, w=i%V_;
    float b = bfp[o]+bfp[C_+o]+bfp[2*C_+o];
    float val = (yacc[i]+b)*(g_gamma[o]*invs)+g_beta[o]+xn[(size_t)o*T_*V_+t*V_+w];
    yo[(size_t)o*T_*V_+t*V_+w]=f2b(fmaxf(val,0.f));
  }
}

// ---------------- K3a: seT[n,c,v] = mean_t y1 ----------------
__global__ __launch_bounds__(256) void k_seT(const __hip_bfloat16* __restrict__ y1,
    float* __restrict__ seT)
{
  const int c=blockIdx.x, n=blockIdx.y, tid=threadIdx.x;
  __shared__ float sv[V_];
  if (tid<V_) sv[tid]=0.f;
  __syncthreads();
  const __hip_bfloat16* yp = y1 + ((size_t)n*C_+c)*T_*V_;
  for (int i=tid;i<TV;i+=256) atomicAdd(&sv[i%V_], b2f(yp[i]));
  __syncthreads();
  if (tid<V_) seT[((size_t)n*C_+c)*V_+tid]=sv[tid]*(1.f/T_);
}

// ---------------- K3b: sa[n,v] spatial gate ----------------
__global__ __launch_bounds__(64) void k_sa(const float* __restrict__ seT,
    const float* __restrict__ W_sa, const float* __restrict__ b_sa,
    float* __restrict__ sa)
{
  const int n=blockIdx.x, tid=threadIdx.x;
  if (tid>=V_) return;
  const float* se = seT + (size_t)n*C_*V_;
  float acc=b_sa[0];
  for (int c=0;c<C_;++c){
    #pragma unroll
    for (int k=0;k<V_;++k){
      int vv=tid+k-12;  // pad = (V-1)/2 = 12
      if (vv>=0&&vv<V_) acc+=se[c*V_+vv]*W_sa[c*V_+k];
    }
  }
  sa[n*V_+tid]=sigm(acc);
}

// ---------------- K3c: seV[n,c,t] = mean_v y1*(1+sa) ----------------
__global__ __launch_bounds__(256) void k_seV(const __hip_bfloat16* __restrict__ y1,
    const float* __restrict__ sa, float* __restrict__ seV)
{
  const int c=blockIdx.x, n=blockIdx.y, tid=threadIdx.x;
  __shared__ float st[T_];
  __shared__ float sal[V_];
  if (tid<T_) st[tid]=0.f;
  if (tid<V_) sal[tid]=1.f+sa[n*V_+tid];
  __syncthreads();
  const __hip_bfloat16* yp = y1 + ((size_t)n*C_+c)*T_*V_;
  for (int i=tid;i<TV;i+=256) atomicAdd(&st[i/V_], b2f(yp[i])*sal[i%V_]);
  __syncthreads();
  if (tid<T_) seV[((size_t)n*C_+c)*T_+tid]=st[tid]*(1.f/V_);
}

// ---------------- K3d: ta[n,t] temporal gate + ca[n,c] channel gate ----------------
__global__ __launch_bounds__(128) void k_ta_ca(const float* __restrict__ seV,
    const float* __restrict__ W_ta, const float* __restrict__ b_ta,
    const float* __restrict__ W_fc1, const float* __restrict__ b_fc1,
    const float* __restrict__ W_fc2, const float* __restrict__ b_fc2,
    float* __restrict__ ta, float* __restrict__ ca)
{
  const int n=blockIdx.x, tid=threadIdx.x;
  __shared__ float tal[T_];
  __shared__ float scl[C_];
  __shared__ float h1[32];
  const float* sv = seV + (size_t)n*C_*T_;
  {
    float acc=b_ta[0];
    for (int c=0;c<C_;++c){
      #pragma unroll
      for (int k=0;k<9;++k){
        int tt=tid+k-4;
        if (tt>=0&&tt<T_) acc+=sv[c*T_+tt]*W_ta[c*9+k];
      }
    }
    float s=sigm(acc);
    tal[tid]=s; ta[n*T_+tid]=s;
  }
  __syncthreads();
  if (tid<C_){
    float acc=0.f;
    for (int t=0;t<T_;++t) acc += sv[tid*T_+t]*(1.f+tal[t]);
    scl[tid]=acc*(1.f/T_);
  }
  __syncthreads();
  if (tid<32){
    float acc=b_fc1[tid];
    for (int c=0;c<C_;++c) acc += scl[c]*W_fc1[tid*C_+c];
    h1[tid]=fmaxf(acc,0.f);
  }
  __syncthreads();
  if (tid<C_){
    float acc=b_fc2[tid];
    for (int j=0;j<32;++j) acc += h1[j]*W_fc2[tid*32+j];
    ca[n*C_+tid]=sigm(acc);
  }
}

// ---------------- K4: xa = y1*gates + pe (bf16), plus q/k/v projections (bf16) ----------------
__global__ __launch_bounds__(256) void k_xa_qkv(
    const __hip_bfloat16* __restrict__ y1, const float* __restrict__ pos_emb,
    const float* __restrict__ sa, const float* __restrict__ ta, const float* __restrict__ ca,
    const float* __restrict__ Wq_h, const float* __restrict__ bq_h,
    const float* __restrict__ Wk_h, const float* __restrict__ bk_h,
    const float* __restrict__ Wv_h, const float* __restrict__ bv_h,
    __hip_bfloat16* __restrict__ xa, __hip_bfloat16* __restrict__ qb,
    __hip_bfloat16* __restrict__ kb, __hip_bfloat16* __restrict__ vb)
{
  const int t=blockIdx.x, n=blockIdx.y, tid=threadIdx.x;
  __shared__ float xal[CV];
  const float tg = 1.f + ta[n*T_+t];
  const __hip_bfloat16* y1n = y1 + (size_t)n*C_*T_*V_;
  __hip_bfloat16* xan = xa + (size_t)n*C_*T_*V_;
  for (int i=tid;i<CV;i+=256){
    int c=i/V_, v=i%V_;
    float val = b2f(y1n[(size_t)c*T_*V_+t*V_+v]) * (1.f+sa[n*V_+v]) * tg * (1.f+ca[n*C_+c])
              + pos_emb[(size_t)t*CV + i];
    xal[i]=val;
    xan[(size_t)c*T_*V_+t*V_+v]=f2b(val);
  }
  __syncthreads();
  for (int i=tid;i<3*CV;i+=256){
    int which=i/CV, r=i%CV, ho=r/V_, v=r%V_;   // ho = h*IH + o
    const float* W = which==0?Wq_h:(which==1?Wk_h:Wv_h);
    const float* B = which==0?bq_h:(which==1?bk_h:bv_h);
    float acc = B[ho];
    const float* wrow = W + (size_t)ho*C_;
    #pragma unroll 8
    for (int c=0;c<C_;++c) acc += wrow[c]*xal[c*V_+v];
    int h=ho/IH, o=ho%IH;
    size_t idx = (((size_t)n*H_+h)*T_+t)*D_ + o*V_ + v;
    __hip_bfloat16 bv16=f2b(acc);
    if (which==0) qb[idx]=bv16; else if (which==1) kb[idx]=bv16; else vb[idx]=bv16;
  }
}

// ---------------- K5: flash-style causal MHA ----------------
// grid (2, H_, N_): blockIdx.x = q-row half (64 rows), 256 thr = 4 waves.
// 4-lane group per q row: lane = (row%16)*4 + dq, dq = d-quarter (50 dims).
// K/V tiles (32 x 200) staged f32 in LDS; online softmax in registers.
#define TKC 32
__global__ __launch_bounds__(256) void k_attn(
    const __hip_bfloat16* __restrict__ qb, const __hip_bfloat16* __restrict__ kb,
    const __hip_bfloat16* __restrict__ vb, __hip_bfloat16* __restrict__ oh)
{
  const int bx = blockIdx.x;
  const int nh = blockIdx.z*H_ + blockIdx.y;
  const int tid = threadIdx.x;
  const int wv = tid>>6, ln = tid&63;
  const int rloc = wv*16 + (ln>>2);
  const int rg = bx*64 + rloc;
  const int dq = ln&3;
  __shared__ float kl[TKC*200];
  __shared__ float vl[TKC*200];
  const __hip_bfloat16* qg = qb + (size_t)nh*T_*D_;
  const __hip_bfloat16* kg = kb + (size_t)nh*T_*D_;
  const __hip_bfloat16* vg = vb + (size_t)nh*T_*D_;
  const float scale = 0.0707106781f;  // 1/sqrt(200)
  float q0[50], acc[50];
  {
    const unsigned int* qrow = (const unsigned int*)(qg + (size_t)rg*D_ + dq*50);
    #pragma unroll
    for (int i=0;i<25;++i){
      unsigned int u = qrow[i];
      q0[2*i]   = __uint_as_float(u<<16)*scale;
      q0[2*i+1] = __uint_as_float(u & 0xffff0000u)*scale;
      acc[2*i]=0.f; acc[2*i+1]=0.f;
    }
  }
  float m = -1e30f, l = 0.f;
  const int ntiles = (bx==0)? 2 : 4;
  for (int kt=0; kt<ntiles; ++kt){
    const int j0 = kt*TKC;
    __syncthreads();
    // stage K,V tile as f32 (2 bf16 per uint)
    for (int i=tid;i<TKC*100;i+=256){
      int row=i/100, c2=i%100;
      unsigned int uk = *(const unsigned int*)(kg + (size_t)(j0+row)*D_ + c2*2);
      unsigned int uv = *(const unsigned int*)(vg + (size_t)(j0+row)*D_ + c2*2);
      kl[row*200+c2*2]   = __uint_as_float(uk<<16);
      kl[row*200+c2*2+1] = __uint_as_float(uk & 0xffff0000u);
      vl[row*200+c2*2]   = __uint_as_float(uv<<16);
      vl[row*200+c2*2+1] = __uint_as_float(uv & 0xffff0000u);
    }
    __syncthreads();
    #pragma unroll
    for (int sub=0; sub<2; ++sub){
      const int j0s = sub*16;
      float s[16];
      #pragma unroll
      for (int jj=0;jj<16;++jj){
        const float2* kr = (const float2*)(kl + (j0s+jj)*200 + dq*50);
        float a0=0.f, a1=0.f;
        #pragma unroll
        for (int i=0;i<25;++i){ float2 kk=kr[i]; a0 += q0[2*i]*kk.x; a1 += q0[2*i+1]*kk.y; }
        float p = a0+a1;
        p += __shfl_xor(p,1);
        p += __shfl_xor(p,2);
        s[jj] = (j0+j0s+jj <= rg) ? p : -1e30f;
      }
      float mt = s[0];
      #pragma unroll
      for (int jj=1;jj<16;++jj) mt = fmaxf(mt, s[jj]);
      float mn = fmaxf(m, mt);
      float sc = __expf(m - mn);
      float lsum = 0.f;
      #pragma unroll
      for (int jj=0;jj<16;++jj){ s[jj] = __expf(s[jj]-mn); lsum += s[jj]; }
      l = l*sc + lsum;
      #pragma unroll
      for (int i=0;i<50;++i) acc[i]*=sc;
      #pragma unroll
      for (int jj=0;jj<16;++jj){
        const float2* vr = (const float2*)(vl + (j0s+jj)*200 + dq*50);
        const float pj = s[jj];
        #pragma unroll
        for (int i=0;i<25;++i){ float2 vv=vr[i]; acc[2*i] += pj*vv.x; acc[2*i+1] += pj*vv.y; }
      }
      m = mn;
    }
  }
  const float rl = 1.f/l;
  __hip_bfloat16* og = oh + (size_t)nh*T_*D_ + (size_t)rg*D_ + dq*50;
  #pragma unroll
  for (int i=0;i<25;++i){
    __hip_bfloat162 hb;
    hb.x = f2b(acc[2*i]*rl);
    hb.y = f2b(acc[2*i+1]*rl);
    ((__hip_bfloat162*)og)[i] = hb;
  }
}

// ---------------- K7: z=bn(oh)+xa; ffn; z2=relu+xa; z3=bn; out=relu(z3+x) ----------------
__global__ __launch_bounds__(256) void k_out(
    const __hip_bfloat16* __restrict__ oh, const __hip_bfloat16* __restrict__ xa,
    const float* __restrict__ x, const float* __restrict__ W_ffn,
    const float* __restrict__ b_ffn, const float* __restrict__ m_gamma,
    const float* __restrict__ m_beta, float* __restrict__ out)
{
  const int t=blockIdx.x, n=blockIdx.y, tid=threadIdx.x;
  __shared__ float zl[CV], xal[CV];
  const float invs=rsqrtf(1.f+EPSB);
  const __hip_bfloat16* xan = xa + (size_t)n*C_*T_*V_;
  for (int i=tid;i<CV;i+=256){
    int c=i/V_, v=i%V_;
    float xav=b2f(xan[(size_t)c*T_*V_+t*V_+v]);
    xal[i]=xav;
    int h=c/IH, o=c%IH;
    float ov=b2f(oh[(((size_t)n*H_+h)*T_+t)*D_ + o*V_ + v]);
    zl[i]=m_gamma[c]*invs*ov + m_beta[c] + xav;
  }
  __syncthreads();
  const float* xn = x + (size_t)n*C_*T_*V_;
  float* outn = out + (size_t)n*C_*T_*V_;
  for (int i=tid;i<CV;i+=256){
    int o=i/V_, v=i%V_;
    float acc=b_ffn[o];
    const float* wr = W_ffn + (size_t)o*C_;
    #pragma unroll 8
    for (int c=0;c<C_;++c) acc += wr[c]*zl[c*V_+v];
    float z2=fmaxf(acc,0.f)+xal[i];
    float z3=m_gamma[o]*invs*z2 + m_beta[o];
    outn[(size_t)o*T_*V_+t*V_+v]=fmaxf(z3 + xn[(size_t)o*T_*V_+t*V_+v], 0.f);
  }
}

extern "C" void kernel_launch(void* const* d_in, const int* in_sizes, int n_in,
                              void* d_out, int out_size, void* d_ws, size_t ws_size,
                              hipStream_t stream) {
  const float* x      = (const float*)d_in[0];
  const float* A      = (const float*)d_in[1];
  const float* alphap = (const float*)d_in[2];
  const float* Wq     = (const float*)d_in[3];
  const float* bq     = (const float*)d_in[4];
  const float* Wk     = (const float*)d_in[5];
  const float* bk     = (const float*)d_in[6];
  const float* Wf     = (const float*)d_in[7];
  const float* bfp    = (const float*)d_in[8];
  const float* g_gamma= (const float*)d_in[9];
  const float* g_beta = (const float*)d_in[10];
  const float* W_sa   = (const float*)d_in[11];
  const float* b_sa   = (const float*)d_in[12];
  const float* W_ta   = (const float*)d_in[13];
  const float* b_ta   = (const float*)d_in[14];
  const float* W_fc1  = (const float*)d_in[15];
  const float* b_fc1  = (const float*)d_in[16];
  const float* W_fc2  = (const float*)d_in[17];
  const float* b_fc2  = (const float*)d_in[18];
  const float* pos_emb= (const float*)d_in[19];
  const float* Wq_h   = (const float*)d_in[20];
  const float* bq_h   = (const float*)d_in[21];
  const float* Wk_h   = (const float*)d_in[22];
  const float* bk_h   = (const float*)d_in[23];
  const float* Wv_h   = (const float*)d_in[24];
  const float* bv_h   = (const float*)d_in[25];
  const float* W_ffn  = (const float*)d_in[26];
  const float* b_ffn  = (const float*)d_in[27];
  const float* m_gamma= (const float*)d_in[28];
  const float* m_beta = (const float*)d_in[29];
  float* out = (float*)d_out;

  // workspace layout (f32 region then bf16 region) — ~268 MB total
  float* ws   = (float*)d_ws;
  float* Aad  = ws;                    // 128*3*625   = 240000
  float* seT  = Aad + 240000;          // 128*64*25   = 204800
  float* seV  = seT + 204800;          // 128*64*128  = 1048576
  float* sa   = seV + 1048576;         // 128*25      = 3200
  float* ta   = sa  + 3200;            // 128*128     = 16384
  float* ca   = ta  + 16384;           // 128*64      = 8192
  __hip_bfloat16* y1 = (__hip_bfloat16*)(ca + 8192);  // 26214400 elems (reused as oh)
  __hip_bfloat16* xa = y1 + (size_t)26214400;
  __hip_bfloat16* qb = xa + (size_t)26214400;
  __hip_bfloat16* kb = qb + (size_t)26214400;
  __hip_bfloat16* vb = kb + (size_t)26214400;
  __hip_bfloat16* oh = y1;  // reuse: y1 dead after k_xa_qkv
  // attg: 8*384*625 f32 = 7.7MB, placed in the (not-yet-written) y1 region
  float* attg = (float*)y1;

  k_gcn_att1<<<dim3(8, N_*S_), 256, 0, stream>>>(x, Wq, bq, Wk, bk, attg);
  k_gcn_att2<<<N_*S_, 256, 0, stream>>>(attg, A, alphap, Aad);
  k_gcn_y<<<dim3(T_, N_), 256, 0, stream>>>(x, Aad, Wf, bfp, g_gamma, g_beta, y1);
  k_seT<<<dim3(C_, N_), 256, 0, stream>>>(y1, seT);
  k_sa<<<N_, 64, 0, stream>>>(seT, W_sa, b_sa, sa);
  k_seV<<<dim3(C_, N_), 256, 0, stream>>>(y1, sa, seV);
  k_ta_ca<<<N_, 128, 0, stream>>>(seV, W_ta, b_ta, W_fc1, b_fc1, W_fc2, b_fc2, ta, ca);
  k_xa_qkv<<<dim3(T_, N_), 256, 0, stream>>>(y1, pos_emb, sa, ta, ca,
      Wq_h, bq_h, Wk_h, bk_h, Wv_h, bv_h, xa, qb, kb, vb);
  k_attn<<<dim3(2, H_, N_), 256, 0, stream>>>(qb, kb, vb, oh);
  k_out<<<dim3(T_, N_), 256, 0, stream>>>(oh, xa, x, W_ffn, b_ffn, m_gamma, m_beta, out);
}

// Round 3
// 3111.495 us; speedup vs baseline: 1.5254x; 1.2120x over previous
//
#include <hip/hip_runtime.h>
#include <hip/hip_bf16.h>

#define N_ 128
#define C_ 64
#define T_ 128
#define V_ 25
#define S_ 3
#define IG 16
#define IH 8
#define H_ 8
#define D_ 200   // IH*V
#define CV 1600  // C_*V_
#define TV 3200  // T_*V_
#define EPSB 1e-5f

__device__ __forceinline__ float sigm(float x){ return 1.f/(1.f+expf(-x)); }
__device__ __forceinline__ float b2f(__hip_bfloat16 b){ return __bfloat162float(b); }
__device__ __forceinline__ __hip_bfloat16 f2b(float f){ return __float2bfloat16(f); }
__device__ __forceinline__ float ubl(unsigned int u){ return __uint_as_float(u<<16); }
__device__ __forceinline__ float ubh(unsigned int u){ return __uint_as_float(u & 0xffff0000u); }
__device__ __forceinline__ unsigned short f2bu(float f){
  unsigned int u = __float_as_uint(f);
  u += 0x7fff + ((u>>16)&1);
  return (unsigned short)(u>>16);
}

// ---------------- K1a: adaptive graph attention partials, chunked over t ----------------
__global__ __launch_bounds__(256) void k_gcn_att1(
    const float* __restrict__ x,
    const float* __restrict__ Wq, const float* __restrict__ bq,
    const float* __restrict__ Wk, const float* __restrict__ bk,
    float* __restrict__ attg)
{
  const int tc = blockIdx.x, ns = blockIdx.y, n = ns / S_, s = ns % S_;
  const int tid = threadIdx.x;
  __shared__ float xt[CV];
  __shared__ float wq_l[IG*C_], wk_l[IG*C_];
  __shared__ float qv[IG*V_], kv[IG*V_];
  __shared__ float att[V_*V_];
  for (int i=tid;i<IG*C_;i+=256){ wq_l[i]=Wq[s*IG*C_+i]; wk_l[i]=Wk[s*IG*C_+i]; }
  for (int i=tid;i<V_*V_;i+=256) att[i]=0.f;
  __syncthreads();
  const float* xn = x + (size_t)n*C_*T_*V_;
  const int t0 = tc*16;
  for (int t=t0;t<t0+16;++t){
    for (int i=tid;i<CV;i+=256) xt[i]=xn[(size_t)(i/V_)*T_*V_ + t*V_ + (i%V_)];
    __syncthreads();
    for (int i=tid;i<2*IG*V_;i+=256){
      int half=i/(IG*V_), r=i%(IG*V_), ii=r/V_, v=r%V_;
      const float* w = half?wk_l:wq_l;
      float acc = half? bk[s*IG+ii] : bq[s*IG+ii];
      #pragma unroll 8
      for (int c=0;c<C_;++c) acc += w[ii*C_+c]*xt[c*V_+v];
      (half?kv:qv)[r]=acc;
    }
    __syncthreads();
    for (int i=tid;i<V_*V_;i+=256){
      int v=i/V_, w=i%V_;
      float acc=0.f;
      #pragma unroll
      for (int ii=0;ii<IG;++ii) acc += qv[ii*V_+v]*kv[ii*V_+w];
      att[i]+=acc;
    }
    __syncthreads();
  }
  float* Ao = attg + ((size_t)tc*(N_*S_) + ns)*(V_*V_);
  for (int i=tid;i<V_*V_;i+=256) Ao[i]=att[i];
}

// ---------------- K1b: reduce chunks + softmax(dim=-2) + Aad ----------------
__global__ __launch_bounds__(256) void k_gcn_att2(
    const float* __restrict__ attg, const float* __restrict__ A,
    const float* __restrict__ alphap, float* __restrict__ Aad)
{
  const int ns = blockIdx.x, s = ns % S_, tid = threadIdx.x;
  __shared__ float att[V_*V_];
  for (int i=tid;i<V_*V_;i+=256){
    float acc=0.f;
    #pragma unroll
    for (int tc=0;tc<8;++tc) acc += attg[((size_t)tc*(N_*S_) + ns)*(V_*V_) + i];
    att[i]=acc;
  }
  __syncthreads();
  if (tid<V_){
    const int w=tid; const float inv=1.f/(IG*T_);
    float mx=-1e30f;
    for (int v=0;v<V_;++v) mx=fmaxf(mx, att[v*V_+w]*inv);
    float sum=0.f;
    for (int v=0;v<V_;++v){ float e=expf(att[v*V_+w]*inv-mx); att[v*V_+w]=e; sum+=e; }
    float rs=1.f/sum;
    for (int v=0;v<V_;++v) att[v*V_+w]*=rs;
  }
  __syncthreads();
  const float alpha=alphap[0];
  float* Ao = Aad + (size_t)ns*V_*V_;
  for (int i=tid;i<V_*V_;i+=256) Ao[i]=A[s*V_*V_+i]+alpha*att[i];
}

// ---------------- K2: graph conv + Wf + bn + residual + relu -> y1 (bf16) ----------------
__global__ __launch_bounds__(256) void k_gcn_y(
    const float* __restrict__ x, const float* __restrict__ Aad,
    const float* __restrict__ Wf, const float* __restrict__ bfp,
    const float* __restrict__ g_gamma, const float* __restrict__ g_beta,
    __hip_bfloat16* __restrict__ y1)
{
  const int t=blockIdx.x, n=blockIdx.y, tid=threadIdx.x;
  __shared__ float xt[CV], tmp[CV], yacc[CV];
  __shared__ float Al[S_*V_*V_];
  __shared__ float wfl[C_*C_];
  const float* xn = x + (size_t)n*C_*T_*V_;
  for (int i=tid;i<CV;i+=256){ xt[i]=xn[(size_t)(i/V_)*T_*V_+t*V_+(i%V_)]; yacc[i]=0.f; }
  for (int i=tid;i<S_*V_*V_;i+=256) Al[i]=Aad[(size_t)n*S_*V_*V_+i];
  __syncthreads();
  for (int s=0;s<S_;++s){
    const float* As = Al + s*V_*V_;
    for (int i=tid;i<CV;i+=256){
      int c=i/V_, w=i%V_;
      float acc=0.f;
      #pragma unroll
      for (int v=0;v<V_;++v) acc += xt[c*V_+v]*As[v*V_+w];
      tmp[i]=acc;
    }
    for (int i=tid;i<C_*C_;i+=256) wfl[i]=Wf[(size_t)s*C_*C_+i];
    __syncthreads();
    for (int i=tid;i<CV;i+=256){
      int o=i/V_, w=i%V_;
      const float* wr = wfl + o*C_;
      float acc=0.f;
      #pragma unroll 8
      for (int c=0;c<C_;++c) acc += wr[c]*tmp[c*V_+w];
      yacc[i]+=acc;
    }
    __syncthreads();
  }
  const float invs = rsqrtf(1.f+EPSB);
  __hip_bfloat16* yo = y1 + (size_t)n*C_*T_*V_;
  for (int i=tid;i<CV;i+=256){
    int o=i/V_, w=i%V_;
    float b = bfp[o]+bfp[C_+o]+bfp[2*C_+o];
    float val = (yacc[i]+b)*(g_gamma[o]*invs)+g_beta[o]+xn[(size_t)o*T_*V_+t*V_+w];
    yo[(size_t)o*T_*V_+t*V_+w]=f2b(fmaxf(val,0.f));
  }
}

// ---------------- K3a: seT[n,c,v] = mean_t y1 ----------------
__global__ __launch_bounds__(256) void k_seT(const __hip_bfloat16* __restrict__ y1,
    float* __restrict__ seT)
{
  const int c=blockIdx.x, n=blockIdx.y, tid=threadIdx.x;
  __shared__ float sv[V_];
  if (tid<V_) sv[tid]=0.f;
  __syncthreads();
  const __hip_bfloat16* yp = y1 + ((size_t)n*C_+c)*T_*V_;
  for (int i=tid;i<TV;i+=256) atomicAdd(&sv[i%V_], b2f(yp[i]));
  __syncthreads();
  if (tid<V_) seT[((size_t)n*C_+c)*V_+tid]=sv[tid]*(1.f/T_);
}

// ---------------- K3b: sa[n,v] spatial gate ----------------
__global__ __launch_bounds__(64) void k_sa(const float* __restrict__ seT,
    const float* __restrict__ W_sa, const float* __restrict__ b_sa,
    float* __restrict__ sa)
{
  const int n=blockIdx.x, tid=threadIdx.x;
  if (tid>=V_) return;
  const float* se = seT + (size_t)n*C_*V_;
  float acc=b_sa[0];
  for (int c=0;c<C_;++c){
    #pragma unroll
    for (int k=0;k<V_;++k){
      int vv=tid+k-12;  // pad = (V-1)/2 = 12
      if (vv>=0&&vv<V_) acc+=se[c*V_+vv]*W_sa[c*V_+k];
    }
  }
  sa[n*V_+tid]=sigm(acc);
}

// ---------------- K3c: seV[n,c,t] = mean_v y1*(1+sa) ----------------
__global__ __launch_bounds__(256) void k_seV(const __hip_bfloat16* __restrict__ y1,
    const float* __restrict__ sa, float* __restrict__ seV)
{
  const int c=blockIdx.x, n=blockIdx.y, tid=threadIdx.x;
  __shared__ float st[T_];
  __shared__ float sal[V_];
  if (tid<T_) st[tid]=0.f;
  if (tid<V_) sal[tid]=1.f+sa[n*V_+tid];
  __syncthreads();
  const __hip_bfloat16* yp = y1 + ((size_t)n*C_+c)*T_*V_;
  for (int i=tid;i<TV;i+=256) atomicAdd(&st[i/V_], b2f(yp[i])*sal[i%V_]);
  __syncthreads();
  if (tid<T_) seV[((size_t)n*C_+c)*T_+tid]=st[tid]*(1.f/V_);
}

// ---------------- K3d: ta[n,t] temporal gate + ca[n,c] channel gate ----------------
__global__ __launch_bounds__(128) void k_ta_ca(const float* __restrict__ seV,
    const float* __restrict__ W_ta, const float* __restrict__ b_ta,
    const float* __restrict__ W_fc1, const float* __restrict__ b_fc1,
    const float* __restrict__ W_fc2, const float* __restrict__ b_fc2,
    float* __restrict__ ta, float* __restrict__ ca)
{
  const int n=blockIdx.x, tid=threadIdx.x;
  __shared__ float tal[T_];
  __shared__ float scl[C_];
  __shared__ float h1[32];
  const float* sv = seV + (size_t)n*C_*T_;
  {
    float acc=b_ta[0];
    for (int c=0;c<C_;++c){
      #pragma unroll
      for (int k=0;k<9;++k){
        int tt=tid+k-4;
        if (tt>=0&&tt<T_) acc+=sv[c*T_+tt]*W_ta[c*9+k];
      }
    }
    float s=sigm(acc);
    tal[tid]=s; ta[n*T_+tid]=s;
  }
  __syncthreads();
  if (tid<C_){
    float acc=0.f;
    for (int t=0;t<T_;++t) acc += sv[tid*T_+t]*(1.f+tal[t]);
    scl[tid]=acc*(1.f/T_);
  }
  __syncthreads();
  if (tid<32){
    float acc=b_fc1[tid];
    for (int c=0;c<C_;++c) acc += scl[c]*W_fc1[tid*C_+c];
    h1[tid]=fmaxf(acc,0.f);
  }
  __syncthreads();
  if (tid<C_){
    float acc=b_fc2[tid];
    for (int j=0;j<32;++j) acc += h1[j]*W_fc2[tid*32+j];
    ca[n*C_+tid]=sigm(acc);
  }
}

// ---------------- K4: xa = y1*gates + pe (bf16), plus q/k/v projections (bf16) ----------------
__global__ __launch_bounds__(256) void k_xa_qkv(
    const __hip_bfloat16* __restrict__ y1, const float* __restrict__ pos_emb,
    const float* __restrict__ sa, const float* __restrict__ ta, const float* __restrict__ ca,
    const float* __restrict__ Wq_h, const float* __restrict__ bq_h,
    const float* __restrict__ Wk_h, const float* __restrict__ bk_h,
    const float* __restrict__ Wv_h, const float* __restrict__ bv_h,
    __hip_bfloat16* __restrict__ xa, __hip_bfloat16* __restrict__ qb,
    __hip_bfloat16* __restrict__ kb, __hip_bfloat16* __restrict__ vb)
{
  const int t=blockIdx.x, n=blockIdx.y, tid=threadIdx.x;
  __shared__ float xal[CV];
  __shared__ float wl[3*C_*C_];   // 48KB: Wq_h | Wk_h | Wv_h
  const float tg = 1.f + ta[n*T_+t];
  const __hip_bfloat16* y1n = y1 + (size_t)n*C_*T_*V_;
  __hip_bfloat16* xan = xa + (size_t)n*C_*T_*V_;
  for (int i=tid;i<C_*C_;i+=256){
    wl[i]=Wq_h[i]; wl[C_*C_+i]=Wk_h[i]; wl[2*C_*C_+i]=Wv_h[i];
  }
  for (int i=tid;i<CV;i+=256){
    int c=i/V_, v=i%V_;
    float val = b2f(y1n[(size_t)c*T_*V_+t*V_+v]) * (1.f+sa[n*V_+v]) * tg * (1.f+ca[n*C_+c])
              + pos_emb[(size_t)t*CV + i];
    xal[i]=val;
    xan[(size_t)c*T_*V_+t*V_+v]=f2b(val);
  }
  __syncthreads();
  for (int i=tid;i<3*CV;i+=256){
    int which=i/CV, r=i%CV, ho=r/V_, v=r%V_;   // ho = h*IH + o
    const float* B = which==0?bq_h:(which==1?bk_h:bv_h);
    float acc = B[ho];
    const float* wrow = wl + which*C_*C_ + ho*C_;
    #pragma unroll 8
    for (int c=0;c<C_;++c) acc += wrow[c]*xal[c*V_+v];
    int h=ho/IH, o=ho%IH;
    size_t idx = (((size_t)n*H_+h)*T_+t)*D_ + o*V_ + v;
    __hip_bfloat16 bv16=f2b(acc);
    if (which==0) qb[idx]=bv16; else if (which==1) kb[idx]=bv16; else vb[idx]=bv16;
  }
}

// ---------------- K5: flash causal MHA, register-tiled two-GEMM ----------------
// grid (2, H_, N_): bx = 64-row q-tile. 256 thr.
// S phase: thread = 4q x 2k micro-tile.  PV phase: thread = 2q x 28d (d interleaved by 4).
#define TQ 64
#define TK 32
__global__ __launch_bounds__(256) void k_attn(
    const __hip_bfloat16* __restrict__ qb, const __hip_bfloat16* __restrict__ kb,
    const __hip_bfloat16* __restrict__ vb, __hip_bfloat16* __restrict__ oh)
{
  const int bx = blockIdx.x;
  const int nh = blockIdx.z*H_ + blockIdx.y;
  const int tid = threadIdx.x;
  __shared__ __align__(16) unsigned short Qt[200*TQ];  // [k][q] bf16
  __shared__ __align__(16) unsigned short Kt[200*TK];  // [k][key] bf16
  __shared__ __align__(16) float vl[TK*224];           // [key][d], zero-padded 200..223
  __shared__ __align__(16) unsigned short Pl[TK*TQ];   // [key][q] bf16
  __shared__ float frl[TQ];
  const __hip_bfloat16* qg_ = qb + (size_t)nh*T_*D_;
  const __hip_bfloat16* kg_ = kb + (size_t)nh*T_*D_;
  const __hip_bfloat16* vg_ = vb + (size_t)nh*T_*D_;
  __hip_bfloat16* og_ = oh + (size_t)nh*T_*D_;
  const float scale = 0.0707106781f;  // 1/sqrt(200)

  // zero V pad columns
  for (int i=tid;i<TK*24;i+=256) vl[(i/24)*224 + 200 + (i%24)] = 0.f;
  // stage Q transposed (bf16): coalesced global reads, scattered LDS writes (tiny vs compute)
  {
    const unsigned int* qsrc = (const unsigned int*)(qg_ + (size_t)bx*TQ*D_);
    for (int i=tid;i<TQ*100;i+=256){
      int row=i/100, w=i%100;
      unsigned int u = qsrc[i];
      Qt[(2*w)*TQ+row]   = (unsigned short)(u&0xffffu);
      Qt[(2*w+1)*TQ+row] = (unsigned short)(u>>16);
    }
  }
  const int qgS=(tid>>4)*4, kgS=(tid&15)*2;       // S-phase map
  const int qpP=(tid>>3)*2, dgP=tid&7;            // PV-phase map
  float mloc[4], lloc[4];
  #pragma unroll
  for (int r=0;r<4;++r){ mloc[r]=-1e30f; lloc[r]=0.f; }
  float accA[28], accB[28];
  #pragma unroll
  for (int i=0;i<28;++i){ accA[i]=0.f; accB[i]=0.f; }

  const int ntiles = (bx==0)? 2 : 4;
  for (int kt=0; kt<ntiles; ++kt){
    const int j0 = kt*TK;
    __syncthreads();
    // stage K transposed + V f32
    {
      const unsigned int* ksrc = (const unsigned int*)(kg_ + (size_t)j0*D_);
      const unsigned int* vsrc = (const unsigned int*)(vg_ + (size_t)j0*D_);
      for (int i=tid;i<TK*100;i+=256){
        int row=i/100, w=i%100;
        unsigned int uk = ksrc[i];
        Kt[(2*w)*TK+row]   = (unsigned short)(uk&0xffffu);
        Kt[(2*w+1)*TK+row] = (unsigned short)(uk>>16);
        unsigned int uv = vsrc[i];
        vl[row*224+2*w]   = ubl(uv);
        vl[row*224+2*w+1] = ubh(uv);
      }
    }
    __syncthreads();
    // ---- S = Q K^T (4q x 2k per thread) ----
    float sA[4][2];
    #pragma unroll
    for (int r=0;r<4;++r){ sA[r][0]=0.f; sA[r][1]=0.f; }
    #pragma unroll 2
    for (int k=0;k<200;++k){
      uint2 qw = *(const uint2*)(Qt + k*TQ + qgS);
      unsigned int kw = *(const unsigned int*)(Kt + k*TK + kgS);
      float qf0=ubl(qw.x), qf1=ubh(qw.x), qf2=ubl(qw.y), qf3=ubh(qw.y);
      float kf0=ubl(kw),  kf1=ubh(kw);
      sA[0][0]+=qf0*kf0; sA[0][1]+=qf0*kf1;
      sA[1][0]+=qf1*kf0; sA[1][1]+=qf1*kf1;
      sA[2][0]+=qf2*kf0; sA[2][1]+=qf2*kf1;
      sA[3][0]+=qf3*kf0; sA[3][1]+=qf3*kf1;
    }
    // ---- online softmax (rows shared by 16 consecutive lanes) ----
    #pragma unroll
    for (int r=0;r<4;++r){
      const int qi = bx*TQ + qgS + r;
      float s0 = (j0+kgS   <= qi) ? sA[r][0]*scale : -1e30f;
      float s1 = (j0+kgS+1 <= qi) ? sA[r][1]*scale : -1e30f;
      float tm = fmaxf(s0,s1);
      #pragma unroll
      for (int off=1;off<16;off<<=1) tm = fmaxf(tm, __shfl_xor(tm, off));
      float mn = fmaxf(mloc[r], tm);
      float frv = __expf(mloc[r]-mn);
      float p0 = __expf(s0-mn), p1 = __expf(s1-mn);
      float ts = p0+p1;
      #pragma unroll
      for (int off=1;off<16;off<<=1) ts += __shfl_xor(ts, off);
      lloc[r] = lloc[r]*frv + ts;
      mloc[r] = mn;
      if ((tid&15)==0) frl[qgS+r] = frv;
      Pl[kgS*TQ + qgS + r]     = f2bu(p0);
      Pl[(kgS+1)*TQ + qgS + r] = f2bu(p1);
    }
    __syncthreads();
    // ---- PV (2q x 28d per thread) ----
    {
      const float f0 = frl[qpP], f1 = frl[qpP+1];
      #pragma unroll
      for (int i=0;i<28;++i){ accA[i]*=f0; accB[i]*=f1; }
      for (int k=0;k<TK;++k){
        unsigned int pw = *(const unsigned int*)(Pl + k*TQ + qpP);
        float p0=ubl(pw), p1=ubh(pw);
        const float* vrow = vl + k*224 + dgP*4;
        #pragma unroll
        for (int i=0;i<7;++i){
          float4 vv = *(const float4*)(vrow + 32*i);
          accA[i*4+0]+=p0*vv.x; accA[i*4+1]+=p0*vv.y; accA[i*4+2]+=p0*vv.z; accA[i*4+3]+=p0*vv.w;
          accB[i*4+0]+=p1*vv.x; accB[i*4+1]+=p1*vv.y; accB[i*4+2]+=p1*vv.z; accB[i*4+3]+=p1*vv.w;
        }
      }
    }
  }
  __syncthreads();
  if ((tid&15)==0){
    #pragma unroll
    for (int r=0;r<4;++r) frl[qgS+r] = 1.f/lloc[r];
  }
  __syncthreads();
  {
    const float li0=frl[qpP], li1=frl[qpP+1];
    __hip_bfloat16* o0 = og_ + (size_t)(bx*TQ+qpP)*D_;
    __hip_bfloat16* o1 = o0 + D_;
    #pragma unroll
    for (int i=0;i<7;++i){
      if (i<6 || dgP<2){
        int d = dgP*4 + 32*i;
        __hip_bfloat162 h0a; h0a.x=f2b(accA[i*4+0]*li0); h0a.y=f2b(accA[i*4+1]*li0);
        __hip_bfloat162 h0b; h0b.x=f2b(accA[i*4+2]*li0); h0b.y=f2b(accA[i*4+3]*li0);
        __hip_bfloat162 h1a; h1a.x=f2b(accB[i*4+0]*li1); h1a.y=f2b(accB[i*4+1]*li1);
        __hip_bfloat162 h1b; h1b.x=f2b(accB[i*4+2]*li1); h1b.y=f2b(accB[i*4+3]*li1);
        *(__hip_bfloat162*)(o0+d)   = h0a;
        *(__hip_bfloat162*)(o0+d+2) = h0b;
        *(__hip_bfloat162*)(o1+d)   = h1a;
        *(__hip_bfloat162*)(o1+d+2) = h1b;
      }
    }
  }
}

// ---------------- K7: z=bn(oh)+xa; ffn; z2=relu+xa; z3=bn; out=relu(z3+x) ----------------
__global__ __launch_bounds__(256) void k_out(
    const __hip_bfloat16* __restrict__ oh, const __hip_bfloat16* __restrict__ xa,
    const float* __restrict__ x, const float* __restrict__ W_ffn,
    const float* __restrict__ b_ffn, const float* __restrict__ m_gamma,
    const float* __restrict__ m_beta, float* __restrict__ out)
{
  const int t=blockIdx.x, n=blockIdx.y, tid=threadIdx.x;
  __shared__ float zl[CV], xal[CV];
  __shared__ float wfl[C_*C_];
  const float invs=rsqrtf(1.f+EPSB);
  const __hip_bfloat16* xan = xa + (size_t)n*C_*T_*V_;
  for (int i=tid;i<C_*C_;i+=256) wfl[i]=W_ffn[i];
  for (int i=tid;i<CV;i+=256){
    int c=i/V_, v=i%V_;
    float xav=b2f(xan[(size_t)c*T_*V_+t*V_+v]);
    xal[i]=xav;
    int h=c/IH, o=c%IH;
    float ov=b2f(oh[(((size_t)n*H_+h)*T_+t)*D_ + o*V_ + v]);
    zl[i]=m_gamma[c]*invs*ov + m_beta[c] + xav;
  }
  __syncthreads();
  const float* xn = x + (size_t)n*C_*T_*V_;
  float* outn = out + (size_t)n*C_*T_*V_;
  for (int i=tid;i<CV;i+=256){
    int o=i/V_, v=i%V_;
    float acc=b_ffn[o];
    const float* wr = wfl + o*C_;
    #pragma unroll 8
    for (int c=0;c<C_;++c) acc += wr[c]*zl[c*V_+v];
    float z2=fmaxf(acc,0.f)+xal[i];
    float z3=m_gamma[o]*invs*z2 + m_beta[o];
    outn[(size_t)o*T_*V_+t*V_+v]=fmaxf(z3 + xn[(size_t)o*T_*V_+t*V_+v], 0.f);
  }
}

extern "C" void kernel_launch(void* const* d_in, const int* in_sizes, int n_in,
                              void* d_out, int out_size, void* d_ws, size_t ws_size,
                              hipStream_t stream) {
  const float* x      = (const float*)d_in[0];
  const float* A      = (const float*)d_in[1];
  const float* alphap = (const float*)d_in[2];
  const float* Wq     = (const float*)d_in[3];
  const float* bq     = (const float*)d_in[4];
  const float* Wk     = (const float*)d_in[5];
  const float* bk     = (const float*)d_in[6];
  const float* Wf     = (const float*)d_in[7];
  const float* bfp    = (const float*)d_in[8];
  const float* g_gamma= (const float*)d_in[9];
  const float* g_beta = (const float*)d_in[10];
  const float* W_sa   = (const float*)d_in[11];
  const float* b_sa   = (const float*)d_in[12];
  const float* W_ta   = (const float*)d_in[13];
  const float* b_ta   = (const float*)d_in[14];
  const float* W_fc1  = (const float*)d_in[15];
  const float* b_fc1  = (const float*)d_in[16];
  const float* W_fc2  = (const float*)d_in[17];
  const float* b_fc2  = (const float*)d_in[18];
  const float* pos_emb= (const float*)d_in[19];
  const float* Wq_h   = (const float*)d_in[20];
  const float* bq_h   = (const float*)d_in[21];
  const float* Wk_h   = (const float*)d_in[22];
  const float* bk_h   = (const float*)d_in[23];
  const float* Wv_h   = (const float*)d_in[24];
  const float* bv_h   = (const float*)d_in[25];
  const float* W_ffn  = (const float*)d_in[26];
  const float* b_ffn  = (const float*)d_in[27];
  const float* m_gamma= (const float*)d_in[28];
  const float* m_beta = (const float*)d_in[29];
  float* out = (float*)d_out;

  float* ws   = (float*)d_ws;
  float* Aad  = ws;                    // 128*3*625   = 240000
  float* seT  = Aad + 240000;          // 128*64*25   = 204800
  float* seV  = seT + 204800;          // 128*64*128  = 1048576
  float* sa   = seV + 1048576;         // 128*25      = 3200
  float* ta   = sa  + 3200;            // 128*128     = 16384
  float* ca   = ta  + 16384;           // 128*64      = 8192
  __hip_bfloat16* y1 = (__hip_bfloat16*)(ca + 8192);  // 26214400 elems (reused as oh)
  __hip_bfloat16* xa = y1 + (size_t)26214400;
  __hip_bfloat16* qb = xa + (size_t)26214400;
  __hip_bfloat16* kb = qb + (size_t)26214400;
  __hip_bfloat16* vb = kb + (size_t)26214400;
  __hip_bfloat16* oh = y1;  // reuse: y1 dead after k_xa_qkv
  float* attg = (float*)y1; // scratch before y1 is written

  k_gcn_att1<<<dim3(8, N_*S_), 256, 0, stream>>>(x, Wq, bq, Wk, bk, attg);
  k_gcn_att2<<<N_*S_, 256, 0, stream>>>(attg, A, alphap, Aad);
  k_gcn_y<<<dim3(T_, N_), 256, 0, stream>>>(x, Aad, Wf, bfp, g_gamma, g_beta, y1);
  k_seT<<<dim3(C_, N_), 256, 0, stream>>>(y1, seT);
  k_sa<<<N_, 64, 0, stream>>>(seT, W_sa, b_sa, sa);
  k_seV<<<dim3(C_, N_), 256, 0, stream>>>(y1, sa, seV);
  k_ta_ca<<<N_, 128, 0, stream>>>(seV, W_ta, b_ta, W_fc1, b_fc1, W_fc2, b_fc2, ta, ca);
  k_xa_qkv<<<dim3(T_, N_), 256, 0, stream>>>(y1, pos_emb, sa, ta, ca,
      Wq_h, bq_h, Wk_h, bk_h, Wv_h, bv_h, xa, qb, kb, vb);
  k_attn<<<dim3(2, H_, N_), 256, 0, stream>>>(qb, kb, vb, oh);
  k_out<<<dim3(T_, N_), 256, 0, stream>>>(oh, xa, x, W_ffn, b_ffn, m_gamma, m_beta, out);
}

// Round 4
// 1717.325 us; speedup vs baseline: 2.7637x; 1.8118x over previous
//
#include <hip/hip_runtime.h>
#include <hip/hip_bf16.h>

#define N_ 128
#define C_ 64
#define T_ 128
#define V_ 25
#define S_ 3
#define IG 16
#define IH 8
#define H_ 8
#define D_ 200   // IH*V
#define CV 1600  // C_*V_
#define TV 3200  // T_*V_
#define EPSB 1e-5f

typedef __attribute__((ext_vector_type(8))) short short8v;
typedef __attribute__((ext_vector_type(4))) float f32x4;
#define MFMA16 __builtin_amdgcn_mfma_f32_16x16x32_bf16

__device__ __forceinline__ float sigm(float x){ return 1.f/(1.f+expf(-x)); }
__device__ __forceinline__ float b2f(__hip_bfloat16 b){ return __bfloat162float(b); }
__device__ __forceinline__ __hip_bfloat16 f2b(float f){ return __float2bfloat16(f); }
__device__ __forceinline__ float ubl(unsigned int u){ return __uint_as_float(u<<16); }
__device__ __forceinline__ float ubh(unsigned int u){ return __uint_as_float(u & 0xffff0000u); }
__device__ __forceinline__ unsigned short f2bu(float f){
  unsigned int u = __float_as_uint(f);
  u += 0x7fff + ((u>>16)&1);
  return (unsigned short)(u>>16);
}
__device__ __forceinline__ unsigned long long pk4bf(f32x4 v){
  unsigned long long a = f2bu(v[0]);
  unsigned long long b = f2bu(v[1]);
  unsigned long long c = f2bu(v[2]);
  unsigned long long d = f2bu(v[3]);
  return a | (b<<16) | (c<<32) | (d<<48);
}

// ---------------- K1a: adaptive graph attention partials, chunked over t ----------------
__global__ __launch_bounds__(256) void k_gcn_att1(
    const float* __restrict__ x,
    const float* __restrict__ Wq, const float* __restrict__ bq,
    const float* __restrict__ Wk, const float* __restrict__ bk,
    float* __restrict__ attg)
{
  const int tc = blockIdx.x, ns = blockIdx.y, n = ns / S_, s = ns % S_;
  const int tid = threadIdx.x;
  __shared__ float xt[CV];
  __shared__ float wq_l[IG*C_], wk_l[IG*C_];
  __shared__ float qv[IG*V_], kv[IG*V_];
  __shared__ float att[V_*V_];
  for (int i=tid;i<IG*C_;i+=256){ wq_l[i]=Wq[s*IG*C_+i]; wk_l[i]=Wk[s*IG*C_+i]; }
  for (int i=tid;i<V_*V_;i+=256) att[i]=0.f;
  __syncthreads();
  const float* xn = x + (size_t)n*C_*T_*V_;
  const int t0 = tc*16;
  for (int t=t0;t<t0+16;++t){
    for (int i=tid;i<CV;i+=256) xt[i]=xn[(size_t)(i/V_)*T_*V_ + t*V_ + (i%V_)];
    __syncthreads();
    for (int i=tid;i<2*IG*V_;i+=256){
      int half=i/(IG*V_), r=i%(IG*V_), ii=r/V_, v=r%V_;
      const float* w = half?wk_l:wq_l;
      float acc = half? bk[s*IG+ii] : bq[s*IG+ii];
      #pragma unroll 8
      for (int c=0;c<C_;++c) acc += w[ii*C_+c]*xt[c*V_+v];
      (half?kv:qv)[r]=acc;
    }
    __syncthreads();
    for (int i=tid;i<V_*V_;i+=256){
      int v=i/V_, w=i%V_;
      float acc=0.f;
      #pragma unroll
      for (int ii=0;ii<IG;++ii) acc += qv[ii*V_+v]*kv[ii*V_+w];
      att[i]+=acc;
    }
    __syncthreads();
  }
  float* Ao = attg + ((size_t)tc*(N_*S_) + ns)*(V_*V_);
  for (int i=tid;i<V_*V_;i+=256) Ao[i]=att[i];
}

// ---------------- K1b: reduce chunks + softmax(dim=-2) + Aad ----------------
__global__ __launch_bounds__(256) void k_gcn_att2(
    const float* __restrict__ attg, const float* __restrict__ A,
    const float* __restrict__ alphap, float* __restrict__ Aad)
{
  const int ns = blockIdx.x, s = ns % S_, tid = threadIdx.x;
  __shared__ float att[V_*V_];
  for (int i=tid;i<V_*V_;i+=256){
    float acc=0.f;
    #pragma unroll
    for (int tc=0;tc<8;++tc) acc += attg[((size_t)tc*(N_*S_) + ns)*(V_*V_) + i];
    att[i]=acc;
  }
  __syncthreads();
  if (tid<V_){
    const int w=tid; const float inv=1.f/(IG*T_);
    float mx=-1e30f;
    for (int v=0;v<V_;++v) mx=fmaxf(mx, att[v*V_+w]*inv);
    float sum=0.f;
    for (int v=0;v<V_;++v){ float e=expf(att[v*V_+w]*inv-mx); att[v*V_+w]=e; sum+=e; }
    float rs=1.f/sum;
    for (int v=0;v<V_;++v) att[v*V_+w]*=rs;
  }
  __syncthreads();
  const float alpha=alphap[0];
  float* Ao = Aad + (size_t)ns*V_*V_;
  for (int i=tid;i<V_*V_;i+=256) Ao[i]=A[s*V_*V_+i]+alpha*att[i];
}

// ---------------- K2: MFMA graph conv + Wf + bn + residual + relu -> y1 (bf16) ----------------
// Phase1: agg_s(64x32) = xt(64x32bf16) * AsT^T ; Phase2: y(64x32) = W~(64x192) * aggT^T
__global__ __launch_bounds__(256) void k_gcn_y(
    const float* __restrict__ x, const float* __restrict__ Aad,
    const float* __restrict__ Wf, const float* __restrict__ bfp,
    const float* __restrict__ g_gamma, const float* __restrict__ g_beta,
    __hip_bfloat16* __restrict__ y1)
{
  const int t=blockIdx.x, n=blockIdx.y, tid=threadIdx.x;
  __shared__ __align__(16) short xtb[64*40];     // [c][v] pad40, v>=25 zeroed
  __shared__ __align__(16) short AsT[3*32*40];   // [s][w][v], v-pad zeroed
  __shared__ __align__(16) short Wt[64*200];     // [o][sc] sc=s*64+c
  __shared__ __align__(16) short aggT[32*200];   // [w][sc]
  const float* xn = x + (size_t)n*C_*T_*V_;
  // stage xt (bf16) + zero pads
  for (int i=tid;i<CV;i+=256){
    int c=i/V_, v=i%V_;
    xtb[c*40+v] = (short)f2bu(xn[(size_t)c*T_*V_ + t*V_ + v]);
  }
  for (int i=tid;i<64*7;i+=256){ int c=i/7, v=25+(i%7); xtb[c*40+v]=0; }
  for (int i=tid;i<3*32*7;i+=256){ int sw=i/7, v=25+(i%7); AsT[sw*40+v]=0; }
  // stage AsT (transposed adjacency)
  const float* Adn = Aad + (size_t)n*S_*V_*V_;
  for (int i=tid;i<S_*V_*V_;i+=256){
    int s=i/(V_*V_), r=i%(V_*V_), v=r/V_, w=r%V_;
    AsT[(s*32+w)*40+v] = (short)f2bu(Adn[i]);
  }
  // stage W~ (bf16, [o][s*64+c], stride 200)
  for (int i=tid;i<64*192;i+=256){
    int o=i/192, sc=i%192, s=sc/64, c=sc%64;
    Wt[o*200+sc] = (short)f2bu(Wf[(size_t)s*C_*C_ + o*C_ + c]);
  }
  __syncthreads();
  const int wv = tid>>6, l = tid&63;
  const int lc = l&15, lk = l>>4;
  // ---- phase 1: agg (rows c = wv*16..+15) ----
  for (int s=0;s<S_;++s){
    short8v a = *(const short8v*)(xtb + (wv*16+lc)*40 + lk*8);
    short8v b0 = *(const short8v*)(AsT + (s*32+lc)*40 + lk*8);
    short8v b1 = *(const short8v*)(AsT + (s*32+16+lc)*40 + lk*8);
    f32x4 z = {0.f,0.f,0.f,0.f};
    f32x4 acc0 = MFMA16(a,b0,z,0,0,0);
    f32x4 acc1 = MFMA16(a,b1,z,0,0,0);
    *(unsigned long long*)(aggT + lc*200      + s*64 + wv*16 + lk*4) = pk4bf(acc0);
    *(unsigned long long*)(aggT + (16+lc)*200 + s*64 + wv*16 + lk*4) = pk4bf(acc1);
  }
  __syncthreads();
  // ---- phase 2: y = W~ * agg (wave wv -> o rows wv*16..+15) ----
  f32x4 acc0 = {0.f,0.f,0.f,0.f}, acc1 = {0.f,0.f,0.f,0.f};
  #pragma unroll
  for (int ks=0;ks<6;++ks){
    short8v a  = *(const short8v*)(Wt + (wv*16+lc)*200 + ks*32 + lk*8);
    short8v b0 = *(const short8v*)(aggT + lc*200      + ks*32 + lk*8);
    short8v b1 = *(const short8v*)(aggT + (16+lc)*200 + ks*32 + lk*8);
    acc0 = MFMA16(a,b0,acc0,0,0,0);
    acc1 = MFMA16(a,b1,acc1,0,0,0);
  }
  // ---- epilogue: bias + bn + residual + relu ----
  const float invs = rsqrtf(1.f+EPSB);
  __hip_bfloat16* yo = y1 + (size_t)n*C_*T_*V_;
  #pragma unroll
  for (int reg=0;reg<4;++reg){
    const int o = wv*16 + lk*4 + reg;
    const float bsum = bfp[o]+bfp[C_+o]+bfp[2*C_+o];
    const float gs = g_gamma[o]*invs, gb = g_beta[o];
    {
      int w = lc;
      float val = (acc0[reg]+bsum)*gs + gb + xn[(size_t)o*T_*V_ + t*V_ + w];
      yo[(size_t)o*T_*V_ + t*V_ + w] = f2b(fmaxf(val,0.f));
    }
    if (lc < 9){
      int w = 16+lc;
      float val = (acc1[reg]+bsum)*gs + gb + xn[(size_t)o*T_*V_ + t*V_ + w];
      yo[(size_t)o*T_*V_ + t*V_ + w] = f2b(fmaxf(val,0.f));
    }
  }
}

// ---------------- K3a: seT[n,c,v] = mean_t y1 ----------------
__global__ __launch_bounds__(256) void k_seT(const __hip_bfloat16* __restrict__ y1,
    float* __restrict__ seT)
{
  const int c=blockIdx.x, n=blockIdx.y, tid=threadIdx.x;
  const int v = tid&31, g = tid>>5;
  __shared__ float red[8][33];
  const __hip_bfloat16* yp = y1 + ((size_t)n*C_+c)*T_*V_;
  float s=0.f;
  if (v < V_){
    #pragma unroll 4
    for (int j=0;j<16;++j){
      int t = g + j*8;
      s += b2f(yp[t*V_+v]);
    }
  }
  red[g][v]=s;
  __syncthreads();
  if (tid < V_){
    float tot=0.f;
    #pragma unroll
    for (int g2=0;g2<8;++g2) tot += red[g2][tid];
    seT[((size_t)n*C_+c)*V_+tid]=tot*(1.f/T_);
  }
}

// ---------------- K3b: sa[n,v] spatial gate ----------------
__global__ __launch_bounds__(64) void k_sa(const float* __restrict__ seT,
    const float* __restrict__ W_sa, const float* __restrict__ b_sa,
    float* __restrict__ sa)
{
  const int n=blockIdx.x, tid=threadIdx.x;
  if (tid>=V_) return;
  const float* se = seT + (size_t)n*C_*V_;
  float acc=b_sa[0];
  for (int c=0;c<C_;++c){
    #pragma unroll
    for (int k=0;k<V_;++k){
      int vv=tid+k-12;  // pad = (V-1)/2 = 12
      if (vv>=0&&vv<V_) acc+=se[c*V_+vv]*W_sa[c*V_+k];
    }
  }
  sa[n*V_+tid]=sigm(acc);
}

// ---------------- K3c: seV[n,c,t] = mean_v y1*(1+sa) ----------------
__global__ __launch_bounds__(256) void k_seV(const __hip_bfloat16* __restrict__ y1,
    const float* __restrict__ sa, float* __restrict__ seV)
{
  const int c=blockIdx.x, n=blockIdx.y, tid=threadIdx.x;
  const int v = tid&31, g = tid>>5;
  __shared__ float sal[32];
  if (tid<32) sal[tid] = (tid<V_)? 1.f+sa[n*V_+tid] : 0.f;
  __syncthreads();
  const __hip_bfloat16* yp = y1 + ((size_t)n*C_+c)*T_*V_;
  float* svo = seV + ((size_t)n*C_+c)*T_;
  const float sv_ = sal[v];
  for (int j=0;j<16;++j){
    int t = g*16 + j;
    float val = (v<V_)? b2f(yp[t*V_+v])*sv_ : 0.f;
    #pragma unroll
    for (int off=16;off;off>>=1) val += __shfl_xor(val, off);
    if (v==0) svo[t]=val*(1.f/V_);
  }
}

// ---------------- K3d: ta[n,t] temporal gate + ca[n,c] channel gate ----------------
__global__ __launch_bounds__(128) void k_ta_ca(const float* __restrict__ seV,
    const float* __restrict__ W_ta, const float* __restrict__ b_ta,
    const float* __restrict__ W_fc1, const float* __restrict__ b_fc1,
    const float* __restrict__ W_fc2, const float* __restrict__ b_fc2,
    float* __restrict__ ta, float* __restrict__ ca)
{
  const int n=blockIdx.x, tid=threadIdx.x;
  __shared__ float tal[T_];
  __shared__ float scl[C_];
  __shared__ float h1[32];
  const float* sv = seV + (size_t)n*C_*T_;
  {
    float acc=b_ta[0];
    for (int c=0;c<C_;++c){
      #pragma unroll
      for (int k=0;k<9;++k){
        int tt=tid+k-4;
        if (tt>=0&&tt<T_) acc+=sv[c*T_+tt]*W_ta[c*9+k];
      }
    }
    float s=sigm(acc);
    tal[tid]=s; ta[n*T_+tid]=s;
  }
  __syncthreads();
  if (tid<C_){
    float acc=0.f;
    for (int t=0;t<T_;++t) acc += sv[tid*T_+t]*(1.f+tal[t]);
    scl[tid]=acc*(1.f/T_);
  }
  __syncthreads();
  if (tid<32){
    float acc=b_fc1[tid];
    for (int c=0;c<C_;++c) acc += scl[c]*W_fc1[tid*C_+c];
    h1[tid]=fmaxf(acc,0.f);
  }
  __syncthreads();
  if (tid<C_){
    float acc=b_fc2[tid];
    for (int j=0;j<32;++j) acc += h1[j]*W_fc2[tid*32+j];
    ca[n*C_+tid]=sigm(acc);
  }
}

// ---------------- K4: MFMA xa/gates + q/k/v projections ----------------
__global__ __launch_bounds__(256) void k_xa_qkv(
    const __hip_bfloat16* __restrict__ y1, const float* __restrict__ pos_emb,
    const float* __restrict__ sa, const float* __restrict__ ta, const float* __restrict__ ca,
    const float* __restrict__ Wq_h, const float* __restrict__ bq_h,
    const float* __restrict__ Wk_h, const float* __restrict__ bk_h,
    const float* __restrict__ Wv_h, const float* __restrict__ bv_h,
    __hip_bfloat16* __restrict__ xa, __hip_bfloat16* __restrict__ qb,
    __hip_bfloat16* __restrict__ kb, __hip_bfloat16* __restrict__ vb)
{
  const int t=blockIdx.x, n=blockIdx.y, tid=threadIdx.x;
  __shared__ __align__(16) short w3[192*72];    // [mu][c], mu = which*64+ho
  __shared__ __align__(16) short xalT[32*72];   // [w][c]
  __shared__ float bl[192];
  // stage W (q|k|v) bf16
  for (int i=tid;i<192*64;i+=256){
    int mu=i/64, c=i%64, which=mu/C_, ho=mu%C_;
    const float* W = which==0?Wq_h:(which==1?Wk_h:Wv_h);
    w3[mu*72+c] = (short)f2bu(W[(size_t)ho*C_+c]);
  }
  if (tid<192){
    int which=tid/C_, ho=tid%C_;
    bl[tid] = (which==0?bq_h:(which==1?bk_h:bv_h))[ho];
  }
  // xa = y1*gates + pe  -> global bf16 + LDS transposed bf16
  const float tg = 1.f + ta[n*T_+t];
  const __hip_bfloat16* y1n = y1 + (size_t)n*C_*T_*V_;
  __hip_bfloat16* xan = xa + (size_t)n*C_*T_*V_;
  for (int i=tid;i<CV;i+=256){
    int c=i/V_, v=i%V_;
    float val = b2f(y1n[(size_t)c*T_*V_+t*V_+v]) * (1.f+sa[n*V_+v]) * tg * (1.f+ca[n*C_+c])
              + pos_emb[(size_t)t*CV + i];
    xan[(size_t)c*T_*V_+t*V_+v]=f2b(val);
    xalT[v*72+c] = (short)f2bu(val);
  }
  __syncthreads();
  const int wv=tid>>6, l=tid&63, lc=l&15, lk=l>>4;
  short8v bf_[2][2];
  #pragma unroll
  for (int ks=0;ks<2;++ks){
    bf_[ks][0] = *(const short8v*)(xalT + lc*72      + ks*32 + lk*8);
    bf_[ks][1] = *(const short8v*)(xalT + (16+lc)*72 + ks*32 + lk*8);
  }
  #pragma unroll
  for (int mt3=0;mt3<3;++mt3){
    const int mt = wv + mt3*4;
    f32x4 acc0 = {0.f,0.f,0.f,0.f}, acc1 = {0.f,0.f,0.f,0.f};
    #pragma unroll
    for (int ks=0;ks<2;++ks){
      short8v a = *(const short8v*)(w3 + (mt*16+lc)*72 + ks*32 + lk*8);
      acc0 = MFMA16(a, bf_[ks][0], acc0,0,0,0);
      acc1 = MFMA16(a, bf_[ks][1], acc1,0,0,0);
    }
    #pragma unroll
    for (int reg=0;reg<4;++reg){
      const int mu = mt*16 + lk*4 + reg;
      const int which = mu/C_, ho = mu%C_, h = ho/IH, o = ho%IH;
      __hip_bfloat16* dst = (which==0?qb:(which==1?kb:vb))
                            + (((size_t)n*H_+h)*T_+t)*D_ + o*V_;
      const float bb = bl[mu];
      dst[lc] = f2b(acc0[reg]+bb);
      if (lc < 9) dst[16+lc] = f2b(acc1[reg]+bb);
    }
  }
}

// ---------------- K5: flash causal MHA, register-tiled two-GEMM ----------------
#define TQ 64
#define TK 32
__global__ __launch_bounds__(256) void k_attn(
    const __hip_bfloat16* __restrict__ qb, const __hip_bfloat16* __restrict__ kb,
    const __hip_bfloat16* __restrict__ vb, __hip_bfloat16* __restrict__ oh)
{
  const int bx = blockIdx.x;
  const int nh = blockIdx.z*H_ + blockIdx.y;
  const int tid = threadIdx.x;
  __shared__ __align__(16) unsigned short Qt[200*TQ];  // [k][q] bf16
  __shared__ __align__(16) unsigned short Kt[200*TK];  // [k][key] bf16
  __shared__ __align__(16) float vl[TK*224];           // [key][d], zero-padded 200..223
  __shared__ __align__(16) unsigned short Pl[TK*TQ];   // [key][q] bf16
  __shared__ float frl[TQ];
  const __hip_bfloat16* qg_ = qb + (size_t)nh*T_*D_;
  const __hip_bfloat16* kg_ = kb + (size_t)nh*T_*D_;
  const __hip_bfloat16* vg_ = vb + (size_t)nh*T_*D_;
  __hip_bfloat16* og_ = oh + (size_t)nh*T_*D_;
  const float scale = 0.0707106781f;  // 1/sqrt(200)

  for (int i=tid;i<TK*24;i+=256) vl[(i/24)*224 + 200 + (i%24)] = 0.f;
  {
    const unsigned int* qsrc = (const unsigned int*)(qg_ + (size_t)bx*TQ*D_);
    for (int i=tid;i<TQ*100;i+=256){
      int row=i/100, w=i%100;
      unsigned int u = qsrc[i];
      Qt[(2*w)*TQ+row]   = (unsigned short)(u&0xffffu);
      Qt[(2*w+1)*TQ+row] = (unsigned short)(u>>16);
    }
  }
  const int qgS=(tid>>4)*4, kgS=(tid&15)*2;
  const int qpP=(tid>>3)*2, dgP=tid&7;
  float mloc[4], lloc[4];
  #pragma unroll
  for (int r=0;r<4;++r){ mloc[r]=-1e30f; lloc[r]=0.f; }
  float accA[28], accB[28];
  #pragma unroll
  for (int i=0;i<28;++i){ accA[i]=0.f; accB[i]=0.f; }

  const int ntiles = (bx==0)? 2 : 4;
  for (int kt=0; kt<ntiles; ++kt){
    const int j0 = kt*TK;
    __syncthreads();
    {
      const unsigned int* ksrc = (const unsigned int*)(kg_ + (size_t)j0*D_);
      const unsigned int* vsrc = (const unsigned int*)(vg_ + (size_t)j0*D_);
      for (int i=tid;i<TK*100;i+=256){
        int row=i/100, w=i%100;
        unsigned int uk = ksrc[i];
        Kt[(2*w)*TK+row]   = (unsigned short)(uk&0xffffu);
        Kt[(2*w+1)*TK+row] = (unsigned short)(uk>>16);
        unsigned int uv = vsrc[i];
        vl[row*224+2*w]   = ubl(uv);
        vl[row*224+2*w+1] = ubh(uv);
      }
    }
    __syncthreads();
    float sA[4][2];
    #pragma unroll
    for (int r=0;r<4;++r){ sA[r][0]=0.f; sA[r][1]=0.f; }
    #pragma unroll 2
    for (int k=0;k<200;++k){
      uint2 qw = *(const uint2*)(Qt + k*TQ + qgS);
      unsigned int kw = *(const unsigned int*)(Kt + k*TK + kgS);
      float qf0=ubl(qw.x), qf1=ubh(qw.x), qf2=ubl(qw.y), qf3=ubh(qw.y);
      float kf0=ubl(kw),  kf1=ubh(kw);
      sA[0][0]+=qf0*kf0; sA[0][1]+=qf0*kf1;
      sA[1][0]+=qf1*kf0; sA[1][1]+=qf1*kf1;
      sA[2][0]+=qf2*kf0; sA[2][1]+=qf2*kf1;
      sA[3][0]+=qf3*kf0; sA[3][1]+=qf3*kf1;
    }
    #pragma unroll
    for (int r=0;r<4;++r){
      const int qi = bx*TQ + qgS + r;
      float s0 = (j0+kgS   <= qi) ? sA[r][0]*scale : -1e30f;
      float s1 = (j0+kgS+1 <= qi) ? sA[r][1]*scale : -1e30f;
      float tm = fmaxf(s0,s1);
      #pragma unroll
      for (int off=1;off<16;off<<=1) tm = fmaxf(tm, __shfl_xor(tm, off));
      float mn = fmaxf(mloc[r], tm);
      float frv = __expf(mloc[r]-mn);
      float p0 = __expf(s0-mn), p1 = __expf(s1-mn);
      float ts = p0+p1;
      #pragma unroll
      for (int off=1;off<16;off<<=1) ts += __shfl_xor(ts, off);
      lloc[r] = lloc[r]*frv + ts;
      mloc[r] = mn;
      if ((tid&15)==0) frl[qgS+r] = frv;
      Pl[kgS*TQ + qgS + r]     = f2bu(p0);
      Pl[(kgS+1)*TQ + qgS + r] = f2bu(p1);
    }
    __syncthreads();
    {
      const float f0 = frl[qpP], f1 = frl[qpP+1];
      #pragma unroll
      for (int i=0;i<28;++i){ accA[i]*=f0; accB[i]*=f1; }
      for (int k=0;k<TK;++k){
        unsigned int pw = *(const unsigned int*)(Pl + k*TQ + qpP);
        float p0=ubl(pw), p1=ubh(pw);
        const float* vrow = vl + k*224 + dgP*4;
        #pragma unroll
        for (int i=0;i<7;++i){
          float4 vv = *(const float4*)(vrow + 32*i);
          accA[i*4+0]+=p0*vv.x; accA[i*4+1]+=p0*vv.y; accA[i*4+2]+=p0*vv.z; accA[i*4+3]+=p0*vv.w;
          accB[i*4+0]+=p1*vv.x; accB[i*4+1]+=p1*vv.y; accB[i*4+2]+=p1*vv.z; accB[i*4+3]+=p1*vv.w;
        }
      }
    }
  }
  __syncthreads();
  if ((tid&15)==0){
    #pragma unroll
    for (int r=0;r<4;++r) frl[qgS+r] = 1.f/lloc[r];
  }
  __syncthreads();
  {
    const float li0=frl[qpP], li1=frl[qpP+1];
    __hip_bfloat16* o0 = og_ + (size_t)(bx*TQ+qpP)*D_;
    __hip_bfloat16* o1 = o0 + D_;
    #pragma unroll
    for (int i=0;i<7;++i){
      if (i<6 || dgP<2){
        int d = dgP*4 + 32*i;
        __hip_bfloat162 h0a; h0a.x=f2b(accA[i*4+0]*li0); h0a.y=f2b(accA[i*4+1]*li0);
        __hip_bfloat162 h0b; h0b.x=f2b(accA[i*4+2]*li0); h0b.y=f2b(accA[i*4+3]*li0);
        __hip_bfloat162 h1a; h1a.x=f2b(accB[i*4+0]*li1); h1a.y=f2b(accB[i*4+1]*li1);
        __hip_bfloat162 h1b; h1b.x=f2b(accB[i*4+2]*li1); h1b.y=f2b(accB[i*4+3]*li1);
        *(__hip_bfloat162*)(o0+d)   = h0a;
        *(__hip_bfloat162*)(o0+d+2) = h0b;
        *(__hip_bfloat162*)(o1+d)   = h1a;
        *(__hip_bfloat162*)(o1+d+2) = h1b;
      }
    }
  }
}

// ---------------- K7: z=bn(oh)+xa; ffn; z2=relu+xa; z3=bn; out=relu(z3+x) ----------------
__global__ __launch_bounds__(256) void k_out(
    const __hip_bfloat16* __restrict__ oh, const __hip_bfloat16* __restrict__ xa,
    const float* __restrict__ x, const float* __restrict__ W_ffn,
    const float* __restrict__ b_ffn, const float* __restrict__ m_gamma,
    const float* __restrict__ m_beta, float* __restrict__ out)
{
  const int t=blockIdx.x, n=blockIdx.y, tid=threadIdx.x;
  __shared__ float zl[CV], xal[CV];
  __shared__ float wfl[C_*C_];
  const float invs=rsqrtf(1.f+EPSB);
  const __hip_bfloat16* xan = xa + (size_t)n*C_*T_*V_;
  for (int i=tid;i<C_*C_;i+=256) wfl[i]=W_ffn[i];
  for (int i=tid;i<CV;i+=256){
    int c=i/V_, v=i%V_;
    float xav=b2f(xan[(size_t)c*T_*V_+t*V_+v]);
    xal[i]=xav;
    int h=c/IH, o=c%IH;
    float ov=b2f(oh[(((size_t)n*H_+h)*T_+t)*D_ + o*V_ + v]);
    zl[i]=m_gamma[c]*invs*ov + m_beta[c] + xav;
  }
  __syncthreads();
  const float* xn = x + (size_t)n*C_*T_*V_;
  float* outn = out + (size_t)n*C_*T_*V_;
  for (int i=tid;i<CV;i+=256){
    int o=i/V_, v=i%V_;
    float acc=b_ffn[o];
    const float* wr = wfl + o*C_;
    #pragma unroll 8
    for (int c=0;c<C_;++c) acc += wr[c]*zl[c*V_+v];
    float z2=fmaxf(acc,0.f)+xal[i];
    float z3=m_gamma[o]*invs*z2 + m_beta[o];
    outn[(size_t)o*T_*V_+t*V_+v]=fmaxf(z3 + xn[(size_t)o*T_*V_+t*V_+v], 0.f);
  }
}

extern "C" void kernel_launch(void* const* d_in, const int* in_sizes, int n_in,
                              void* d_out, int out_size, void* d_ws, size_t ws_size,
                              hipStream_t stream) {
  const float* x      = (const float*)d_in[0];
  const float* A      = (const float*)d_in[1];
  const float* alphap = (const float*)d_in[2];
  const float* Wq     = (const float*)d_in[3];
  const float* bq     = (const float*)d_in[4];
  const float* Wk     = (const float*)d_in[5];
  const float* bk     = (const float*)d_in[6];
  const float* Wf     = (const float*)d_in[7];
  const float* bfp    = (const float*)d_in[8];
  const float* g_gamma= (const float*)d_in[9];
  const float* g_beta = (const float*)d_in[10];
  const float* W_sa   = (const float*)d_in[11];
  const float* b_sa   = (const float*)d_in[12];
  const float* W_ta   = (const float*)d_in[13];
  const float* b_ta   = (const float*)d_in[14];
  const float* W_fc1  = (const float*)d_in[15];
  const float* b_fc1  = (const float*)d_in[16];
  const float* W_fc2  = (const float*)d_in[17];
  const float* b_fc2  = (const float*)d_in[18];
  const float* pos_emb= (const float*)d_in[19];
  const float* Wq_h   = (const float*)d_in[20];
  const float* bq_h   = (const float*)d_in[21];
  const float* Wk_h   = (const float*)d_in[22];
  const float* bk_h   = (const float*)d_in[23];
  const float* Wv_h   = (const float*)d_in[24];
  const float* bv_h   = (const float*)d_in[25];
  const float* W_ffn  = (const float*)d_in[26];
  const float* b_ffn  = (const float*)d_in[27];
  const float* m_gamma= (const float*)d_in[28];
  const float* m_beta = (const float*)d_in[29];
  float* out = (float*)d_out;

  float* ws   = (float*)d_ws;
  float* Aad  = ws;                    // 128*3*625   = 240000
  float* seT  = Aad + 240000;          // 128*64*25   = 204800
  float* seV  = seT + 204800;          // 128*64*128  = 1048576
  float* sa   = seV + 1048576;         // 128*25      = 3200
  float* ta   = sa  + 3200;            // 128*128     = 16384
  float* ca   = ta  + 16384;           // 128*64      = 8192
  __hip_bfloat16* y1 = (__hip_bfloat16*)(ca + 8192);  // 26214400 elems (reused as oh)
  __hip_bfloat16* xa = y1 + (size_t)26214400;
  __hip_bfloat16* qb = xa + (size_t)26214400;
  __hip_bfloat16* kb = qb + (size_t)26214400;
  __hip_bfloat16* vb = kb + (size_t)26214400;
  __hip_bfloat16* oh = y1;  // reuse: y1 dead after k_xa_qkv
  float* attg = (float*)y1; // scratch before y1 is written

  k_gcn_att1<<<dim3(8, N_*S_), 256, 0, stream>>>(x, Wq, bq, Wk, bk, attg);
  k_gcn_att2<<<N_*S_, 256, 0, stream>>>(attg, A, alphap, Aad);
  k_gcn_y<<<dim3(T_, N_), 256, 0, stream>>>(x, Aad, Wf, bfp, g_gamma, g_beta, y1);
  k_seT<<<dim3(C_, N_), 256, 0, stream>>>(y1, seT);
  k_sa<<<N_, 64, 0, stream>>>(seT, W_sa, b_sa, sa);
  k_seV<<<dim3(C_, N_), 256, 0, stream>>>(y1, sa, seV);
  k_ta_ca<<<N_, 128, 0, stream>>>(seV, W_ta, b_ta, W_fc1, b_fc1, W_fc2, b_fc2, ta, ca);
  k_xa_qkv<<<dim3(T_, N_), 256, 0, stream>>>(y1, pos_emb, sa, ta, ca,
      Wq_h, bq_h, Wk_h, bk_h, Wv_h, bv_h, xa, qb, kb, vb);
  k_attn<<<dim3(2, H_, N_), 256, 0, stream>>>(qb, kb, vb, oh);
  k_out<<<dim3(T_, N_), 256, 0, stream>>>(oh, xa, x, W_ffn, b_ffn, m_gamma, m_beta, out);
}

// Round 5
// 1395.959 us; speedup vs baseline: 3.3999x; 1.2302x over previous
//
#include <hip/hip_runtime.h>
#include <hip/hip_bf16.h>

#define N_ 128
#define C_ 64
#define T_ 128
#define V_ 25
#define S_ 3
#define IG 16
#define IH 8
#define H_ 8
#define D_ 200   // IH*V
#define CV 1600  // C_*V_
#define TV 3200  // T_*V_
#define EPSB 1e-5f

typedef __attribute__((ext_vector_type(8))) short short8v;
typedef __attribute__((ext_vector_type(4))) float f32x4;
#define MFMA16 __builtin_amdgcn_mfma_f32_16x16x32_bf16

__device__ __forceinline__ float sigm(float x){ return 1.f/(1.f+expf(-x)); }
__device__ __forceinline__ float b2f(__hip_bfloat16 b){ return __bfloat162float(b); }
__device__ __forceinline__ __hip_bfloat16 f2b(float f){ return __float2bfloat16(f); }
__device__ __forceinline__ float ubl(unsigned int u){ return __uint_as_float(u<<16); }
__device__ __forceinline__ float ubh(unsigned int u){ return __uint_as_float(u & 0xffff0000u); }
__device__ __forceinline__ unsigned short f2bu(float f){
  unsigned int u = __float_as_uint(f);
  u += 0x7fff + ((u>>16)&1);
  return (unsigned short)(u>>16);
}
__device__ __forceinline__ unsigned long long pk4bf(f32x4 v){
  unsigned long long a = f2bu(v[0]);
  unsigned long long b = f2bu(v[1]);
  unsigned long long c = f2bu(v[2]);
  unsigned long long d = f2bu(v[3]);
  return a | (b<<16) | (c<<32) | (d<<48);
}

// ---------------- K1a: adaptive graph attention partials, chunked over t ----------------
__global__ __launch_bounds__(256) void k_gcn_att1(
    const float* __restrict__ x,
    const float* __restrict__ Wq, const float* __restrict__ bq,
    const float* __restrict__ Wk, const float* __restrict__ bk,
    float* __restrict__ attg)
{
  const int tc = blockIdx.x, ns = blockIdx.y, n = ns / S_, s = ns % S_;
  const int tid = threadIdx.x;
  __shared__ float xt[CV];
  __shared__ float wq_l[IG*C_], wk_l[IG*C_];
  __shared__ float qv[IG*V_], kv[IG*V_];
  __shared__ float att[V_*V_];
  for (int i=tid;i<IG*C_;i+=256){ wq_l[i]=Wq[s*IG*C_+i]; wk_l[i]=Wk[s*IG*C_+i]; }
  for (int i=tid;i<V_*V_;i+=256) att[i]=0.f;
  __syncthreads();
  const float* xn = x + (size_t)n*C_*T_*V_;
  const int t0 = tc*16;
  for (int t=t0;t<t0+16;++t){
    for (int i=tid;i<CV;i+=256) xt[i]=xn[(size_t)(i/V_)*T_*V_ + t*V_ + (i%V_)];
    __syncthreads();
    for (int i=tid;i<2*IG*V_;i+=256){
      int half=i/(IG*V_), r=i%(IG*V_), ii=r/V_, v=r%V_;
      const float* w = half?wk_l:wq_l;
      float acc = half? bk[s*IG+ii] : bq[s*IG+ii];
      #pragma unroll 8
      for (int c=0;c<C_;++c) acc += w[ii*C_+c]*xt[c*V_+v];
      (half?kv:qv)[r]=acc;
    }
    __syncthreads();
    for (int i=tid;i<V_*V_;i+=256){
      int v=i/V_, w=i%V_;
      float acc=0.f;
      #pragma unroll
      for (int ii=0;ii<IG;++ii) acc += qv[ii*V_+v]*kv[ii*V_+w];
      att[i]+=acc;
    }
    __syncthreads();
  }
  float* Ao = attg + ((size_t)tc*(N_*S_) + ns)*(V_*V_);
  for (int i=tid;i<V_*V_;i+=256) Ao[i]=att[i];
}

// ---------------- K1b: reduce chunks + softmax(dim=-2) + Aad ----------------
__global__ __launch_bounds__(256) void k_gcn_att2(
    const float* __restrict__ attg, const float* __restrict__ A,
    const float* __restrict__ alphap, float* __restrict__ Aad)
{
  const int ns = blockIdx.x, s = ns % S_, tid = threadIdx.x;
  __shared__ float att[V_*V_];
  for (int i=tid;i<V_*V_;i+=256){
    float acc=0.f;
    #pragma unroll
    for (int tc=0;tc<8;++tc) acc += attg[((size_t)tc*(N_*S_) + ns)*(V_*V_) + i];
    att[i]=acc;
  }
  __syncthreads();
  if (tid<V_){
    const int w=tid; const float inv=1.f/(IG*T_);
    float mx=-1e30f;
    for (int v=0;v<V_;++v) mx=fmaxf(mx, att[v*V_+w]*inv);
    float sum=0.f;
    for (int v=0;v<V_;++v){ float e=expf(att[v*V_+w]*inv-mx); att[v*V_+w]=e; sum+=e; }
    float rs=1.f/sum;
    for (int v=0;v<V_;++v) att[v*V_+w]*=rs;
  }
  __syncthreads();
  const float alpha=alphap[0];
  float* Ao = Aad + (size_t)ns*V_*V_;
  for (int i=tid;i<V_*V_;i+=256) Ao[i]=A[s*V_*V_+i]+alpha*att[i];
}

// ---------------- K2: MFMA graph conv + Wf + bn + residual + relu -> y1 (bf16) ----------------
__global__ __launch_bounds__(256) void k_gcn_y(
    const float* __restrict__ x, const float* __restrict__ Aad,
    const float* __restrict__ Wf, const float* __restrict__ bfp,
    const float* __restrict__ g_gamma, const float* __restrict__ g_beta,
    __hip_bfloat16* __restrict__ y1)
{
  const int t=blockIdx.x, n=blockIdx.y, tid=threadIdx.x;
  __shared__ __align__(16) short xtb[64*40];     // [c][v] pad40, v>=25 zeroed
  __shared__ __align__(16) short AsT[3*32*40];   // [s][w][v], v-pad zeroed
  __shared__ __align__(16) short Wt[64*200];     // [o][sc] sc=s*64+c
  __shared__ __align__(16) short aggT[32*200];   // [w][sc]
  const float* xn = x + (size_t)n*C_*T_*V_;
  for (int i=tid;i<CV;i+=256){
    int c=i/V_, v=i%V_;
    xtb[c*40+v] = (short)f2bu(xn[(size_t)c*T_*V_ + t*V_ + v]);
  }
  for (int i=tid;i<64*7;i+=256){ int c=i/7, v=25+(i%7); xtb[c*40+v]=0; }
  for (int i=tid;i<3*32*7;i+=256){ int sw=i/7, v=25+(i%7); AsT[sw*40+v]=0; }
  const float* Adn = Aad + (size_t)n*S_*V_*V_;
  for (int i=tid;i<S_*V_*V_;i+=256){
    int s=i/(V_*V_), r=i%(V_*V_), v=r/V_, w=r%V_;
    AsT[(s*32+w)*40+v] = (short)f2bu(Adn[i]);
  }
  for (int i=tid;i<64*192;i+=256){
    int o=i/192, sc=i%192, s=sc/64, c=sc%64;
    Wt[o*200+sc] = (short)f2bu(Wf[(size_t)s*C_*C_ + o*C_ + c]);
  }
  __syncthreads();
  const int wv = tid>>6, l = tid&63;
  const int lc = l&15, lk = l>>4;
  for (int s=0;s<S_;++s){
    short8v a = *(const short8v*)(xtb + (wv*16+lc)*40 + lk*8);
    short8v b0 = *(const short8v*)(AsT + (s*32+lc)*40 + lk*8);
    short8v b1 = *(const short8v*)(AsT + (s*32+16+lc)*40 + lk*8);
    f32x4 z = {0.f,0.f,0.f,0.f};
    f32x4 acc0 = MFMA16(a,b0,z,0,0,0);
    f32x4 acc1 = MFMA16(a,b1,z,0,0,0);
    *(unsigned long long*)(aggT + lc*200      + s*64 + wv*16 + lk*4) = pk4bf(acc0);
    *(unsigned long long*)(aggT + (16+lc)*200 + s*64 + wv*16 + lk*4) = pk4bf(acc1);
  }
  __syncthreads();
  f32x4 acc0 = {0.f,0.f,0.f,0.f}, acc1 = {0.f,0.f,0.f,0.f};
  #pragma unroll
  for (int ks=0;ks<6;++ks){
    short8v a  = *(const short8v*)(Wt + (wv*16+lc)*200 + ks*32 + lk*8);
    short8v b0 = *(const short8v*)(aggT + lc*200      + ks*32 + lk*8);
    short8v b1 = *(const short8v*)(aggT + (16+lc)*200 + ks*32 + lk*8);
    acc0 = MFMA16(a,b0,acc0,0,0,0);
    acc1 = MFMA16(a,b1,acc1,0,0,0);
  }
  const float invs = rsqrtf(1.f+EPSB);
  __hip_bfloat16* yo = y1 + (size_t)n*C_*T_*V_;
  #pragma unroll
  for (int reg=0;reg<4;++reg){
    const int o = wv*16 + lk*4 + reg;
    const float bsum = bfp[o]+bfp[C_+o]+bfp[2*C_+o];
    const float gs = g_gamma[o]*invs, gb = g_beta[o];
    {
      int w = lc;
      float val = (acc0[reg]+bsum)*gs + gb + xn[(size_t)o*T_*V_ + t*V_ + w];
      yo[(size_t)o*T_*V_ + t*V_ + w] = f2b(fmaxf(val,0.f));
    }
    if (lc < 9){
      int w = 16+lc;
      float val = (acc1[reg]+bsum)*gs + gb + xn[(size_t)o*T_*V_ + t*V_ + w];
      yo[(size_t)o*T_*V_ + t*V_ + w] = f2b(fmaxf(val,0.f));
    }
  }
}

// ---------------- K3a: seT[n,c,v] = mean_t y1 ----------------
__global__ __launch_bounds__(256) void k_seT(const __hip_bfloat16* __restrict__ y1,
    float* __restrict__ seT)
{
  const int c=blockIdx.x, n=blockIdx.y, tid=threadIdx.x;
  const int v = tid&31, g = tid>>5;
  __shared__ float red[8][33];
  const __hip_bfloat16* yp = y1 + ((size_t)n*C_+c)*T_*V_;
  float s=0.f;
  if (v < V_){
    #pragma unroll 4
    for (int j=0;j<16;++j){
      int t = g + j*8;
      s += b2f(yp[t*V_+v]);
    }
  }
  red[g][v]=s;
  __syncthreads();
  if (tid < V_){
    float tot=0.f;
    #pragma unroll
    for (int g2=0;g2<8;++g2) tot += red[g2][tid];
    seT[((size_t)n*C_+c)*V_+tid]=tot*(1.f/T_);
  }
}

// ---------------- K3b: sa[n,v] spatial gate ----------------
__global__ __launch_bounds__(64) void k_sa(const float* __restrict__ seT,
    const float* __restrict__ W_sa, const float* __restrict__ b_sa,
    float* __restrict__ sa)
{
  const int n=blockIdx.x, tid=threadIdx.x;
  if (tid>=V_) return;
  const float* se = seT + (size_t)n*C_*V_;
  float acc=b_sa[0];
  for (int c=0;c<C_;++c){
    #pragma unroll
    for (int k=0;k<V_;++k){
      int vv=tid+k-12;  // pad = (V-1)/2 = 12
      if (vv>=0&&vv<V_) acc+=se[c*V_+vv]*W_sa[c*V_+k];
    }
  }
  sa[n*V_+tid]=sigm(acc);
}

// ---------------- K3c: seV[n,c,t] = mean_v y1*(1+sa) ----------------
__global__ __launch_bounds__(256) void k_seV(const __hip_bfloat16* __restrict__ y1,
    const float* __restrict__ sa, float* __restrict__ seV)
{
  const int c=blockIdx.x, n=blockIdx.y, tid=threadIdx.x;
  const int v = tid&31, g = tid>>5;
  __shared__ float sal[32];
  if (tid<32) sal[tid] = (tid<V_)? 1.f+sa[n*V_+tid] : 0.f;
  __syncthreads();
  const __hip_bfloat16* yp = y1 + ((size_t)n*C_+c)*T_*V_;
  float* svo = seV + ((size_t)n*C_+c)*T_;
  const float sv_ = sal[v];
  for (int j=0;j<16;++j){
    int t = g*16 + j;
    float val = (v<V_)? b2f(yp[t*V_+v])*sv_ : 0.f;
    #pragma unroll
    for (int off=16;off;off>>=1) val += __shfl_xor(val, off);
    if (v==0) svo[t]=val*(1.f/V_);
  }
}

// ---------------- K3d: ta[n,t] temporal gate + ca[n,c] channel gate ----------------
__global__ __launch_bounds__(128) void k_ta_ca(const float* __restrict__ seV,
    const float* __restrict__ W_ta, const float* __restrict__ b_ta,
    const float* __restrict__ W_fc1, const float* __restrict__ b_fc1,
    const float* __restrict__ W_fc2, const float* __restrict__ b_fc2,
    float* __restrict__ ta, float* __restrict__ ca)
{
  const int n=blockIdx.x, tid=threadIdx.x;
  __shared__ float tal[T_];
  __shared__ float scl[C_];
  __shared__ float h1[32];
  const float* sv = seV + (size_t)n*C_*T_;
  {
    float acc=b_ta[0];
    for (int c=0;c<C_;++c){
      #pragma unroll
      for (int k=0;k<9;++k){
        int tt=tid+k-4;
        if (tt>=0&&tt<T_) acc+=sv[c*T_+tt]*W_ta[c*9+k];
      }
    }
    float s=sigm(acc);
    tal[tid]=s; ta[n*T_+tid]=s;
  }
  __syncthreads();
  if (tid<C_){
    float acc=0.f;
    for (int t=0;t<T_;++t) acc += sv[tid*T_+t]*(1.f+tal[t]);
    scl[tid]=acc*(1.f/T_);
  }
  __syncthreads();
  if (tid<32){
    float acc=b_fc1[tid];
    for (int c=0;c<C_;++c) acc += scl[c]*W_fc1[tid*C_+c];
    h1[tid]=fmaxf(acc,0.f);
  }
  __syncthreads();
  if (tid<C_){
    float acc=b_fc2[tid];
    for (int j=0;j<32;++j) acc += h1[j]*W_fc2[tid*32+j];
    ca[n*C_+tid]=sigm(acc);
  }
}

// ---------------- K4: MFMA xa/gates + q/k/v projections ----------------
__global__ __launch_bounds__(256) void k_xa_qkv(
    const __hip_bfloat16* __restrict__ y1, const float* __restrict__ pos_emb,
    const float* __restrict__ sa, const float* __restrict__ ta, const float* __restrict__ ca,
    const float* __restrict__ Wq_h, const float* __restrict__ bq_h,
    const float* __restrict__ Wk_h, const float* __restrict__ bk_h,
    const float* __restrict__ Wv_h, const float* __restrict__ bv_h,
    __hip_bfloat16* __restrict__ xa, __hip_bfloat16* __restrict__ qb,
    __hip_bfloat16* __restrict__ kb, __hip_bfloat16* __restrict__ vb)
{
  const int t=blockIdx.x, n=blockIdx.y, tid=threadIdx.x;
  __shared__ __align__(16) short w3[192*72];    // [mu][c], mu = which*64+ho
  __shared__ __align__(16) short xalT[32*72];   // [w][c]
  __shared__ float bl[192];
  for (int i=tid;i<192*64;i+=256){
    int mu=i/64, c=i%64, which=mu/C_, ho=mu%C_;
    const float* W = which==0?Wq_h:(which==1?Wk_h:Wv_h);
    w3[mu*72+c] = (short)f2bu(W[(size_t)ho*C_+c]);
  }
  if (tid<192){
    int which=tid/C_, ho=tid%C_;
    bl[tid] = (which==0?bq_h:(which==1?bk_h:bv_h))[ho];
  }
  const float tg = 1.f + ta[n*T_+t];
  const __hip_bfloat16* y1n = y1 + (size_t)n*C_*T_*V_;
  __hip_bfloat16* xan = xa + (size_t)n*C_*T_*V_;
  for (int i=tid;i<CV;i+=256){
    int c=i/V_, v=i%V_;
    float val = b2f(y1n[(size_t)c*T_*V_+t*V_+v]) * (1.f+sa[n*V_+v]) * tg * (1.f+ca[n*C_+c])
              + pos_emb[(size_t)t*CV + i];
    xan[(size_t)c*T_*V_+t*V_+v]=f2b(val);
    xalT[v*72+c] = (short)f2bu(val);
  }
  __syncthreads();
  const int wv=tid>>6, l=tid&63, lc=l&15, lk=l>>4;
  short8v bf_[2][2];
  #pragma unroll
  for (int ks=0;ks<2;++ks){
    bf_[ks][0] = *(const short8v*)(xalT + lc*72      + ks*32 + lk*8);
    bf_[ks][1] = *(const short8v*)(xalT + (16+lc)*72 + ks*32 + lk*8);
  }
  #pragma unroll
  for (int mt3=0;mt3<3;++mt3){
    const int mt = wv + mt3*4;
    f32x4 acc0 = {0.f,0.f,0.f,0.f}, acc1 = {0.f,0.f,0.f,0.f};
    #pragma unroll
    for (int ks=0;ks<2;++ks){
      short8v a = *(const short8v*)(w3 + (mt*16+lc)*72 + ks*32 + lk*8);
      acc0 = MFMA16(a, bf_[ks][0], acc0,0,0,0);
      acc1 = MFMA16(a, bf_[ks][1], acc1,0,0,0);
    }
    #pragma unroll
    for (int reg=0;reg<4;++reg){
      const int mu = mt*16 + lk*4 + reg;
      const int which = mu/C_, ho = mu%C_, h = ho/IH, o = ho%IH;
      __hip_bfloat16* dst = (which==0?qb:(which==1?kb:vb))
                            + (((size_t)n*H_+h)*T_+t)*D_ + o*V_;
      const float bb = bl[mu];
      dst[lc] = f2b(acc0[reg]+bb);
      if (lc < 9) dst[16+lc] = f2b(acc1[reg]+bb);
    }
  }
}

// ---------------- K5: MFMA flash causal MHA ----------------
// grid (2, H_, N_), 256 thr = 4 waves; wave owns 16 q rows.
// Q: global->register frags. K: LDS row-major [32][256] XOR-swizzled.
// V: LDS transposed VT[208][40]. P: per-wave Pl[64][40].
__global__ __launch_bounds__(256) void k_attn(
    const __hip_bfloat16* __restrict__ qb, const __hip_bfloat16* __restrict__ kb,
    const __hip_bfloat16* __restrict__ vb, __hip_bfloat16* __restrict__ oh)
{
  const int bx = blockIdx.x;
  const int nh = blockIdx.z*H_ + blockIdx.y;
  const int tid = threadIdx.x;
  const int wv = tid>>6, l = tid&63;
  const int lc = l&15, lg = l>>4;
  __shared__ __align__(16) char KlB[32*512];      // [key][d(256sh)] bf16, byte^=(key&7)<<4
  __shared__ __align__(16) short VT[208*40];      // [d][key] bf16
  __shared__ __align__(16) short Pl[64*40];       // [qloc][key] bf16 (per-wave slices)
  const __hip_bfloat16* qg_ = qb + (size_t)nh*T_*D_;
  const __hip_bfloat16* kg_ = kb + (size_t)nh*T_*D_;
  const __hip_bfloat16* vg_ = vb + (size_t)nh*T_*D_;
  __hip_bfloat16* og_ = oh + (size_t)nh*T_*D_;
  const float scale = 0.0707106781f;  // 1/sqrt(200)

  // one-time zeroing: K d-pad cols [200,224), VT rows [200,208)
  for (int i=tid;i<32*12;i+=256){
    int key=i/12, j=i%12;
    *(unsigned int*)(KlB + ((key*512 + 400 + j*4) ^ ((key&7)<<4))) = 0u;
  }
  for (int i=tid;i<8*40;i+=256) VT[200*40 + i] = 0;

  // Q fragments: wave wv covers q rows bx*64+wv*16 .. +15
  const int qrow = bx*64 + wv*16 + lc;
  short8v qf[7];
  {
    const short8v* qs8 = (const short8v*)(qg_ + (size_t)qrow*D_);
    #pragma unroll
    for (int ks=0;ks<7;++ks) qf[ks] = qs8[ks*4 + lg];  // d = ks*32+lg*8 (overread d>=200 hits zeroed K-pad)
  }
  f32x4 oacc[13];
  #pragma unroll
  for (int i=0;i<13;++i) oacc[i] = (f32x4){0.f,0.f,0.f,0.f};
  float m[4], lsm[4];
  #pragma unroll
  for (int r=0;r<4;++r){ m[r]=-1e30f; lsm[r]=0.f; }

  const int ntiles = (bx==0)? 2 : 4;
  for (int kt=0; kt<ntiles; ++kt){
    const int j0 = kt*32;
    __syncthreads();   // previous tile fully consumed (and init writes visible on kt=0)
    // ---- stage K (swizzled b128 writes) ----
    {
      const short8v* ks8 = (const short8v*)(kg_ + (size_t)j0*D_);
      for (int i=tid;i<32*25;i+=256){
        int row=i/25, w=i%25;
        *(short8v*)(KlB + ((row*512 + w*16) ^ ((row&7)<<4))) = ks8[i];
      }
      // ---- stage V transposed ----
      const short8v* vs8 = (const short8v*)(vg_ + (size_t)j0*D_);
      for (int i=tid;i<32*25;i+=256){
        int row=i&31, w4=i>>5;
        short8v u = vs8[row*25 + w4];
        #pragma unroll
        for (int j=0;j<8;++j) VT[(w4*8+j)*40 + row] = u[j];
      }
    }
    __syncthreads();
    const bool active = (j0 <= bx*64 + wv*16 + 15);
    if (active){
      // ---- S = Q K^T ----
      f32x4 s0 = {0.f,0.f,0.f,0.f}, s1 = {0.f,0.f,0.f,0.f};
      #pragma unroll
      for (int ks=0;ks<7;++ks){
        short8v b0 = *(const short8v*)(KlB + ((lc*512      + ks*64 + lg*16) ^ ((lc&7)<<4)));
        short8v b1 = *(const short8v*)(KlB + (((16+lc)*512 + ks*64 + lg*16) ^ ((lc&7)<<4)));
        s0 = MFMA16(qf[ks], b0, s0,0,0,0);
        s1 = MFMA16(qf[ks], b1, s1,0,0,0);
      }
      // ---- online softmax (row = wv*16 + lg*4 + r, keys across lc) ----
      float fr[4];
      #pragma unroll
      for (int r=0;r<4;++r){
        const int qg = bx*64 + wv*16 + lg*4 + r;
        float v0 = (j0+lc    <= qg) ? s0[r]*scale : -1e30f;
        float v1 = (j0+16+lc <= qg) ? s1[r]*scale : -1e30f;
        float mx = fmaxf(v0,v1);
        #pragma unroll
        for (int off=1;off<16;off<<=1) mx = fmaxf(mx, __shfl_xor(mx, off));
        float mn = fmaxf(m[r], mx);
        fr[r] = __expf(m[r]-mn);
        float p0 = __expf(v0-mn), p1 = __expf(v1-mn);
        float ts = p0+p1;
        #pragma unroll
        for (int off=1;off<16;off<<=1) ts += __shfl_xor(ts, off);
        lsm[r] = lsm[r]*fr[r] + ts;
        m[r] = mn;
        Pl[(wv*16 + lg*4 + r)*40 + lc]      = (short)f2bu(p0);
        Pl[(wv*16 + lg*4 + r)*40 + 16 + lc] = (short)f2bu(p1);
      }
      // rescale O accumulator
      #pragma unroll
      for (int dt=0;dt<13;++dt){
        #pragma unroll
        for (int r=0;r<4;++r) oacc[dt][r] *= fr[r];
      }
      // ---- PV ----
      short8v pa = *(const short8v*)(Pl + (wv*16+lc)*40 + lg*8);
      #pragma unroll
      for (int dt=0;dt<13;++dt){
        short8v b = *(const short8v*)(VT + (dt*16+lc)*40 + lg*8);
        oacc[dt] = MFMA16(pa, b, oacc[dt],0,0,0);
      }
    }
  }
  // ---- epilogue: normalize + store ----
  float rl[4];
  #pragma unroll
  for (int r=0;r<4;++r) rl[r] = 1.f/lsm[r];
  #pragma unroll
  for (int dt=0;dt<13;++dt){
    const int d = dt*16 + lc;
    if (d < D_){
      #pragma unroll
      for (int r=0;r<4;++r){
        const int q = bx*64 + wv*16 + lg*4 + r;
        og_[(size_t)q*D_ + d] = f2b(oacc[dt][r]*rl[r]);
      }
    }
  }
}

// ---------------- K7: z=bn(oh)+xa; ffn; z2=relu+xa; z3=bn; out=relu(z3+x) ----------------
__global__ __launch_bounds__(256) void k_out(
    const __hip_bfloat16* __restrict__ oh, const __hip_bfloat16* __restrict__ xa,
    const float* __restrict__ x, const float* __restrict__ W_ffn,
    const float* __restrict__ b_ffn, const float* __restrict__ m_gamma,
    const float* __restrict__ m_beta, float* __restrict__ out)
{
  const int t=blockIdx.x, n=blockIdx.y, tid=threadIdx.x;
  __shared__ float zl[CV], xal[CV];
  __shared__ float wfl[C_*C_];
  const float invs=rsqrtf(1.f+EPSB);
  const __hip_bfloat16* xan = xa + (size_t)n*C_*T_*V_;
  for (int i=tid;i<C_*C_;i+=256) wfl[i]=W_ffn[i];
  for (int i=tid;i<CV;i+=256){
    int c=i/V_, v=i%V_;
    float xav=b2f(xan[(size_t)c*T_*V_+t*V_+v]);
    xal[i]=xav;
    int h=c/IH, o=c%IH;
    float ov=b2f(oh[(((size_t)n*H_+h)*T_+t)*D_ + o*V_ + v]);
    zl[i]=m_gamma[c]*invs*ov + m_beta[c] + xav;
  }
  __syncthreads();
  const float* xn = x + (size_t)n*C_*T_*V_;
  float* outn = out + (size_t)n*C_*T_*V_;
  for (int i=tid;i<CV;i+=256){
    int o=i/V_, v=i%V_;
    float acc=b_ffn[o];
    const float* wr = wfl + o*C_;
    #pragma unroll 8
    for (int c=0;c<C_;++c) acc += wr[c]*zl[c*V_+v];
    float z2=fmaxf(acc,0.f)+xal[i];
    float z3=m_gamma[o]*invs*z2 + m_beta[o];
    outn[(size_t)o*T_*V_+t*V_+v]=fmaxf(z3 + xn[(size_t)o*T_*V_+t*V_+v], 0.f);
  }
}

extern "C" void kernel_launch(void* const* d_in, const int* in_sizes, int n_in,
                              void* d_out, int out_size, void* d_ws, size_t ws_size,
                              hipStream_t stream) {
  const float* x      = (const float*)d_in[0];
  const float* A      = (const float*)d_in[1];
  const float* alphap = (const float*)d_in[2];
  const float* Wq     = (const float*)d_in[3];
  const float* bq     = (const float*)d_in[4];
  const float* Wk     = (const float*)d_in[5];
  const float* bk     = (const float*)d_in[6];
  const float* Wf     = (const float*)d_in[7];
  const float* bfp    = (const float*)d_in[8];
  const float* g_gamma= (const float*)d_in[9];
  const float* g_beta = (const float*)d_in[10];
  const float* W_sa   = (const float*)d_in[11];
  const float* b_sa   = (const float*)d_in[12];
  const float* W_ta   = (const float*)d_in[13];
  const float* b_ta   = (const float*)d_in[14];
  const float* W_fc1  = (const float*)d_in[15];
  const float* b_fc1  = (const float*)d_in[16];
  const float* W_fc2  = (const float*)d_in[17];
  const float* b_fc2  = (const float*)d_in[18];
  const float* pos_emb= (const float*)d_in[19];
  const float* Wq_h   = (const float*)d_in[20];
  const float* bq_h   = (const float*)d_in[21];
  const float* Wk_h   = (const float*)d_in[22];
  const float* bk_h   = (const float*)d_in[23];
  const float* Wv_h   = (const float*)d_in[24];
  const float* bv_h   = (const float*)d_in[25];
  const float* W_ffn  = (const float*)d_in[26];
  const float* b_ffn  = (const float*)d_in[27];
  const float* m_gamma= (const float*)d_in[28];
  const float* m_beta = (const float*)d_in[29];
  float* out = (float*)d_out;

  float* ws   = (float*)d_ws;
  float* Aad  = ws;                    // 128*3*625   = 240000
  float* seT  = Aad + 240000;          // 128*64*25   = 204800
  float* seV  = seT + 204800;          // 128*64*128  = 1048576
  float* sa   = seV + 1048576;         // 128*25      = 3200
  float* ta   = sa  + 3200;            // 128*128     = 16384
  float* ca   = ta  + 16384;           // 128*64      = 8192
  __hip_bfloat16* y1 = (__hip_bfloat16*)(ca + 8192);  // 26214400 elems (reused as oh)
  __hip_bfloat16* xa = y1 + (size_t)26214400;
  __hip_bfloat16* qb = xa + (size_t)26214400;
  __hip_bfloat16* kb = qb + (size_t)26214400;
  __hip_bfloat16* vb = kb + (size_t)26214400;
  __hip_bfloat16* oh = y1;  // reuse: y1 dead after k_xa_qkv
  float* attg = (float*)y1; // scratch before y1 is written

  k_gcn_att1<<<dim3(8, N_*S_), 256, 0, stream>>>(x, Wq, bq, Wk, bk, attg);
  k_gcn_att2<<<N_*S_, 256, 0, stream>>>(attg, A, alphap, Aad);
  k_gcn_y<<<dim3(T_, N_), 256, 0, stream>>>(x, Aad, Wf, bfp, g_gamma, g_beta, y1);
  k_seT<<<dim3(C_, N_), 256, 0, stream>>>(y1, seT);
  k_sa<<<N_, 64, 0, stream>>>(seT, W_sa, b_sa, sa);
  k_seV<<<dim3(C_, N_), 256, 0, stream>>>(y1, sa, seV);
  k_ta_ca<<<N_, 128, 0, stream>>>(seV, W_ta, b_ta, W_fc1, b_fc1, W_fc2, b_fc2, ta, ca);
  k_xa_qkv<<<dim3(T_, N_), 256, 0, stream>>>(y1, pos_emb, sa, ta, ca,
      Wq_h, bq_h, Wk_h, bk_h, Wv_h, bv_h, xa, qb, kb, vb);
  k_attn<<<dim3(2, H_, N_), 256, 0, stream>>>(qb, kb, vb, oh);
  k_out<<<dim3(T_, N_), 256, 0, stream>>>(oh, xa, x, W_ffn, b_ffn, m_gamma, m_beta, out);
}

// Round 6
// 1100.119 us; speedup vs baseline: 4.3142x; 1.2689x over previous
//
#include <hip/hip_runtime.h>
#include <hip/hip_bf16.h>

#define N_ 128
#define C_ 64
#define T_ 128
#define V_ 25
#define S_ 3
#define IG 16
#define IH 8
#define H_ 8
#define D_ 200   // IH*V
#define CV 1600  // C_*V_
#define TV 3200  // T_*V_
#define EPSB 1e-5f
#define NCHUNK 16
#define TPC 8    // t per chunk

typedef __attribute__((ext_vector_type(8))) short short8v;
typedef __attribute__((ext_vector_type(4))) float f32x4;
#define MFMA16 __builtin_amdgcn_mfma_f32_16x16x32_bf16

__device__ __forceinline__ float sigm(float x){ return 1.f/(1.f+expf(-x)); }
__device__ __forceinline__ float b2f(__hip_bfloat16 b){ return __bfloat162float(b); }
__device__ __forceinline__ __hip_bfloat16 f2b(float f){ return __float2bfloat16(f); }
__device__ __forceinline__ float ubl(unsigned int u){ return __uint_as_float(u<<16); }
__device__ __forceinline__ float ubh(unsigned int u){ return __uint_as_float(u & 0xffff0000u); }
__device__ __forceinline__ unsigned short f2bu(float f){
  unsigned int u = __float_as_uint(f);
  u += 0x7fff + ((u>>16)&1);
  return (unsigned short)(u>>16);
}
__device__ __forceinline__ unsigned long long pk4bf(f32x4 v){
  unsigned long long a = f2bu(v[0]);
  unsigned long long b = f2bu(v[1]);
  unsigned long long c = f2bu(v[2]);
  unsigned long long d = f2bu(v[3]);
  return a | (b<<16) | (c<<32) | (d<<48);
}

// ---------------- K1a: MFMA adaptive graph attention partials ----------------
// grid (NCHUNK, N_*S_). Per chunk of 8 t's: per t, q_t=Wq@x_t, k_t=Wk@x_t via MFMA
// (wave per t, groups of 4); D-frags (+bias) -> QB/KB[32 v][128 K] bf16 XOR-swizzled;
// then att(25x25) += Q~ K~^T (2x2 tiles x 4 ksteps), one tile per wave.
__global__ __launch_bounds__(256) void k_gcn_att1(
    const float* __restrict__ x,
    const float* __restrict__ Wq, const float* __restrict__ bq,
    const float* __restrict__ Wk, const float* __restrict__ bk,
    float* __restrict__ attg)
{
  const int tc = blockIdx.x, ns = blockIdx.y, n = ns / S_, s = ns % S_;
  const int tid = threadIdx.x;
  const int wv = tid>>6, l = tid&63, lc = l&15, lk = l>>4;
  __shared__ __align__(16) short wql[16*72], wkl[16*72];
  __shared__ float bql[16], bkl[16];
  __shared__ __align__(16) short xtb[4*32*72];   // [tl][v(32)][c(72)], v>=25 zeroed
  __shared__ __align__(16) char QB[32*256];      // [v][K=128 bf16], byte^=(v&7)<<4
  __shared__ __align__(16) char KB[32*256];
  // stage weights bf16 (row stride 72 shorts)
  for (int i=tid;i<IG*C_;i+=256){
    int ii=i>>6, c=i&63;
    wql[ii*72+c] = (short)f2bu(Wq[s*IG*C_+i]);
    wkl[ii*72+c] = (short)f2bu(Wk[s*IG*C_+i]);
  }
  if (tid<16){ bql[tid]=bq[s*IG+tid]; bkl[tid]=bk[s*IG+tid]; }
  // zero xtb pad rows v=25..31 (contiguous 7*72 shorts per tl)
  for (int i=tid;i<4*7*72;i+=256){
    int tl=i/(7*72), r=i%(7*72);
    xtb[(tl*32+25)*72 + r] = 0;
  }
  const float* xn = x + (size_t)n*C_*T_*V_;
  const int t0 = tc*TPC;
  #pragma unroll
  for (int tg=0; tg<2; ++tg){
    __syncthreads();
    for (int i=tid;i<4*1600;i+=256){
      int tl=i/1600, r=i%1600, c=r/25, v=r%25;
      xtb[(tl*32+v)*72 + c] = (short)f2bu(xn[(size_t)c*TV + (t0+tg*4+tl)*V_ + v]);
    }
    __syncthreads();
    // projection: wave wv handles t_local = tg*4+wv
    const int tcol = (tg*4+wv)*32;   // byte base of this t's 16 K-cols
    f32x4 z={0.f,0.f,0.f,0.f};
    f32x4 aq0=z,aq1=z,ak0=z,ak1=z;
    #pragma unroll
    for (int ks=0;ks<2;++ks){
      short8v aq = *(const short8v*)(wql + lc*72 + ks*32 + lk*8);
      short8v ak = *(const short8v*)(wkl + lc*72 + ks*32 + lk*8);
      short8v b0 = *(const short8v*)(xtb + (wv*32+lc)*72 + ks*32 + lk*8);
      short8v b1 = *(const short8v*)(xtb + (wv*32+16+lc)*72 + ks*32 + lk*8);
      aq0 = MFMA16(aq,b0,aq0,0,0,0);
      aq1 = MFMA16(aq,b1,aq1,0,0,0);
      ak0 = MFMA16(ak,b0,ak0,0,0,0);
      ak1 = MFMA16(ak,b1,ak1,0,0,0);
    }
    // add bias (per ii = lk*4+reg), pack to bf16, swizzled b64 writes
    f32x4 q0,q1,k0,k1;
    #pragma unroll
    for (int r=0;r<4;++r){
      float bqv = bql[lk*4+r], bkv = bkl[lk*4+r];
      q0[r]=aq0[r]+bqv; q1[r]=aq1[r]+bqv;
      k0[r]=ak0[r]+bkv; k1[r]=ak1[r]+bkv;
    }
    const int sw = (lc&7)<<4;
    *(unsigned long long*)(QB + ((lc*256      + tcol + lk*8) ^ sw)) = pk4bf(q0);
    *(unsigned long long*)(QB + (((16+lc)*256 + tcol + lk*8) ^ sw)) = pk4bf(q1);
    *(unsigned long long*)(KB + ((lc*256      + tcol + lk*8) ^ sw)) = pk4bf(k0);
    *(unsigned long long*)(KB + (((16+lc)*256 + tcol + lk*8) ^ sw)) = pk4bf(k1);
  }
  __syncthreads();
  // att tile per wave: (mt,nt)
  const int mt = wv>>1, nt = wv&1;
  const int sw = (lc&7)<<4;
  f32x4 acc = {0.f,0.f,0.f,0.f};
  #pragma unroll
  for (int ks=0;ks<4;++ks){
    short8v a = *(const short8v*)(QB + (((mt*16+lc)*256 + ks*64 + lk*16) ^ sw));
    short8v b = *(const short8v*)(KB + (((nt*16+lc)*256 + ks*64 + lk*16) ^ sw));
    acc = MFMA16(a,b,acc,0,0,0);
  }
  float* Ao = attg + ((size_t)tc*(N_*S_) + ns)*(V_*V_);
  #pragma unroll
  for (int reg=0;reg<4;++reg){
    int v = mt*16 + lk*4 + reg, w = nt*16 + lc;
    if (v<V_ && w<V_) Ao[v*V_+w] = acc[reg];
  }
}

// ---------------- K1b: reduce chunks + softmax(dim=-2) + Aad ----------------
__global__ __launch_bounds__(256) void k_gcn_att2(
    const float* __restrict__ attg, const float* __restrict__ A,
    const float* __restrict__ alphap, float* __restrict__ Aad)
{
  const int ns = blockIdx.x, s = ns % S_, tid = threadIdx.x;
  __shared__ float att[V_*V_];
  for (int i=tid;i<V_*V_;i+=256){
    float acc=0.f;
    #pragma unroll
    for (int tcc=0;tcc<NCHUNK;++tcc) acc += attg[((size_t)tcc*(N_*S_) + ns)*(V_*V_) + i];
    att[i]=acc;
  }
  __syncthreads();
  if (tid<V_){
    const int w=tid; const float inv=1.f/(IG*T_);
    float mx=-1e30f;
    for (int v=0;v<V_;++v) mx=fmaxf(mx, att[v*V_+w]*inv);
    float sum=0.f;
    for (int v=0;v<V_;++v){ float e=expf(att[v*V_+w]*inv-mx); att[v*V_+w]=e; sum+=e; }
    float rs=1.f/sum;
    for (int v=0;v<V_;++v) att[v*V_+w]*=rs;
  }
  __syncthreads();
  const float alpha=alphap[0];
  float* Ao = Aad + (size_t)ns*V_*V_;
  for (int i=tid;i<V_*V_;i+=256) Ao[i]=A[s*V_*V_+i]+alpha*att[i];
}

// ---------------- K2: MFMA graph conv + Wf + bn + residual + relu -> y1 (bf16) ----------------
__global__ __launch_bounds__(256) void k_gcn_y(
    const float* __restrict__ x, const float* __restrict__ Aad,
    const float* __restrict__ Wf, const float* __restrict__ bfp,
    const float* __restrict__ g_gamma, const float* __restrict__ g_beta,
    __hip_bfloat16* __restrict__ y1)
{
  const int t=blockIdx.x, n=blockIdx.y, tid=threadIdx.x;
  __shared__ __align__(16) short xtb[64*40];     // [c][v] pad40, v>=25 zeroed
  __shared__ __align__(16) short AsT[3*32*40];   // [s][w][v], v-pad zeroed
  __shared__ __align__(16) short Wt[64*200];     // [o][sc] sc=s*64+c
  __shared__ __align__(16) short aggT[32*200];   // [w][sc]
  const float* xn = x + (size_t)n*C_*T_*V_;
  for (int i=tid;i<CV;i+=256){
    int c=i/V_, v=i%V_;
    xtb[c*40+v] = (short)f2bu(xn[(size_t)c*T_*V_ + t*V_ + v]);
  }
  for (int i=tid;i<64*7;i+=256){ int c=i/7, v=25+(i%7); xtb[c*40+v]=0; }
  for (int i=tid;i<3*32*7;i+=256){ int sw=i/7, v=25+(i%7); AsT[sw*40+v]=0; }
  const float* Adn = Aad + (size_t)n*S_*V_*V_;
  for (int i=tid;i<S_*V_*V_;i+=256){
    int s=i/(V_*V_), r=i%(V_*V_), v=r/V_, w=r%V_;
    AsT[(s*32+w)*40+v] = (short)f2bu(Adn[i]);
  }
  for (int i=tid;i<64*192;i+=256){
    int o=i/192, sc=i%192, s=sc/64, c=sc%64;
    Wt[o*200+sc] = (short)f2bu(Wf[(size_t)s*C_*C_ + o*C_ + c]);
  }
  __syncthreads();
  const int wv = tid>>6, l = tid&63;
  const int lc = l&15, lk = l>>4;
  for (int s=0;s<S_;++s){
    short8v a = *(const short8v*)(xtb + (wv*16+lc)*40 + lk*8);
    short8v b0 = *(const short8v*)(AsT + (s*32+lc)*40 + lk*8);
    short8v b1 = *(const short8v*)(AsT + (s*32+16+lc)*40 + lk*8);
    f32x4 z = {0.f,0.f,0.f,0.f};
    f32x4 acc0 = MFMA16(a,b0,z,0,0,0);
    f32x4 acc1 = MFMA16(a,b1,z,0,0,0);
    *(unsigned long long*)(aggT + lc*200      + s*64 + wv*16 + lk*4) = pk4bf(acc0);
    *(unsigned long long*)(aggT + (16+lc)*200 + s*64 + wv*16 + lk*4) = pk4bf(acc1);
  }
  __syncthreads();
  f32x4 acc0 = {0.f,0.f,0.f,0.f}, acc1 = {0.f,0.f,0.f,0.f};
  #pragma unroll
  for (int ks=0;ks<6;++ks){
    short8v a  = *(const short8v*)(Wt + (wv*16+lc)*200 + ks*32 + lk*8);
    short8v b0 = *(const short8v*)(aggT + lc*200      + ks*32 + lk*8);
    short8v b1 = *(const short8v*)(aggT + (16+lc)*200 + ks*32 + lk*8);
    acc0 = MFMA16(a,b0,acc0,0,0,0);
    acc1 = MFMA16(a,b1,acc1,0,0,0);
  }
  const float invs = rsqrtf(1.f+EPSB);
  __hip_bfloat16* yo = y1 + (size_t)n*C_*T_*V_;
  #pragma unroll
  for (int reg=0;reg<4;++reg){
    const int o = wv*16 + lk*4 + reg;
    const float bsum = bfp[o]+bfp[C_+o]+bfp[2*C_+o];
    const float gs = g_gamma[o]*invs, gb = g_beta[o];
    {
      int w = lc;
      float val = (acc0[reg]+bsum)*gs + gb + xn[(size_t)o*T_*V_ + t*V_ + w];
      yo[(size_t)o*T_*V_ + t*V_ + w] = f2b(fmaxf(val,0.f));
    }
    if (lc < 9){
      int w = 16+lc;
      float val = (acc1[reg]+bsum)*gs + gb + xn[(size_t)o*T_*V_ + t*V_ + w];
      yo[(size_t)o*T_*V_ + t*V_ + w] = f2b(fmaxf(val,0.f));
    }
  }
}

// ---------------- K3a: seT[n,c,v] = mean_t y1 ----------------
__global__ __launch_bounds__(256) void k_seT(const __hip_bfloat16* __restrict__ y1,
    float* __restrict__ seT)
{
  const int c=blockIdx.x, n=blockIdx.y, tid=threadIdx.x;
  const int v = tid&31, g = tid>>5;
  __shared__ float red[8][33];
  const __hip_bfloat16* yp = y1 + ((size_t)n*C_+c)*T_*V_;
  float s=0.f;
  if (v < V_){
    #pragma unroll 4
    for (int j=0;j<16;++j){
      int t = g + j*8;
      s += b2f(yp[t*V_+v]);
    }
  }
  red[g][v]=s;
  __syncthreads();
  if (tid < V_){
    float tot=0.f;
    #pragma unroll
    for (int g2=0;g2<8;++g2) tot += red[g2][tid];
    seT[((size_t)n*C_+c)*V_+tid]=tot*(1.f/T_);
  }
}

// ---------------- K3b: sa[n,v] spatial gate ----------------
__global__ __launch_bounds__(64) void k_sa(const float* __restrict__ seT,
    const float* __restrict__ W_sa, const float* __restrict__ b_sa,
    float* __restrict__ sa)
{
  const int n=blockIdx.x, tid=threadIdx.x;
  if (tid>=V_) return;
  const float* se = seT + (size_t)n*C_*V_;
  float acc=b_sa[0];
  for (int c=0;c<C_;++c){
    #pragma unroll
    for (int k=0;k<V_;++k){
      int vv=tid+k-12;  // pad = (V-1)/2 = 12
      if (vv>=0&&vv<V_) acc+=se[c*V_+vv]*W_sa[c*V_+k];
    }
  }
  sa[n*V_+tid]=sigm(acc);
}

// ---------------- K3c: seV[n,c,t] = mean_v y1*(1+sa) ----------------
__global__ __launch_bounds__(256) void k_seV(const __hip_bfloat16* __restrict__ y1,
    const float* __restrict__ sa, float* __restrict__ seV)
{
  const int c=blockIdx.x, n=blockIdx.y, tid=threadIdx.x;
  const int v = tid&31, g = tid>>5;
  __shared__ float sal[32];
  if (tid<32) sal[tid] = (tid<V_)? 1.f+sa[n*V_+tid] : 0.f;
  __syncthreads();
  const __hip_bfloat16* yp = y1 + ((size_t)n*C_+c)*T_*V_;
  float* svo = seV + ((size_t)n*C_+c)*T_;
  const float sv_ = sal[v];
  for (int j=0;j<16;++j){
    int t = g*16 + j;
    float val = (v<V_)? b2f(yp[t*V_+v])*sv_ : 0.f;
    #pragma unroll
    for (int off=16;off;off>>=1) val += __shfl_xor(val, off);
    if (v==0) svo[t]=val*(1.f/V_);
  }
}

// ---------------- K3d: ta[n,t] temporal gate + ca[n,c] channel gate ----------------
__global__ __launch_bounds__(128) void k_ta_ca(const float* __restrict__ seV,
    const float* __restrict__ W_ta, const float* __restrict__ b_ta,
    const float* __restrict__ W_fc1, const float* __restrict__ b_fc1,
    const float* __restrict__ W_fc2, const float* __restrict__ b_fc2,
    float* __restrict__ ta, float* __restrict__ ca)
{
  const int n=blockIdx.x, tid=threadIdx.x;
  __shared__ float tal[T_];
  __shared__ float scl[C_];
  __shared__ float h1[32];
  const float* sv = seV + (size_t)n*C_*T_;
  {
    float acc=b_ta[0];
    for (int c=0;c<C_;++c){
      #pragma unroll
      for (int k=0;k<9;++k){
        int tt=tid+k-4;
        if (tt>=0&&tt<T_) acc+=sv[c*T_+tt]*W_ta[c*9+k];
      }
    }
    float s=sigm(acc);
    tal[tid]=s; ta[n*T_+tid]=s;
  }
  __syncthreads();
  if (tid<C_){
    float acc=0.f;
    for (int t=0;t<T_;++t) acc += sv[tid*T_+t]*(1.f+tal[t]);
    scl[tid]=acc*(1.f/T_);
  }
  __syncthreads();
  if (tid<32){
    float acc=b_fc1[tid];
    for (int c=0;c<C_;++c) acc += scl[c]*W_fc1[tid*C_+c];
    h1[tid]=fmaxf(acc,0.f);
  }
  __syncthreads();
  if (tid<C_){
    float acc=b_fc2[tid];
    for (int j=0;j<32;++j) acc += h1[j]*W_fc2[tid*32+j];
    ca[n*C_+tid]=sigm(acc);
  }
}

// ---------------- K4: MFMA xa/gates + q/k/v projections ----------------
__global__ __launch_bounds__(256) void k_xa_qkv(
    const __hip_bfloat16* __restrict__ y1, const float* __restrict__ pos_emb,
    const float* __restrict__ sa, const float* __restrict__ ta, const float* __restrict__ ca,
    const float* __restrict__ Wq_h, const float* __restrict__ bq_h,
    const float* __restrict__ Wk_h, const float* __restrict__ bk_h,
    const float* __restrict__ Wv_h, const float* __restrict__ bv_h,
    __hip_bfloat16* __restrict__ xa, __hip_bfloat16* __restrict__ qb,
    __hip_bfloat16* __restrict__ kb, __hip_bfloat16* __restrict__ vb)
{
  const int t=blockIdx.x, n=blockIdx.y, tid=threadIdx.x;
  __shared__ __align__(16) short w3[192*72];    // [mu][c], mu = which*64+ho
  __shared__ __align__(16) short xalT[32*72];   // [w][c]
  __shared__ float bl[192];
  for (int i=tid;i<192*64;i+=256){
    int mu=i/64, c=i%64, which=mu/C_, ho=mu%C_;
    const float* W = which==0?Wq_h:(which==1?Wk_h:Wv_h);
    w3[mu*72+c] = (short)f2bu(W[(size_t)ho*C_+c]);
  }
  if (tid<192){
    int which=tid/C_, ho=tid%C_;
    bl[tid] = (which==0?bq_h:(which==1?bk_h:bv_h))[ho];
  }
  const float tg = 1.f + ta[n*T_+t];
  const __hip_bfloat16* y1n = y1 + (size_t)n*C_*T_*V_;
  __hip_bfloat16* xan = xa + (size_t)n*C_*T_*V_;
  for (int i=tid;i<CV;i+=256){
    int c=i/V_, v=i%V_;
    float val = b2f(y1n[(size_t)c*T_*V_+t*V_+v]) * (1.f+sa[n*V_+v]) * tg * (1.f+ca[n*C_+c])
              + pos_emb[(size_t)t*CV + i];
    xan[(size_t)c*T_*V_+t*V_+v]=f2b(val);
    xalT[v*72+c] = (short)f2bu(val);
  }
  __syncthreads();
  const int wv=tid>>6, l=tid&63, lc=l&15, lk=l>>4;
  short8v bf_[2][2];
  #pragma unroll
  for (int ks=0;ks<2;++ks){
    bf_[ks][0] = *(const short8v*)(xalT + lc*72      + ks*32 + lk*8);
    bf_[ks][1] = *(const short8v*)(xalT + (16+lc)*72 + ks*32 + lk*8);
  }
  #pragma unroll
  for (int mt3=0;mt3<3;++mt3){
    const int mt = wv + mt3*4;
    f32x4 acc0 = {0.f,0.f,0.f,0.f}, acc1 = {0.f,0.f,0.f,0.f};
    #pragma unroll
    for (int ks=0;ks<2;++ks){
      short8v a = *(const short8v*)(w3 + (mt*16+lc)*72 + ks*32 + lk*8);
      acc0 = MFMA16(a, bf_[ks][0], acc0,0,0,0);
      acc1 = MFMA16(a, bf_[ks][1], acc1,0,0,0);
    }
    #pragma unroll
    for (int reg=0;reg<4;++reg){
      const int mu = mt*16 + lk*4 + reg;
      const int which = mu/C_, ho = mu%C_, h = ho/IH, o = ho%IH;
      __hip_bfloat16* dst = (which==0?qb:(which==1?kb:vb))
                            + (((size_t)n*H_+h)*T_+t)*D_ + o*V_;
      const float bb = bl[mu];
      dst[lc] = f2b(acc0[reg]+bb);
      if (lc < 9) dst[16+lc] = f2b(acc1[reg]+bb);
    }
  }
}

// ---------------- K5: MFMA flash causal MHA ----------------
// grid (2, H_, N_), 256 thr = 4 waves; wave owns 16 q rows.
__global__ __launch_bounds__(256) void k_attn(
    const __hip_bfloat16* __restrict__ qb, const __hip_bfloat16* __restrict__ kb,
    const __hip_bfloat16* __restrict__ vb, __hip_bfloat16* __restrict__ oh)
{
  const int bx = blockIdx.x;
  const int nh = blockIdx.z*H_ + blockIdx.y;
  const int tid = threadIdx.x;
  const int wv = tid>>6, l = tid&63;
  const int lc = l&15, lg = l>>4;
  __shared__ __align__(16) char KlB[32*512];      // [key][d(256sh)] bf16, byte^=(key&7)<<4
  __shared__ __align__(16) short VT[208*40];      // [d][key] bf16
  __shared__ __align__(16) short Pl[64*40];       // [qloc][key] bf16 (per-wave slices)
  const __hip_bfloat16* qg_ = qb + (size_t)nh*T_*D_;
  const __hip_bfloat16* kg_ = kb + (size_t)nh*T_*D_;
  const __hip_bfloat16* vg_ = vb + (size_t)nh*T_*D_;
  __hip_bfloat16* og_ = oh + (size_t)nh*T_*D_;
  const float scale = 0.0707106781f;  // 1/sqrt(200)

  for (int i=tid;i<32*12;i+=256){
    int key=i/12, j=i%12;
    *(unsigned int*)(KlB + ((key*512 + 400 + j*4) ^ ((key&7)<<4))) = 0u;
  }
  for (int i=tid;i<8*40;i+=256) VT[200*40 + i] = 0;

  const int qrow = bx*64 + wv*16 + lc;
  short8v qf[7];
  {
    const short8v* qs8 = (const short8v*)(qg_ + (size_t)qrow*D_);
    #pragma unroll
    for (int ks=0;ks<7;++ks) qf[ks] = qs8[ks*4 + lg];
  }
  f32x4 oacc[13];
  #pragma unroll
  for (int i=0;i<13;++i) oacc[i] = (f32x4){0.f,0.f,0.f,0.f};
  float m[4], lsm[4];
  #pragma unroll
  for (int r=0;r<4;++r){ m[r]=-1e30f; lsm[r]=0.f; }

  const int ntiles = (bx==0)? 2 : 4;
  for (int kt=0; kt<ntiles; ++kt){
    const int j0 = kt*32;
    __syncthreads();
    {
      const short8v* ks8 = (const short8v*)(kg_ + (size_t)j0*D_);
      for (int i=tid;i<32*25;i+=256){
        int row=i/25, w=i%25;
        *(short8v*)(KlB + ((row*512 + w*16) ^ ((row&7)<<4))) = ks8[i];
      }
      const short8v* vs8 = (const short8v*)(vg_ + (size_t)j0*D_);
      for (int i=tid;i<32*25;i+=256){
        int row=i&31, w4=i>>5;
        short8v u = vs8[row*25 + w4];
        #pragma unroll
        for (int j=0;j<8;++j) VT[(w4*8+j)*40 + row] = u[j];
      }
    }
    __syncthreads();
    const bool active = (j0 <= bx*64 + wv*16 + 15);
    if (active){
      f32x4 s0 = {0.f,0.f,0.f,0.f}, s1 = {0.f,0.f,0.f,0.f};
      #pragma unroll
      for (int ks=0;ks<7;++ks){
        short8v b0 = *(const short8v*)(KlB + ((lc*512      + ks*64 + lg*16) ^ ((lc&7)<<4)));
        short8v b1 = *(const short8v*)(KlB + (((16+lc)*512 + ks*64 + lg*16) ^ ((lc&7)<<4)));
        s0 = MFMA16(qf[ks], b0, s0,0,0,0);
        s1 = MFMA16(qf[ks], b1, s1,0,0,0);
      }
      float fr[4];
      #pragma unroll
      for (int r=0;r<4;++r){
        const int qg = bx*64 + wv*16 + lg*4 + r;
        float v0 = (j0+lc    <= qg) ? s0[r]*scale : -1e30f;
        float v1 = (j0+16+lc <= qg) ? s1[r]*scale : -1e30f;
        float mx = fmaxf(v0,v1);
        #pragma unroll
        for (int off=1;off<16;off<<=1) mx = fmaxf(mx, __shfl_xor(mx, off));
        float mn = fmaxf(m[r], mx);
        fr[r] = __expf(m[r]-mn);
        float p0 = __expf(v0-mn), p1 = __expf(v1-mn);
        float ts = p0+p1;
        #pragma unroll
        for (int off=1;off<16;off<<=1) ts += __shfl_xor(ts, off);
        lsm[r] = lsm[r]*fr[r] + ts;
        m[r] = mn;
        Pl[(wv*16 + lg*4 + r)*40 + lc]      = (short)f2bu(p0);
        Pl[(wv*16 + lg*4 + r)*40 + 16 + lc] = (short)f2bu(p1);
      }
      #pragma unroll
      for (int dt=0;dt<13;++dt){
        #pragma unroll
        for (int r=0;r<4;++r) oacc[dt][r] *= fr[r];
      }
      short8v pa = *(const short8v*)(Pl + (wv*16+lc)*40 + lg*8);
      #pragma unroll
      for (int dt=0;dt<13;++dt){
        short8v b = *(const short8v*)(VT + (dt*16+lc)*40 + lg*8);
        oacc[dt] = MFMA16(pa, b, oacc[dt],0,0,0);
      }
    }
  }
  float rl[4];
  #pragma unroll
  for (int r=0;r<4;++r) rl[r] = 1.f/lsm[r];
  #pragma unroll
  for (int dt=0;dt<13;++dt){
    const int d = dt*16 + lc;
    if (d < D_){
      #pragma unroll
      for (int r=0;r<4;++r){
        const int q = bx*64 + wv*16 + lg*4 + r;
        og_[(size_t)q*D_ + d] = f2b(oacc[dt][r]*rl[r]);
      }
    }
  }
}

// ---------------- K7: z=bn(oh)+xa; ffn; z2=relu+xa; z3=bn; out=relu(z3+x) ----------------
__global__ __launch_bounds__(256) void k_out(
    const __hip_bfloat16* __restrict__ oh, const __hip_bfloat16* __restrict__ xa,
    const float* __restrict__ x, const float* __restrict__ W_ffn,
    const float* __restrict__ b_ffn, const float* __restrict__ m_gamma,
    const float* __restrict__ m_beta, float* __restrict__ out)
{
  const int t=blockIdx.x, n=blockIdx.y, tid=threadIdx.x;
  __shared__ float zl[CV], xal[CV];
  __shared__ float wfl[C_*C_];
  const float invs=rsqrtf(1.f+EPSB);
  const __hip_bfloat16* xan = xa + (size_t)n*C_*T_*V_;
  for (int i=tid;i<C_*C_;i+=256) wfl[i]=W_ffn[i];
  for (int i=tid;i<CV;i+=256){
    int c=i/V_, v=i%V_;
    float xav=b2f(xan[(size_t)c*T_*V_+t*V_+v]);
    xal[i]=xav;
    int h=c/IH, o=c%IH;
    float ov=b2f(oh[(((size_t)n*H_+h)*T_+t)*D_ + o*V_ + v]);
    zl[i]=m_gamma[c]*invs*ov + m_beta[c] + xav;
  }
  __syncthreads();
  const float* xn = x + (size_t)n*C_*T_*V_;
  float* outn = out + (size_t)n*C_*T_*V_;
  for (int i=tid;i<CV;i+=256){
    int o=i/V_, v=i%V_;
    float acc=b_ffn[o];
    const float* wr = wfl + o*C_;
    #pragma unroll 8
    for (int c=0;c<C_;++c) acc += wr[c]*zl[c*V_+v];
    float z2=fmaxf(acc,0.f)+xal[i];
    float z3=m_gamma[o]*invs*z2 + m_beta[o];
    outn[(size_t)o*T_*V_+t*V_+v]=fmaxf(z3 + xn[(size_t)o*T_*V_+t*V_+v], 0.f);
  }
}

extern "C" void kernel_launch(void* const* d_in, const int* in_sizes, int n_in,
                              void* d_out, int out_size, void* d_ws, size_t ws_size,
                              hipStream_t stream) {
  const float* x      = (const float*)d_in[0];
  const float* A      = (const float*)d_in[1];
  const float* alphap = (const float*)d_in[2];
  const float* Wq     = (const float*)d_in[3];
  const float* bq     = (const float*)d_in[4];
  const float* Wk     = (const float*)d_in[5];
  const float* bk     = (const float*)d_in[6];
  const float* Wf     = (const float*)d_in[7];
  const float* bfp    = (const float*)d_in[8];
  const float* g_gamma= (const float*)d_in[9];
  const float* g_beta = (const float*)d_in[10];
  const float* W_sa   = (const float*)d_in[11];
  const float* b_sa   = (const float*)d_in[12];
  const float* W_ta   = (const float*)d_in[13];
  const float* b_ta   = (const float*)d_in[14];
  const float* W_fc1  = (const float*)d_in[15];
  const float* b_fc1  = (const float*)d_in[16];
  const float* W_fc2  = (const float*)d_in[17];
  const float* b_fc2  = (const float*)d_in[18];
  const float* pos_emb= (const float*)d_in[19];
  const float* Wq_h   = (const float*)d_in[20];
  const float* bq_h   = (const float*)d_in[21];
  const float* Wk_h   = (const float*)d_in[22];
  const float* bk_h   = (const float*)d_in[23];
  const float* Wv_h   = (const float*)d_in[24];
  const float* bv_h   = (const float*)d_in[25];
  const float* W_ffn  = (const float*)d_in[26];
  const float* b_ffn  = (const float*)d_in[27];
  const float* m_gamma= (const float*)d_in[28];
  const float* m_beta = (const float*)d_in[29];
  float* out = (float*)d_out;

  float* ws   = (float*)d_ws;
  float* Aad  = ws;                    // 128*3*625   = 240000
  float* seT  = Aad + 240000;          // 128*64*25   = 204800
  float* seV  = seT + 204800;          // 128*64*128  = 1048576
  float* sa   = seV + 1048576;         // 128*25      = 3200
  float* ta   = sa  + 3200;            // 128*128     = 16384
  float* ca   = ta  + 16384;           // 128*64      = 8192
  __hip_bfloat16* y1 = (__hip_bfloat16*)(ca + 8192);  // 26214400 elems (reused as oh)
  __hip_bfloat16* xa = y1 + (size_t)26214400;
  __hip_bfloat16* qb = xa + (size_t)26214400;
  __hip_bfloat16* kb = qb + (size_t)26214400;
  __hip_bfloat16* vb = kb + (size_t)26214400;
  __hip_bfloat16* oh = y1;  // reuse: y1 dead after k_xa_qkv
  float* attg = (float*)y1; // scratch before y1 is written (16*384*625*4 = 15.4MB)

  k_gcn_att1<<<dim3(NCHUNK, N_*S_), 256, 0, stream>>>(x, Wq, bq, Wk, bk, attg);
  k_gcn_att2<<<N_*S_, 256, 0, stream>>>(attg, A, alphap, Aad);
  k_gcn_y<<<dim3(T_, N_), 256, 0, stream>>>(x, Aad, Wf, bfp, g_gamma, g_beta, y1);
  k_seT<<<dim3(C_, N_), 256, 0, stream>>>(y1, seT);
  k_sa<<<N_, 64, 0, stream>>>(seT, W_sa, b_sa, sa);
  k_seV<<<dim3(C_, N_), 256, 0, stream>>>(y1, sa, seV);
  k_ta_ca<<<N_, 128, 0, stream>>>(seV, W_ta, b_ta, W_fc1, b_fc1, W_fc2, b_fc2, ta, ca);
  k_xa_qkv<<<dim3(T_, N_), 256, 0, stream>>>(y1, pos_emb, sa, ta, ca,
      Wq_h, bq_h, Wk_h, bk_h, Wv_h, bv_h, xa, qb, kb, vb);
  k_attn<<<dim3(2, H_, N_), 256, 0, stream>>>(qb, kb, vb, oh);
  k_out<<<dim3(T_, N_), 256, 0, stream>>>(oh, xa, x, W_ffn, b_ffn, m_gamma, m_beta, out);
}

// Round 7
// 982.155 us; speedup vs baseline: 4.8324x; 1.1201x over previous
//
#include <hip/hip_runtime.h>
#include <hip/hip_bf16.h>

#define N_ 128
#define C_ 64
#define T_ 128
#define V_ 25
#define S_ 3
#define IG 16
#define IH 8
#define H_ 8
#define D_ 200   // IH*V
#define CV 1600  // C_*V_
#define TV 3200  // T_*V_
#define EPSB 1e-5f
#define NCHUNK 16
#define TPC 8    // t per chunk

typedef __attribute__((ext_vector_type(8))) short short8v;
typedef __attribute__((ext_vector_type(4))) float f32x4;
#define MFMA16 __builtin_amdgcn_mfma_f32_16x16x32_bf16

__device__ __forceinline__ float sigm(float x){ return 1.f/(1.f+expf(-x)); }
__device__ __forceinline__ float b2f(__hip_bfloat16 b){ return __bfloat162float(b); }
__device__ __forceinline__ __hip_bfloat16 f2b(float f){ return __float2bfloat16(f); }
__device__ __forceinline__ float ubl(unsigned int u){ return __uint_as_float(u<<16); }
__device__ __forceinline__ float ubh(unsigned int u){ return __uint_as_float(u & 0xffff0000u); }
__device__ __forceinline__ unsigned short f2bu(float f){
  unsigned int u = __float_as_uint(f);
  u += 0x7fff + ((u>>16)&1);
  return (unsigned short)(u>>16);
}
__device__ __forceinline__ unsigned long long pk4bf(f32x4 v){
  unsigned long long a = f2bu(v[0]);
  unsigned long long b = f2bu(v[1]);
  unsigned long long c = f2bu(v[2]);
  unsigned long long d = f2bu(v[3]);
  return a | (b<<16) | (c<<32) | (d<<48);
}

// ---------------- K1a: MFMA adaptive graph attention partials ----------------
__global__ __launch_bounds__(256) void k_gcn_att1(
    const float* __restrict__ x,
    const float* __restrict__ Wq, const float* __restrict__ bq,
    const float* __restrict__ Wk, const float* __restrict__ bk,
    float* __restrict__ attg)
{
  const int tc = blockIdx.x, ns = blockIdx.y, n = ns / S_, s = ns % S_;
  const int tid = threadIdx.x;
  const int wv = tid>>6, l = tid&63, lc = l&15, lk = l>>4;
  __shared__ __align__(16) short wql[16*72], wkl[16*72];
  __shared__ float bql[16], bkl[16];
  __shared__ __align__(16) short xtb[4*32*72];   // [tl][v(32)][c(72)], v>=25 zeroed
  __shared__ __align__(16) char QB[32*256];      // [v][K=128 bf16], byte^=(v&7)<<4
  __shared__ __align__(16) char KB[32*256];
  for (int i=tid;i<IG*C_;i+=256){
    int ii=i>>6, c=i&63;
    wql[ii*72+c] = (short)f2bu(Wq[s*IG*C_+i]);
    wkl[ii*72+c] = (short)f2bu(Wk[s*IG*C_+i]);
  }
  if (tid<16){ bql[tid]=bq[s*IG+tid]; bkl[tid]=bk[s*IG+tid]; }
  for (int i=tid;i<4*7*72;i+=256){
    int tl=i/(7*72), r=i%(7*72);
    xtb[(tl*32+25)*72 + r] = 0;
  }
  const float* xn = x + (size_t)n*C_*T_*V_;
  const int t0 = tc*TPC;
  #pragma unroll
  for (int tg=0; tg<2; ++tg){
    __syncthreads();
    for (int i=tid;i<4*1600;i+=256){
      int tl=i/1600, r=i%1600, c=r/25, v=r%25;
      xtb[(tl*32+v)*72 + c] = (short)f2bu(xn[(size_t)c*TV + (t0+tg*4+tl)*V_ + v]);
    }
    __syncthreads();
    const int tcol = (tg*4+wv)*32;
    f32x4 z={0.f,0.f,0.f,0.f};
    f32x4 aq0=z,aq1=z,ak0=z,ak1=z;
    #pragma unroll
    for (int ks=0;ks<2;++ks){
      short8v aq = *(const short8v*)(wql + lc*72 + ks*32 + lk*8);
      short8v ak = *(const short8v*)(wkl + lc*72 + ks*32 + lk*8);
      short8v b0 = *(const short8v*)(xtb + (wv*32+lc)*72 + ks*32 + lk*8);
      short8v b1 = *(const short8v*)(xtb + (wv*32+16+lc)*72 + ks*32 + lk*8);
      aq0 = MFMA16(aq,b0,aq0,0,0,0);
      aq1 = MFMA16(aq,b1,aq1,0,0,0);
      ak0 = MFMA16(ak,b0,ak0,0,0,0);
      ak1 = MFMA16(ak,b1,ak1,0,0,0);
    }
    f32x4 q0,q1,k0,k1;
    #pragma unroll
    for (int r=0;r<4;++r){
      float bqv = bql[lk*4+r], bkv = bkl[lk*4+r];
      q0[r]=aq0[r]+bqv; q1[r]=aq1[r]+bqv;
      k0[r]=ak0[r]+bkv; k1[r]=ak1[r]+bkv;
    }
    const int sw = (lc&7)<<4;
    *(unsigned long long*)(QB + ((lc*256      + tcol + lk*8) ^ sw)) = pk4bf(q0);
    *(unsigned long long*)(QB + (((16+lc)*256 + tcol + lk*8) ^ sw)) = pk4bf(q1);
    *(unsigned long long*)(KB + ((lc*256      + tcol + lk*8) ^ sw)) = pk4bf(k0);
    *(unsigned long long*)(KB + (((16+lc)*256 + tcol + lk*8) ^ sw)) = pk4bf(k1);
  }
  __syncthreads();
  const int mt = wv>>1, nt = wv&1;
  const int sw = (lc&7)<<4;
  f32x4 acc = {0.f,0.f,0.f,0.f};
  #pragma unroll
  for (int ks=0;ks<4;++ks){
    short8v a = *(const short8v*)(QB + (((mt*16+lc)*256 + ks*64 + lk*16) ^ sw));
    short8v b = *(const short8v*)(KB + (((nt*16+lc)*256 + ks*64 + lk*16) ^ sw));
    acc = MFMA16(a,b,acc,0,0,0);
  }
  float* Ao = attg + ((size_t)tc*(N_*S_) + ns)*(V_*V_);
  #pragma unroll
  for (int reg=0;reg<4;++reg){
    int v = mt*16 + lk*4 + reg, w = nt*16 + lc;
    if (v<V_ && w<V_) Ao[v*V_+w] = acc[reg];
  }
}

// ---------------- K1b: reduce chunks + softmax(dim=-2) + Aad ----------------
__global__ __launch_bounds__(256) void k_gcn_att2(
    const float* __restrict__ attg, const float* __restrict__ A,
    const float* __restrict__ alphap, float* __restrict__ Aad)
{
  const int ns = blockIdx.x, s = ns % S_, tid = threadIdx.x;
  __shared__ float att[V_*V_];
  for (int i=tid;i<V_*V_;i+=256){
    float acc=0.f;
    #pragma unroll
    for (int tcc=0;tcc<NCHUNK;++tcc) acc += attg[((size_t)tcc*(N_*S_) + ns)*(V_*V_) + i];
    att[i]=acc;
  }
  __syncthreads();
  if (tid<V_){
    const int w=tid; const float inv=1.f/(IG*T_);
    float mx=-1e30f;
    for (int v=0;v<V_;++v) mx=fmaxf(mx, att[v*V_+w]*inv);
    float sum=0.f;
    for (int v=0;v<V_;++v){ float e=expf(att[v*V_+w]*inv-mx); att[v*V_+w]=e; sum+=e; }
    float rs=1.f/sum;
    for (int v=0;v<V_;++v) att[v*V_+w]*=rs;
  }
  __syncthreads();
  const float alpha=alphap[0];
  float* Ao = Aad + (size_t)ns*V_*V_;
  for (int i=tid;i<V_*V_;i+=256) Ao[i]=A[s*V_*V_+i]+alpha*att[i];
}

// ---------------- K2: MFMA graph conv + Wf + bn + residual + relu -> y1 (bf16) ----------------
__global__ __launch_bounds__(256) void k_gcn_y(
    const float* __restrict__ x, const float* __restrict__ Aad,
    const float* __restrict__ Wf, const float* __restrict__ bfp,
    const float* __restrict__ g_gamma, const float* __restrict__ g_beta,
    __hip_bfloat16* __restrict__ y1)
{
  const int t=blockIdx.x, n=blockIdx.y, tid=threadIdx.x;
  __shared__ __align__(16) short xtb[64*40];     // [c][v] pad40, v>=25 zeroed
  __shared__ __align__(16) short AsT[3*32*40];   // [s][w][v], v-pad zeroed
  __shared__ __align__(16) short Wt[64*200];     // [o][sc] sc=s*64+c
  __shared__ __align__(16) short aggT[32*200];   // [w][sc]
  const float* xn = x + (size_t)n*C_*T_*V_;
  for (int i=tid;i<CV;i+=256){
    int c=i/V_, v=i%V_;
    xtb[c*40+v] = (short)f2bu(xn[(size_t)c*T_*V_ + t*V_ + v]);
  }
  for (int i=tid;i<64*7;i+=256){ int c=i/7, v=25+(i%7); xtb[c*40+v]=0; }
  for (int i=tid;i<3*32*7;i+=256){ int sw=i/7, v=25+(i%7); AsT[sw*40+v]=0; }
  const float* Adn = Aad + (size_t)n*S_*V_*V_;
  for (int i=tid;i<S_*V_*V_;i+=256){
    int s=i/(V_*V_), r=i%(V_*V_), v=r/V_, w=r%V_;
    AsT[(s*32+w)*40+v] = (short)f2bu(Adn[i]);
  }
  for (int i=tid;i<64*192;i+=256){
    int o=i/192, sc=i%192, s=sc/64, c=sc%64;
    Wt[o*200+sc] = (short)f2bu(Wf[(size_t)s*C_*C_ + o*C_ + c]);
  }
  __syncthreads();
  const int wv = tid>>6, l = tid&63;
  const int lc = l&15, lk = l>>4;
  for (int s=0;s<S_;++s){
    short8v a = *(const short8v*)(xtb + (wv*16+lc)*40 + lk*8);
    short8v b0 = *(const short8v*)(AsT + (s*32+lc)*40 + lk*8);
    short8v b1 = *(const short8v*)(AsT + (s*32+16+lc)*40 + lk*8);
    f32x4 z = {0.f,0.f,0.f,0.f};
    f32x4 acc0 = MFMA16(a,b0,z,0,0,0);
    f32x4 acc1 = MFMA16(a,b1,z,0,0,0);
    *(unsigned long long*)(aggT + lc*200      + s*64 + wv*16 + lk*4) = pk4bf(acc0);
    *(unsigned long long*)(aggT + (16+lc)*200 + s*64 + wv*16 + lk*4) = pk4bf(acc1);
  }
  __syncthreads();
  f32x4 acc0 = {0.f,0.f,0.f,0.f}, acc1 = {0.f,0.f,0.f,0.f};
  #pragma unroll
  for (int ks=0;ks<6;++ks){
    short8v a  = *(const short8v*)(Wt + (wv*16+lc)*200 + ks*32 + lk*8);
    short8v b0 = *(const short8v*)(aggT + lc*200      + ks*32 + lk*8);
    short8v b1 = *(const short8v*)(aggT + (16+lc)*200 + ks*32 + lk*8);
    acc0 = MFMA16(a,b0,acc0,0,0,0);
    acc1 = MFMA16(a,b1,acc1,0,0,0);
  }
  const float invs = rsqrtf(1.f+EPSB);
  __hip_bfloat16* yo = y1 + (size_t)n*C_*T_*V_;
  #pragma unroll
  for (int reg=0;reg<4;++reg){
    const int o = wv*16 + lk*4 + reg;
    const float bsum = bfp[o]+bfp[C_+o]+bfp[2*C_+o];
    const float gs = g_gamma[o]*invs, gb = g_beta[o];
    {
      int w = lc;
      float val = (acc0[reg]+bsum)*gs + gb + xn[(size_t)o*T_*V_ + t*V_ + w];
      yo[(size_t)o*T_*V_ + t*V_ + w] = f2b(fmaxf(val,0.f));
    }
    if (lc < 9){
      int w = 16+lc;
      float val = (acc1[reg]+bsum)*gs + gb + xn[(size_t)o*T_*V_ + t*V_ + w];
      yo[(size_t)o*T_*V_ + t*V_ + w] = f2b(fmaxf(val,0.f));
    }
  }
}

// ---------------- K3a: seT[n,c,v] = mean_t y1 ----------------
__global__ __launch_bounds__(256) void k_seT(const __hip_bfloat16* __restrict__ y1,
    float* __restrict__ seT)
{
  const int c=blockIdx.x, n=blockIdx.y, tid=threadIdx.x;
  const int v = tid&31, g = tid>>5;
  __shared__ float red[8][33];
  const __hip_bfloat16* yp = y1 + ((size_t)n*C_+c)*T_*V_;
  float s=0.f;
  if (v < V_){
    #pragma unroll 4
    for (int j=0;j<16;++j){
      int t = g + j*8;
      s += b2f(yp[t*V_+v]);
    }
  }
  red[g][v]=s;
  __syncthreads();
  if (tid < V_){
    float tot=0.f;
    #pragma unroll
    for (int g2=0;g2<8;++g2) tot += red[g2][tid];
    seT[((size_t)n*C_+c)*V_+tid]=tot*(1.f/T_);
  }
}

// ---------------- K3b: sa[n,v] spatial gate ----------------
__global__ __launch_bounds__(64) void k_sa(const float* __restrict__ seT,
    const float* __restrict__ W_sa, const float* __restrict__ b_sa,
    float* __restrict__ sa)
{
  const int n=blockIdx.x, tid=threadIdx.x;
  if (tid>=V_) return;
  const float* se = seT + (size_t)n*C_*V_;
  float acc=b_sa[0];
  for (int c=0;c<C_;++c){
    #pragma unroll
    for (int k=0;k<V_;++k){
      int vv=tid+k-12;  // pad = (V-1)/2 = 12
      if (vv>=0&&vv<V_) acc+=se[c*V_+vv]*W_sa[c*V_+k];
    }
  }
  sa[n*V_+tid]=sigm(acc);
}

// ---------------- K3c: seV[n,c,t] = mean_v y1*(1+sa) ----------------
__global__ __launch_bounds__(256) void k_seV(const __hip_bfloat16* __restrict__ y1,
    const float* __restrict__ sa, float* __restrict__ seV)
{
  const int c=blockIdx.x, n=blockIdx.y, tid=threadIdx.x;
  const int v = tid&31, g = tid>>5;
  __shared__ float sal[32];
  if (tid<32) sal[tid] = (tid<V_)? 1.f+sa[n*V_+tid] : 0.f;
  __syncthreads();
  const __hip_bfloat16* yp = y1 + ((size_t)n*C_+c)*T_*V_;
  float* svo = seV + ((size_t)n*C_+c)*T_;
  const float sv_ = sal[v];
  for (int j=0;j<16;++j){
    int t = g*16 + j;
    float val = (v<V_)? b2f(yp[t*V_+v])*sv_ : 0.f;
    #pragma unroll
    for (int off=16;off;off>>=1) val += __shfl_xor(val, off);
    if (v==0) svo[t]=val*(1.f/V_);
  }
}

// ---------------- K3d: ta[n,t] temporal gate + ca[n,c] channel gate ----------------
__global__ __launch_bounds__(128) void k_ta_ca(const float* __restrict__ seV,
    const float* __restrict__ W_ta, const float* __restrict__ b_ta,
    const float* __restrict__ W_fc1, const float* __restrict__ b_fc1,
    const float* __restrict__ W_fc2, const float* __restrict__ b_fc2,
    float* __restrict__ ta, float* __restrict__ ca)
{
  const int n=blockIdx.x, tid=threadIdx.x;
  __shared__ float tal[T_];
  __shared__ float scl[C_];
  __shared__ float h1[32];
  const float* sv = seV + (size_t)n*C_*T_;
  {
    float acc=b_ta[0];
    for (int c=0;c<C_;++c){
      #pragma unroll
      for (int k=0;k<9;++k){
        int tt=tid+k-4;
        if (tt>=0&&tt<T_) acc+=sv[c*T_+tt]*W_ta[c*9+k];
      }
    }
    float s=sigm(acc);
    tal[tid]=s; ta[n*T_+tid]=s;
  }
  __syncthreads();
  if (tid<C_){
    float acc=0.f;
    for (int t=0;t<T_;++t) acc += sv[tid*T_+t]*(1.f+tal[t]);
    scl[tid]=acc*(1.f/T_);
  }
  __syncthreads();
  if (tid<32){
    float acc=b_fc1[tid];
    for (int c=0;c<C_;++c) acc += scl[c]*W_fc1[tid*C_+c];
    h1[tid]=fmaxf(acc,0.f);
  }
  __syncthreads();
  if (tid<C_){
    float acc=b_fc2[tid];
    for (int j=0;j<32;++j) acc += h1[j]*W_fc2[tid*32+j];
    ca[n*C_+tid]=sigm(acc);
  }
}

// ---------------- K4: MFMA xa/gates + q/k/v projections ----------------
__global__ __launch_bounds__(256) void k_xa_qkv(
    const __hip_bfloat16* __restrict__ y1, const float* __restrict__ pos_emb,
    const float* __restrict__ sa, const float* __restrict__ ta, const float* __restrict__ ca,
    const float* __restrict__ Wq_h, const float* __restrict__ bq_h,
    const float* __restrict__ Wk_h, const float* __restrict__ bk_h,
    const float* __restrict__ Wv_h, const float* __restrict__ bv_h,
    __hip_bfloat16* __restrict__ xa, __hip_bfloat16* __restrict__ qb,
    __hip_bfloat16* __restrict__ kb, __hip_bfloat16* __restrict__ vb)
{
  const int t=blockIdx.x, n=blockIdx.y, tid=threadIdx.x;
  __shared__ __align__(16) short w3[192*72];    // [mu][c], mu = which*64+ho
  __shared__ __align__(16) short xalT[32*72];   // [w][c]
  __shared__ float bl[192];
  for (int i=tid;i<192*64;i+=256){
    int mu=i/64, c=i%64, which=mu/C_, ho=mu%C_;
    const float* W = which==0?Wq_h:(which==1?Wk_h:Wv_h);
    w3[mu*72+c] = (short)f2bu(W[(size_t)ho*C_+c]);
  }
  if (tid<192){
    int which=tid/C_, ho=tid%C_;
    bl[tid] = (which==0?bq_h:(which==1?bk_h:bv_h))[ho];
  }
  const float tg = 1.f + ta[n*T_+t];
  const __hip_bfloat16* y1n = y1 + (size_t)n*C_*T_*V_;
  __hip_bfloat16* xan = xa + (size_t)n*C_*T_*V_;
  for (int i=tid;i<CV;i+=256){
    int c=i/V_, v=i%V_;
    float val = b2f(y1n[(size_t)c*T_*V_+t*V_+v]) * (1.f+sa[n*V_+v]) * tg * (1.f+ca[n*C_+c])
              + pos_emb[(size_t)t*CV + i];
    xan[(size_t)c*T_*V_+t*V_+v]=f2b(val);
    xalT[v*72+c] = (short)f2bu(val);
  }
  __syncthreads();
  const int wv=tid>>6, l=tid&63, lc=l&15, lk=l>>4;
  short8v bf_[2][2];
  #pragma unroll
  for (int ks=0;ks<2;++ks){
    bf_[ks][0] = *(const short8v*)(xalT + lc*72      + ks*32 + lk*8);
    bf_[ks][1] = *(const short8v*)(xalT + (16+lc)*72 + ks*32 + lk*8);
  }
  #pragma unroll
  for (int mt3=0;mt3<3;++mt3){
    const int mt = wv + mt3*4;
    f32x4 acc0 = {0.f,0.f,0.f,0.f}, acc1 = {0.f,0.f,0.f,0.f};
    #pragma unroll
    for (int ks=0;ks<2;++ks){
      short8v a = *(const short8v*)(w3 + (mt*16+lc)*72 + ks*32 + lk*8);
      acc0 = MFMA16(a, bf_[ks][0], acc0,0,0,0);
      acc1 = MFMA16(a, bf_[ks][1], acc1,0,0,0);
    }
    #pragma unroll
    for (int reg=0;reg<4;++reg){
      const int mu = mt*16 + lk*4 + reg;
      const int which = mu/C_, ho = mu%C_, h = ho/IH, o = ho%IH;
      __hip_bfloat16* dst = (which==0?qb:(which==1?kb:vb))
                            + (((size_t)n*H_+h)*T_+t)*D_ + o*V_;
      const float bb = bl[mu];
      dst[lc] = f2b(acc0[reg]+bb);
      if (lc < 9) dst[16+lc] = f2b(acc1[reg]+bb);
    }
  }
}

// ---------------- K5: MFMA flash causal MHA ----------------
__global__ __launch_bounds__(256) void k_attn(
    const __hip_bfloat16* __restrict__ qb, const __hip_bfloat16* __restrict__ kb,
    const __hip_bfloat16* __restrict__ vb, __hip_bfloat16* __restrict__ oh)
{
  const int bx = blockIdx.x;
  const int nh = blockIdx.z*H_ + blockIdx.y;
  const int tid = threadIdx.x;
  const int wv = tid>>6, l = tid&63;
  const int lc = l&15, lg = l>>4;
  __shared__ __align__(16) char KlB[32*512];      // [key][d(256sh)] bf16, byte^=(key&7)<<4
  __shared__ __align__(16) short VT[208*40];      // [d][key] bf16
  __shared__ __align__(16) short Pl[64*40];       // [qloc][key] bf16 (per-wave slices)
  const __hip_bfloat16* qg_ = qb + (size_t)nh*T_*D_;
  const __hip_bfloat16* kg_ = kb + (size_t)nh*T_*D_;
  const __hip_bfloat16* vg_ = vb + (size_t)nh*T_*D_;
  __hip_bfloat16* og_ = oh + (size_t)nh*T_*D_;
  const float scale = 0.0707106781f;  // 1/sqrt(200)

  for (int i=tid;i<32*12;i+=256){
    int key=i/12, j=i%12;
    *(unsigned int*)(KlB + ((key*512 + 400 + j*4) ^ ((key&7)<<4))) = 0u;
  }
  for (int i=tid;i<8*40;i+=256) VT[200*40 + i] = 0;

  const int qrow = bx*64 + wv*16 + lc;
  short8v qf[7];
  {
    const short8v* qs8 = (const short8v*)(qg_ + (size_t)qrow*D_);
    #pragma unroll
    for (int ks=0;ks<7;++ks) qf[ks] = qs8[ks*4 + lg];
  }
  f32x4 oacc[13];
  #pragma unroll
  for (int i=0;i<13;++i) oacc[i] = (f32x4){0.f,0.f,0.f,0.f};
  float m[4], lsm[4];
  #pragma unroll
  for (int r=0;r<4;++r){ m[r]=-1e30f; lsm[r]=0.f; }

  const int ntiles = (bx==0)? 2 : 4;
  for (int kt=0; kt<ntiles; ++kt){
    const int j0 = kt*32;
    __syncthreads();
    {
      const short8v* ks8 = (const short8v*)(kg_ + (size_t)j0*D_);
      for (int i=tid;i<32*25;i+=256){
        int row=i/25, w=i%25;
        *(short8v*)(KlB + ((row*512 + w*16) ^ ((row&7)<<4))) = ks8[i];
      }
      const short8v* vs8 = (const short8v*)(vg_ + (size_t)j0*D_);
      for (int i=tid;i<32*25;i+=256){
        int row=i&31, w4=i>>5;
        short8v u = vs8[row*25 + w4];
        #pragma unroll
        for (int j=0;j<8;++j) VT[(w4*8+j)*40 + row] = u[j];
      }
    }
    __syncthreads();
    const bool active = (j0 <= bx*64 + wv*16 + 15);
    if (active){
      f32x4 s0 = {0.f,0.f,0.f,0.f}, s1 = {0.f,0.f,0.f,0.f};
      #pragma unroll
      for (int ks=0;ks<7;++ks){
        short8v b0 = *(const short8v*)(KlB + ((lc*512      + ks*64 + lg*16) ^ ((lc&7)<<4)));
        short8v b1 = *(const short8v*)(KlB + (((16+lc)*512 + ks*64 + lg*16) ^ ((lc&7)<<4)));
        s0 = MFMA16(qf[ks], b0, s0,0,0,0);
        s1 = MFMA16(qf[ks], b1, s1,0,0,0);
      }
      float fr[4];
      #pragma unroll
      for (int r=0;r<4;++r){
        const int qg = bx*64 + wv*16 + lg*4 + r;
        float v0 = (j0+lc    <= qg) ? s0[r]*scale : -1e30f;
        float v1 = (j0+16+lc <= qg) ? s1[r]*scale : -1e30f;
        float mx = fmaxf(v0,v1);
        #pragma unroll
        for (int off=1;off<16;off<<=1) mx = fmaxf(mx, __shfl_xor(mx, off));
        float mn = fmaxf(m[r], mx);
        fr[r] = __expf(m[r]-mn);
        float p0 = __expf(v0-mn), p1 = __expf(v1-mn);
        float ts = p0+p1;
        #pragma unroll
        for (int off=1;off<16;off<<=1) ts += __shfl_xor(ts, off);
        lsm[r] = lsm[r]*fr[r] + ts;
        m[r] = mn;
        Pl[(wv*16 + lg*4 + r)*40 + lc]      = (short)f2bu(p0);
        Pl[(wv*16 + lg*4 + r)*40 + 16 + lc] = (short)f2bu(p1);
      }
      #pragma unroll
      for (int dt=0;dt<13;++dt){
        #pragma unroll
        for (int r=0;r<4;++r) oacc[dt][r] *= fr[r];
      }
      short8v pa = *(const short8v*)(Pl + (wv*16+lc)*40 + lg*8);
      #pragma unroll
      for (int dt=0;dt<13;++dt){
        short8v b = *(const short8v*)(VT + (dt*16+lc)*40 + lg*8);
        oacc[dt] = MFMA16(pa, b, oacc[dt],0,0,0);
      }
    }
  }
  float rl[4];
  #pragma unroll
  for (int r=0;r<4;++r) rl[r] = 1.f/lsm[r];
  #pragma unroll
  for (int dt=0;dt<13;++dt){
    const int d = dt*16 + lc;
    if (d < D_){
      #pragma unroll
      for (int r=0;r<4;++r){
        const int q = bx*64 + wv*16 + lg*4 + r;
        og_[(size_t)q*D_ + d] = f2b(oacc[dt][r]*rl[r]);
      }
    }
  }
}

// ---------------- K7: 8-t tile MFMA out kernel ----------------
// grid (T_/8, N_). z=bn(oh)+xa staged as zT[tv][c] bf16; FFN = 64x200x64 MFMA;
// epilogue: +b_ffn, relu, +xa, bn, +x, relu -> out (coalesced 200-wide rows).
__global__ __launch_bounds__(256) void k_out(
    const __hip_bfloat16* __restrict__ oh, const __hip_bfloat16* __restrict__ xa,
    const float* __restrict__ x, const float* __restrict__ W_ffn,
    const float* __restrict__ b_ffn, const float* __restrict__ m_gamma,
    const float* __restrict__ m_beta, float* __restrict__ out)
{
  const int tc = blockIdx.x, n = blockIdx.y, tid = threadIdx.x;
  const int wv = tid>>6, l = tid&63, lc = l&15, lg = l>>4;
  __shared__ __align__(16) short wfl[64*72];   // W_ffn bf16 [o][c]
  __shared__ __align__(16) short zT[208*72];   // z^T bf16 [tv][c], rows 200..207 zeroed
  __shared__ float bn_s[64], bn_b[64], bff[64];
  const float invs = rsqrtf(1.f+EPSB);
  for (int i=tid;i<64*64;i+=256){
    int o=i>>6, c=i&63;
    wfl[o*72+c] = (short)f2bu(W_ffn[i]);
  }
  if (tid<64){ bn_s[tid]=m_gamma[tid]*invs; bn_b[tid]=m_beta[tid]; bff[tid]=b_ffn[tid]; }
  for (int i=tid;i<8*72;i+=256) zT[200*72+i]=0;
  __syncthreads();
  const int tv0 = tc*200;   // global tv base (= t0*V_)
  const __hip_bfloat16* xan = xa + (size_t)n*C_*TV;
  // ---- assemble z^T ----
  for (int i=tid;i<64*200;i+=256){
    int c=i/200, tv=i%200;
    int t = tc*8 + tv/25, v = tv%25;
    float xav = b2f(xan[(size_t)c*TV + tv0 + tv]);
    int h=c>>3, oi=c&7;
    float ohv = b2f(oh[(((size_t)n*H_+h)*T_+t)*D_ + oi*V_ + v]);
    zT[tv*72 + c] = (short)f2bu(bn_s[c]*ohv + bn_b[c] + xav);
  }
  __syncthreads();
  // ---- FFN GEMM: wave wv = o-rows wv*16..+15; 13 N-tiles ----
  const int lk = lg;
  short8v af0 = *(const short8v*)(wfl + (wv*16+lc)*72 + lk*8);
  short8v af1 = *(const short8v*)(wfl + (wv*16+lc)*72 + 32 + lk*8);
  f32x4 acc[13];
  #pragma unroll
  for (int dt=0;dt<13;++dt) acc[dt] = (f32x4){0.f,0.f,0.f,0.f};
  #pragma unroll
  for (int dt=0;dt<13;++dt){
    short8v b0 = *(const short8v*)(zT + (dt*16+lc)*72 + lk*8);
    short8v b1 = *(const short8v*)(zT + (dt*16+lc)*72 + 32 + lk*8);
    acc[dt] = MFMA16(af0, b0, acc[dt],0,0,0);
    acc[dt] = MFMA16(af1, b1, acc[dt],0,0,0);
  }
  // ---- epilogue ----
  const float* xn = x + (size_t)n*C_*TV;
  float* outn = out + (size_t)n*C_*TV;
  #pragma unroll
  for (int dt=0;dt<13;++dt){
    const int tv = dt*16 + lc;
    if (tv < 200){
      #pragma unroll
      for (int reg=0;reg<4;++reg){
        const int o = wv*16 + lg*4 + reg;
        float z2 = fmaxf(acc[dt][reg] + bff[o], 0.f) + b2f(xan[(size_t)o*TV + tv0 + tv]);
        float z3 = bn_s[o]*z2 + bn_b[o];
        outn[(size_t)o*TV + tv0 + tv] = fmaxf(z3 + xn[(size_t)o*TV + tv0 + tv], 0.f);
      }
    }
  }
}

extern "C" void kernel_launch(void* const* d_in, const int* in_sizes, int n_in,
                              void* d_out, int out_size, void* d_ws, size_t ws_size,
                              hipStream_t stream) {
  const float* x      = (const float*)d_in[0];
  const float* A      = (const float*)d_in[1];
  const float* alphap = (const float*)d_in[2];
  const float* Wq     = (const float*)d_in[3];
  const float* bq     = (const float*)d_in[4];
  const float* Wk     = (const float*)d_in[5];
  const float* bk     = (const float*)d_in[6];
  const float* Wf     = (const float*)d_in[7];
  const float* bfp    = (const float*)d_in[8];
  const float* g_gamma= (const float*)d_in[9];
  const float* g_beta = (const float*)d_in[10];
  const float* W_sa   = (const float*)d_in[11];
  const float* b_sa   = (const float*)d_in[12];
  const float* W_ta   = (const float*)d_in[13];
  const float* b_ta   = (const float*)d_in[14];
  const float* W_fc1  = (const float*)d_in[15];
  const float* b_fc1  = (const float*)d_in[16];
  const float* W_fc2  = (const float*)d_in[17];
  const float* b_fc2  = (const float*)d_in[18];
  const float* pos_emb= (const float*)d_in[19];
  const float* Wq_h   = (const float*)d_in[20];
  const float* bq_h   = (const float*)d_in[21];
  const float* Wk_h   = (const float*)d_in[22];
  const float* bk_h   = (const float*)d_in[23];
  const float* Wv_h   = (const float*)d_in[24];
  const float* bv_h   = (const float*)d_in[25];
  const float* W_ffn  = (const float*)d_in[26];
  const float* b_ffn  = (const float*)d_in[27];
  const float* m_gamma= (const float*)d_in[28];
  const float* m_beta = (const float*)d_in[29];
  float* out = (float*)d_out;

  float* ws   = (float*)d_ws;
  float* Aad  = ws;                    // 128*3*625   = 240000
  float* seT  = Aad + 240000;          // 128*64*25   = 204800
  float* seV  = seT + 204800;          // 128*64*128  = 1048576
  float* sa   = seV + 1048576;         // 128*25      = 3200
  float* ta   = sa  + 3200;            // 128*128     = 16384
  float* ca   = ta  + 16384;           // 128*64      = 8192
  __hip_bfloat16* y1 = (__hip_bfloat16*)(ca + 8192);  // 26214400 elems (reused as oh)
  __hip_bfloat16* xa = y1 + (size_t)26214400;
  __hip_bfloat16* qb = xa + (size_t)26214400;
  __hip_bfloat16* kb = qb + (size_t)26214400;
  __hip_bfloat16* vb = kb + (size_t)26214400;
  __hip_bfloat16* oh = y1;  // reuse: y1 dead after k_xa_qkv
  float* attg = (float*)y1; // scratch before y1 is written (16*384*625*4 = 15.4MB)

  k_gcn_att1<<<dim3(NCHUNK, N_*S_), 256, 0, stream>>>(x, Wq, bq, Wk, bk, attg);
  k_gcn_att2<<<N_*S_, 256, 0, stream>>>(attg, A, alphap, Aad);
  k_gcn_y<<<dim3(T_, N_), 256, 0, stream>>>(x, Aad, Wf, bfp, g_gamma, g_beta, y1);
  k_seT<<<dim3(C_, N_), 256, 0, stream>>>(y1, seT);
  k_sa<<<N_, 64, 0, stream>>>(seT, W_sa, b_sa, sa);
  k_seV<<<dim3(C_, N_), 256, 0, stream>>>(y1, sa, seV);
  k_ta_ca<<<N_, 128, 0, stream>>>(seV, W_ta, b_ta, W_fc1, b_fc1, W_fc2, b_fc2, ta, ca);
  k_xa_qkv<<<dim3(T_, N_), 256, 0, stream>>>(y1, pos_emb, sa, ta, ca,
      Wq_h, bq_h, Wk_h, bk_h, Wv_h, bv_h, xa, qb, kb, vb);
  k_attn<<<dim3(2, H_, N_), 256, 0, stream>>>(qb, kb, vb, oh);
  k_out<<<dim3(T_/8, N_), 256, 0, stream>>>(oh, xa, x, W_ffn, b_ffn, m_gamma, m_beta, out);
}

// Round 8
// 842.719 us; speedup vs baseline: 5.6320x; 1.1655x over previous
//
#include <hip/hip_runtime.h>
#include <hip/hip_bf16.h>

#define N_ 128
#define C_ 64
#define T_ 128
#define V_ 25
#define S_ 3
#define IG 16
#define IH 8
#define H_ 8
#define D_ 200   // IH*V
#define CV 1600  // C_*V_
#define TV 3200  // T_*V_
#define EPSB 1e-5f
#define NCHUNK 16
#define TPC 8    // t per chunk (k_gcn_att1)

typedef __attribute__((ext_vector_type(8))) short short8v;
typedef __attribute__((ext_vector_type(4))) float f32x4;
#define MFMA16 __builtin_amdgcn_mfma_f32_16x16x32_bf16

__device__ __forceinline__ float sigm(float x){ return 1.f/(1.f+expf(-x)); }
__device__ __forceinline__ float b2f(__hip_bfloat16 b){ return __bfloat162float(b); }
__device__ __forceinline__ __hip_bfloat16 f2b(float f){ return __float2bfloat16(f); }
__device__ __forceinline__ float ubl(unsigned int u){ return __uint_as_float(u<<16); }
__device__ __forceinline__ float ubh(unsigned int u){ return __uint_as_float(u & 0xffff0000u); }
__device__ __forceinline__ unsigned short f2bu(float f){
  unsigned int u = __float_as_uint(f);
  u += 0x7fff + ((u>>16)&1);
  return (unsigned short)(u>>16);
}
__device__ __forceinline__ unsigned long long pk4bf(f32x4 v){
  unsigned long long a = f2bu(v[0]);
  unsigned long long b = f2bu(v[1]);
  unsigned long long c = f2bu(v[2]);
  unsigned long long d = f2bu(v[3]);
  return a | (b<<16) | (c<<32) | (d<<48);
}

// ---------------- K1a: MFMA adaptive graph attention partials ----------------
__global__ __launch_bounds__(256) void k_gcn_att1(
    const float* __restrict__ x,
    const float* __restrict__ Wq, const float* __restrict__ bq,
    const float* __restrict__ Wk, const float* __restrict__ bk,
    float* __restrict__ attg)
{
  const int tc = blockIdx.x, ns = blockIdx.y, n = ns / S_, s = ns % S_;
  const int tid = threadIdx.x;
  const int wv = tid>>6, l = tid&63, lc = l&15, lk = l>>4;
  __shared__ __align__(16) short wql[16*72], wkl[16*72];
  __shared__ float bql[16], bkl[16];
  __shared__ __align__(16) short xtb[4*32*72];   // [tl][v(32)][c(72)], v>=25 zeroed
  __shared__ __align__(16) char QB[32*256];      // [v][K=128 bf16], byte^=(v&7)<<4
  __shared__ __align__(16) char KB[32*256];
  for (int i=tid;i<IG*C_;i+=256){
    int ii=i>>6, c=i&63;
    wql[ii*72+c] = (short)f2bu(Wq[s*IG*C_+i]);
    wkl[ii*72+c] = (short)f2bu(Wk[s*IG*C_+i]);
  }
  if (tid<16){ bql[tid]=bq[s*IG+tid]; bkl[tid]=bk[s*IG+tid]; }
  for (int i=tid;i<4*7*72;i+=256){
    int tl=i/(7*72), r=i%(7*72);
    xtb[(tl*32+25)*72 + r] = 0;
  }
  const float* xn = x + (size_t)n*C_*T_*V_;
  const int t0 = tc*TPC;
  #pragma unroll
  for (int tg=0; tg<2; ++tg){
    __syncthreads();
    for (int i=tid;i<4*1600;i+=256){
      int tl=i/1600, r=i%1600, c=r/25, v=r%25;
      xtb[(tl*32+v)*72 + c] = (short)f2bu(xn[(size_t)c*TV + (t0+tg*4+tl)*V_ + v]);
    }
    __syncthreads();
    const int tcol = (tg*4+wv)*32;
    f32x4 z={0.f,0.f,0.f,0.f};
    f32x4 aq0=z,aq1=z,ak0=z,ak1=z;
    #pragma unroll
    for (int ks=0;ks<2;++ks){
      short8v aq = *(const short8v*)(wql + lc*72 + ks*32 + lk*8);
      short8v ak = *(const short8v*)(wkl + lc*72 + ks*32 + lk*8);
      short8v b0 = *(const short8v*)(xtb + (wv*32+lc)*72 + ks*32 + lk*8);
      short8v b1 = *(const short8v*)(xtb + (wv*32+16+lc)*72 + ks*32 + lk*8);
      aq0 = MFMA16(aq,b0,aq0,0,0,0);
      aq1 = MFMA16(aq,b1,aq1,0,0,0);
      ak0 = MFMA16(ak,b0,ak0,0,0,0);
      ak1 = MFMA16(ak,b1,ak1,0,0,0);
    }
    f32x4 q0,q1,k0,k1;
    #pragma unroll
    for (int r=0;r<4;++r){
      float bqv = bql[lk*4+r], bkv = bkl[lk*4+r];
      q0[r]=aq0[r]+bqv; q1[r]=aq1[r]+bqv;
      k0[r]=ak0[r]+bkv; k1[r]=ak1[r]+bkv;
    }
    const int sw = (lc&7)<<4;
    *(unsigned long long*)(QB + ((lc*256      + tcol + lk*8) ^ sw)) = pk4bf(q0);
    *(unsigned long long*)(QB + (((16+lc)*256 + tcol + lk*8) ^ sw)) = pk4bf(q1);
    *(unsigned long long*)(KB + ((lc*256      + tcol + lk*8) ^ sw)) = pk4bf(k0);
    *(unsigned long long*)(KB + (((16+lc)*256 + tcol + lk*8) ^ sw)) = pk4bf(k1);
  }
  __syncthreads();
  const int mt = wv>>1, nt = wv&1;
  const int sw = (lc&7)<<4;
  f32x4 acc = {0.f,0.f,0.f,0.f};
  #pragma unroll
  for (int ks=0;ks<4;++ks){
    short8v a = *(const short8v*)(QB + (((mt*16+lc)*256 + ks*64 + lk*16) ^ sw));
    short8v b = *(const short8v*)(KB + (((nt*16+lc)*256 + ks*64 + lk*16) ^ sw));
    acc = MFMA16(a,b,acc,0,0,0);
  }
  float* Ao = attg + ((size_t)tc*(N_*S_) + ns)*(V_*V_);
  #pragma unroll
  for (int reg=0;reg<4;++reg){
    int v = mt*16 + lk*4 + reg, w = nt*16 + lc;
    if (v<V_ && w<V_) Ao[v*V_+w] = acc[reg];
  }
}

// ---------------- K1b: reduce chunks + softmax(dim=-2) + Aad ----------------
__global__ __launch_bounds__(256) void k_gcn_att2(
    const float* __restrict__ attg, const float* __restrict__ A,
    const float* __restrict__ alphap, float* __restrict__ Aad)
{
  const int ns = blockIdx.x, s = ns % S_, tid = threadIdx.x;
  __shared__ float att[V_*V_];
  for (int i=tid;i<V_*V_;i+=256){
    float acc=0.f;
    #pragma unroll
    for (int tcc=0;tcc<NCHUNK;++tcc) acc += attg[((size_t)tcc*(N_*S_) + ns)*(V_*V_) + i];
    att[i]=acc;
  }
  __syncthreads();
  if (tid<V_){
    const int w=tid; const float inv=1.f/(IG*T_);
    float mx=-1e30f;
    for (int v=0;v<V_;++v) mx=fmaxf(mx, att[v*V_+w]*inv);
    float sum=0.f;
    for (int v=0;v<V_;++v){ float e=expf(att[v*V_+w]*inv-mx); att[v*V_+w]=e; sum+=e; }
    float rs=1.f/sum;
    for (int v=0;v<V_;++v) att[v*V_+w]*=rs;
  }
  __syncthreads();
  const float alpha=alphap[0];
  float* Ao = Aad + (size_t)ns*V_*V_;
  for (int i=tid;i<V_*V_;i+=256) Ao[i]=A[s*V_*V_+i]+alpha*att[i];
}

// ---------------- K2: 4-t tile MFMA graph conv + Wf + bn + residual + relu ----------------
// grid (T_/4, N_). Phase1: per-t agg via MFMA -> aggT[tv][sc] bf16.
// Phase2: y(64 x 100) = W~(64x192) @ aggT^T, A-frags from global Wf (registers).
__global__ __launch_bounds__(256) void k_gcn_y(
    const float* __restrict__ x, const float* __restrict__ Aad,
    const float* __restrict__ Wf, const float* __restrict__ bfp,
    const float* __restrict__ g_gamma, const float* __restrict__ g_beta,
    __hip_bfloat16* __restrict__ y1)
{
  const int tc=blockIdx.x, n=blockIdx.y, tid=threadIdx.x;
  const int wv=tid>>6, l=tid&63, lc=l&15, lk=l>>4;
  __shared__ __align__(16) short xtb[64*136];   // [c][t*32+v], v-pad zeroed (stride 136 -> 2-way banks)
  __shared__ __align__(16) short AsT[3*32*40];  // [s][w][v], v-pad zeroed
  __shared__ __align__(16) short aggT[112*200]; // [tv][sc], rows 100..111 zeroed
  const float* xn = x + (size_t)n*C_*TV;
  const int tv0 = tc*100;
  // stage x (4 t's), coalesced 400B rows
  for (int i=tid;i<64*100;i+=256){
    int c=i/100, tv=i%100, t=tv/25, v=tv%25;
    xtb[c*136 + t*32 + v] = (short)f2bu(xn[(size_t)c*TV + tv0 + tv]);
  }
  for (int i=tid;i<64*28;i+=256){ int c=i/28, r=i%28; xtb[c*136 + (r/7)*32 + 25 + (r%7)] = 0; }
  for (int i=tid;i<3*32*7;i+=256){ int sw_=i/7; AsT[sw_*40 + 25 + (i%7)] = 0; }
  const float* Adn = Aad + (size_t)n*S_*V_*V_;
  for (int i=tid;i<S_*V_*V_;i+=256){
    int s=i/625, r=i%625, v=r/25, w=r%25;
    AsT[(s*32+w)*40+v] = (short)f2bu(Adn[i]);
  }
  for (int i=tid;i<12*200;i+=256) aggT[100*200+i]=0;
  __syncthreads();
  // ---- phase 1: wave wv owns t=wv ----
  {
    const int t = wv;
    for (int s=0;s<S_;++s){
      short8v b0 = *(const short8v*)(AsT + (s*32+lc)*40 + lk*8);
      short8v b1 = *(const short8v*)(AsT + (s*32+16+lc)*40 + lk*8);
      #pragma unroll
      for (int mt=0;mt<4;++mt){
        short8v a = *(const short8v*)(xtb + (mt*16+lc)*136 + t*32 + lk*8);
        f32x4 z={0.f,0.f,0.f,0.f};
        f32x4 acc0 = MFMA16(a,b0,z,0,0,0);
        f32x4 acc1 = MFMA16(a,b1,z,0,0,0);
        *(unsigned long long*)(aggT + (t*25+lc)*200 + s*64 + mt*16 + lk*4) = pk4bf(acc0);
        if (lc<9)
          *(unsigned long long*)(aggT + (t*25+16+lc)*200 + s*64 + mt*16 + lk*4) = pk4bf(acc1);
      }
    }
  }
  // ---- A-frags of W~ from global (registers) ----
  short8v af[6];
  #pragma unroll
  for (int ks=0;ks<6;++ks){
    const int s = ks>>1, c0 = (ks&1)*32 + lk*8;
    const float* wr = Wf + ((size_t)s*C_ + wv*16+lc)*C_ + c0;
    short8v t8;
    #pragma unroll
    for (int j=0;j<8;++j) t8[j] = (short)f2bu(wr[j]);
    af[ks]=t8;
  }
  __syncthreads();
  // ---- phase 2: 7 N-tiles x 6 k-steps ----
  f32x4 acc[7];
  #pragma unroll
  for (int dt=0;dt<7;++dt) acc[dt]=(f32x4){0.f,0.f,0.f,0.f};
  #pragma unroll
  for (int dt=0;dt<7;++dt){
    #pragma unroll
    for (int ks=0;ks<6;++ks){
      short8v b = *(const short8v*)(aggT + (dt*16+lc)*200 + ks*32 + lk*8);
      acc[dt] = MFMA16(af[ks], b, acc[dt],0,0,0);
    }
  }
  // ---- epilogue: bias + bn + residual + relu, coalesced ----
  const float invs = rsqrtf(1.f+EPSB);
  __hip_bfloat16* yo = y1 + (size_t)n*C_*TV;
  #pragma unroll
  for (int reg=0;reg<4;++reg){
    const int o = wv*16 + lk*4 + reg;
    const float bsum = bfp[o]+bfp[C_+o]+bfp[2*C_+o];
    const float gs = g_gamma[o]*invs, gb = g_beta[o];
    #pragma unroll
    for (int dt=0;dt<7;++dt){
      const int tv = dt*16 + lc;
      if (tv < 100){
        float val = (acc[dt][reg]+bsum)*gs + gb + xn[(size_t)o*TV + tv0 + tv];
        yo[(size_t)o*TV + tv0 + tv] = f2b(fmaxf(val,0.f));
      }
    }
  }
}

// ---------------- K3a: seT[n,c,v] = mean_t y1 ----------------
__global__ __launch_bounds__(256) void k_seT(const __hip_bfloat16* __restrict__ y1,
    float* __restrict__ seT)
{
  const int c=blockIdx.x, n=blockIdx.y, tid=threadIdx.x;
  const int v = tid&31, g = tid>>5;
  __shared__ float red[8][33];
  const __hip_bfloat16* yp = y1 + ((size_t)n*C_+c)*T_*V_;
  float s=0.f;
  if (v < V_){
    #pragma unroll 4
    for (int j=0;j<16;++j){
      int t = g + j*8;
      s += b2f(yp[t*V_+v]);
    }
  }
  red[g][v]=s;
  __syncthreads();
  if (tid < V_){
    float tot=0.f;
    #pragma unroll
    for (int g2=0;g2<8;++g2) tot += red[g2][tid];
    seT[((size_t)n*C_+c)*V_+tid]=tot*(1.f/T_);
  }
}

// ---------------- K3b: sa[n,v] spatial gate ----------------
__global__ __launch_bounds__(64) void k_sa(const float* __restrict__ seT,
    const float* __restrict__ W_sa, const float* __restrict__ b_sa,
    float* __restrict__ sa)
{
  const int n=blockIdx.x, tid=threadIdx.x;
  if (tid>=V_) return;
  const float* se = seT + (size_t)n*C_*V_;
  float acc=b_sa[0];
  for (int c=0;c<C_;++c){
    #pragma unroll
    for (int k=0;k<V_;++k){
      int vv=tid+k-12;  // pad = (V-1)/2 = 12
      if (vv>=0&&vv<V_) acc+=se[c*V_+vv]*W_sa[c*V_+k];
    }
  }
  sa[n*V_+tid]=sigm(acc);
}

// ---------------- K3c: seV[n,c,t] = mean_v y1*(1+sa) ----------------
__global__ __launch_bounds__(256) void k_seV(const __hip_bfloat16* __restrict__ y1,
    const float* __restrict__ sa, float* __restrict__ seV)
{
  const int c=blockIdx.x, n=blockIdx.y, tid=threadIdx.x;
  const int v = tid&31, g = tid>>5;
  __shared__ float sal[32];
  if (tid<32) sal[tid] = (tid<V_)? 1.f+sa[n*V_+tid] : 0.f;
  __syncthreads();
  const __hip_bfloat16* yp = y1 + ((size_t)n*C_+c)*T_*V_;
  float* svo = seV + ((size_t)n*C_+c)*T_;
  const float sv_ = sal[v];
  for (int j=0;j<16;++j){
    int t = g*16 + j;
    float val = (v<V_)? b2f(yp[t*V_+v])*sv_ : 0.f;
    #pragma unroll
    for (int off=16;off;off>>=1) val += __shfl_xor(val, off);
    if (v==0) svo[t]=val*(1.f/V_);
  }
}

// ---------------- K3d: ta[n,t] temporal gate + ca[n,c] channel gate ----------------
__global__ __launch_bounds__(128) void k_ta_ca(const float* __restrict__ seV,
    const float* __restrict__ W_ta, const float* __restrict__ b_ta,
    const float* __restrict__ W_fc1, const float* __restrict__ b_fc1,
    const float* __restrict__ W_fc2, const float* __restrict__ b_fc2,
    float* __restrict__ ta, float* __restrict__ ca)
{
  const int n=blockIdx.x, tid=threadIdx.x;
  __shared__ float tal[T_];
  __shared__ float scl[C_];
  __shared__ float h1[32];
  const float* sv = seV + (size_t)n*C_*T_;
  {
    float acc=b_ta[0];
    for (int c=0;c<C_;++c){
      #pragma unroll
      for (int k=0;k<9;++k){
        int tt=tid+k-4;
        if (tt>=0&&tt<T_) acc+=sv[c*T_+tt]*W_ta[c*9+k];
      }
    }
    float s=sigm(acc);
    tal[tid]=s; ta[n*T_+tid]=s;
  }
  __syncthreads();
  if (tid<C_){
    float acc=0.f;
    for (int t=0;t<T_;++t) acc += sv[tid*T_+t]*(1.f+tal[t]);
    scl[tid]=acc*(1.f/T_);
  }
  __syncthreads();
  if (tid<32){
    float acc=b_fc1[tid];
    for (int c=0;c<C_;++c) acc += scl[c]*W_fc1[tid*C_+c];
    h1[tid]=fmaxf(acc,0.f);
  }
  __syncthreads();
  if (tid<C_){
    float acc=b_fc2[tid];
    for (int j=0;j<32;++j) acc += h1[j]*W_fc2[tid*32+j];
    ca[n*C_+tid]=sigm(acc);
  }
}

// ---------------- K4: MFMA xa/gates + q/k/v projections ----------------
__global__ __launch_bounds__(256) void k_xa_qkv(
    const __hip_bfloat16* __restrict__ y1, const float* __restrict__ pos_emb,
    const float* __restrict__ sa, const float* __restrict__ ta, const float* __restrict__ ca,
    const float* __restrict__ Wq_h, const float* __restrict__ bq_h,
    const float* __restrict__ Wk_h, const float* __restrict__ bk_h,
    const float* __restrict__ Wv_h, const float* __restrict__ bv_h,
    __hip_bfloat16* __restrict__ xa, __hip_bfloat16* __restrict__ qb,
    __hip_bfloat16* __restrict__ kb, __hip_bfloat16* __restrict__ vb)
{
  const int t=blockIdx.x, n=blockIdx.y, tid=threadIdx.x;
  __shared__ __align__(16) short w3[192*72];    // [mu][c], mu = which*64+ho
  __shared__ __align__(16) short xalT[32*72];   // [w][c]
  __shared__ float bl[192];
  for (int i=tid;i<192*64;i+=256){
    int mu=i/64, c=i%64, which=mu/C_, ho=mu%C_;
    const float* W = which==0?Wq_h:(which==1?Wk_h:Wv_h);
    w3[mu*72+c] = (short)f2bu(W[(size_t)ho*C_+c]);
  }
  if (tid<192){
    int which=tid/C_, ho=tid%C_;
    bl[tid] = (which==0?bq_h:(which==1?bk_h:bv_h))[ho];
  }
  const float tg = 1.f + ta[n*T_+t];
  const __hip_bfloat16* y1n = y1 + (size_t)n*C_*T_*V_;
  __hip_bfloat16* xan = xa + (size_t)n*C_*T_*V_;
  for (int i=tid;i<CV;i+=256){
    int c=i/V_, v=i%V_;
    float val = b2f(y1n[(size_t)c*T_*V_+t*V_+v]) * (1.f+sa[n*V_+v]) * tg * (1.f+ca[n*C_+c])
              + pos_emb[(size_t)t*CV + i];
    xan[(size_t)c*T_*V_+t*V_+v]=f2b(val);
    xalT[v*72+c] = (short)f2bu(val);
  }
  __syncthreads();
  const int wv=tid>>6, l=tid&63, lc=l&15, lk=l>>4;
  short8v bf_[2][2];
  #pragma unroll
  for (int ks=0;ks<2;++ks){
    bf_[ks][0] = *(const short8v*)(xalT + lc*72      + ks*32 + lk*8);
    bf_[ks][1] = *(const short8v*)(xalT + (16+lc)*72 + ks*32 + lk*8);
  }
  #pragma unroll
  for (int mt3=0;mt3<3;++mt3){
    const int mt = wv + mt3*4;
    f32x4 acc0 = {0.f,0.f,0.f,0.f}, acc1 = {0.f,0.f,0.f,0.f};
    #pragma unroll
    for (int ks=0;ks<2;++ks){
      short8v a = *(const short8v*)(w3 + (mt*16+lc)*72 + ks*32 + lk*8);
      acc0 = MFMA16(a, bf_[ks][0], acc0,0,0,0);
      acc1 = MFMA16(a, bf_[ks][1], acc1,0,0,0);
    }
    #pragma unroll
    for (int reg=0;reg<4;++reg){
      const int mu = mt*16 + lk*4 + reg;
      const int which = mu/C_, ho = mu%C_, h = ho/IH, o = ho%IH;
      __hip_bfloat16* dst = (which==0?qb:(which==1?kb:vb))
                            + (((size_t)n*H_+h)*T_+t)*D_ + o*V_;
      const float bb = bl[mu];
      dst[lc] = f2b(acc0[reg]+bb);
      if (lc < 9) dst[16+lc] = f2b(acc1[reg]+bb);
    }
  }
}

// ---------------- K5: MFMA flash causal MHA ----------------
__global__ __launch_bounds__(256) void k_attn(
    const __hip_bfloat16* __restrict__ qb, const __hip_bfloat16* __restrict__ kb,
    const __hip_bfloat16* __restrict__ vb, __hip_bfloat16* __restrict__ oh)
{
  const int bx = blockIdx.x;
  const int nh = blockIdx.z*H_ + blockIdx.y;
  const int tid = threadIdx.x;
  const int wv = tid>>6, l = tid&63;
  const int lc = l&15, lg = l>>4;
  __shared__ __align__(16) char KlB[32*512];      // [key][d(256sh)] bf16, byte^=(key&7)<<4
  __shared__ __align__(16) short VT[208*40];      // [d][key] bf16
  __shared__ __align__(16) short Pl[64*40];       // [qloc][key] bf16 (per-wave slices)
  const __hip_bfloat16* qg_ = qb + (size_t)nh*T_*D_;
  const __hip_bfloat16* kg_ = kb + (size_t)nh*T_*D_;
  const __hip_bfloat16* vg_ = vb + (size_t)nh*T_*D_;
  __hip_bfloat16* og_ = oh + (size_t)nh*T_*D_;
  const float scale = 0.0707106781f;  // 1/sqrt(200)

  for (int i=tid;i<32*12;i+=256){
    int key=i/12, j=i%12;
    *(unsigned int*)(KlB + ((key*512 + 400 + j*4) ^ ((key&7)<<4))) = 0u;
  }
  for (int i=tid;i<8*40;i+=256) VT[200*40 + i] = 0;

  const int qrow = bx*64 + wv*16 + lc;
  short8v qf[7];
  {
    const short8v* qs8 = (const short8v*)(qg_ + (size_t)qrow*D_);
    #pragma unroll
    for (int ks=0;ks<7;++ks) qf[ks] = qs8[ks*4 + lg];
  }
  f32x4 oacc[13];
  #pragma unroll
  for (int i=0;i<13;++i) oacc[i] = (f32x4){0.f,0.f,0.f,0.f};
  float m[4], lsm[4];
  #pragma unroll
  for (int r=0;r<4;++r){ m[r]=-1e30f; lsm[r]=0.f; }

  const int ntiles = (bx==0)? 2 : 4;
  for (int kt=0; kt<ntiles; ++kt){
    const int j0 = kt*32;
    __syncthreads();
    {
      const short8v* ks8 = (const short8v*)(kg_ + (size_t)j0*D_);
      for (int i=tid;i<32*25;i+=256){
        int row=i/25, w=i%25;
        *(short8v*)(KlB + ((row*512 + w*16) ^ ((row&7)<<4))) = ks8[i];
      }
      const short8v* vs8 = (const short8v*)(vg_ + (size_t)j0*D_);
      for (int i=tid;i<32*25;i+=256){
        int row=i&31, w4=i>>5;
        short8v u = vs8[row*25 + w4];
        #pragma unroll
        for (int j=0;j<8;++j) VT[(w4*8+j)*40 + row] = u[j];
      }
    }
    __syncthreads();
    const bool active = (j0 <= bx*64 + wv*16 + 15);
    if (active){
      f32x4 s0 = {0.f,0.f,0.f,0.f}, s1 = {0.f,0.f,0.f,0.f};
      #pragma unroll
      for (int ks=0;ks<7;++ks){
        short8v b0 = *(const short8v*)(KlB + ((lc*512      + ks*64 + lg*16) ^ ((lc&7)<<4)));
        short8v b1 = *(const short8v*)(KlB + (((16+lc)*512 + ks*64 + lg*16) ^ ((lc&7)<<4)));
        s0 = MFMA16(qf[ks], b0, s0,0,0,0);
        s1 = MFMA16(qf[ks], b1, s1,0,0,0);
      }
      float fr[4];
      #pragma unroll
      for (int r=0;r<4;++r){
        const int qg = bx*64 + wv*16 + lg*4 + r;
        float v0 = (j0+lc    <= qg) ? s0[r]*scale : -1e30f;
        float v1 = (j0+16+lc <= qg) ? s1[r]*scale : -1e30f;
        float mx = fmaxf(v0,v1);
        #pragma unroll
        for (int off=1;off<16;off<<=1) mx = fmaxf(mx, __shfl_xor(mx, off));
        float mn = fmaxf(m[r], mx);
        fr[r] = __expf(m[r]-mn);
        float p0 = __expf(v0-mn), p1 = __expf(v1-mn);
        float ts = p0+p1;
        #pragma unroll
        for (int off=1;off<16;off<<=1) ts += __shfl_xor(ts, off);
        lsm[r] = lsm[r]*fr[r] + ts;
        m[r] = mn;
        Pl[(wv*16 + lg*4 + r)*40 + lc]      = (short)f2bu(p0);
        Pl[(wv*16 + lg*4 + r)*40 + 16 + lc] = (short)f2bu(p1);
      }
      #pragma unroll
      for (int dt=0;dt<13;++dt){
        #pragma unroll
        for (int r=0;r<4;++r) oacc[dt][r] *= fr[r];
      }
      short8v pa = *(const short8v*)(Pl + (wv*16+lc)*40 + lg*8);
      #pragma unroll
      for (int dt=0;dt<13;++dt){
        short8v b = *(const short8v*)(VT + (dt*16+lc)*40 + lg*8);
        oacc[dt] = MFMA16(pa, b, oacc[dt],0,0,0);
      }
    }
  }
  float rl[4];
  #pragma unroll
  for (int r=0;r<4;++r) rl[r] = 1.f/lsm[r];
  #pragma unroll
  for (int dt=0;dt<13;++dt){
    const int d = dt*16 + lc;
    if (d < D_){
      #pragma unroll
      for (int r=0;r<4;++r){
        const int q = bx*64 + wv*16 + lg*4 + r;
        og_[(size_t)q*D_ + d] = f2b(oacc[dt][r]*rl[r]);
      }
    }
  }
}

// ---------------- K7: 8-t tile MFMA out kernel ----------------
__global__ __launch_bounds__(256) void k_out(
    const __hip_bfloat16* __restrict__ oh, const __hip_bfloat16* __restrict__ xa,
    const float* __restrict__ x, const float* __restrict__ W_ffn,
    const float* __restrict__ b_ffn, const float* __restrict__ m_gamma,
    const float* __restrict__ m_beta, float* __restrict__ out)
{
  const int tc = blockIdx.x, n = blockIdx.y, tid = threadIdx.x;
  const int wv = tid>>6, l = tid&63, lc = l&15, lg = l>>4;
  __shared__ __align__(16) short wfl[64*72];   // W_ffn bf16 [o][c]
  __shared__ __align__(16) short zT[208*72];   // z^T bf16 [tv][c], rows 200..207 zeroed
  __shared__ float bn_s[64], bn_b[64], bff[64];
  const float invs = rsqrtf(1.f+EPSB);
  for (int i=tid;i<64*64;i+=256){
    int o=i>>6, c=i&63;
    wfl[o*72+c] = (short)f2bu(W_ffn[i]);
  }
  if (tid<64){ bn_s[tid]=m_gamma[tid]*invs; bn_b[tid]=m_beta[tid]; bff[tid]=b_ffn[tid]; }
  for (int i=tid;i<8*72;i+=256) zT[200*72+i]=0;
  __syncthreads();
  const int tv0 = tc*200;   // global tv base (= t0*V_)
  const __hip_bfloat16* xan = xa + (size_t)n*C_*TV;
  // ---- assemble z^T ----
  for (int i=tid;i<64*200;i+=256){
    int c=i/200, tv=i%200;
    int t = tc*8 + tv/25, v = tv%25;
    float xav = b2f(xan[(size_t)c*TV + tv0 + tv]);
    int h=c>>3, oi=c&7;
    float ohv = b2f(oh[(((size_t)n*H_+h)*T_+t)*D_ + oi*V_ + v]);
    zT[tv*72 + c] = (short)f2bu(bn_s[c]*ohv + bn_b[c] + xav);
  }
  __syncthreads();
  // ---- FFN GEMM ----
  const int lk = lg;
  short8v af0 = *(const short8v*)(wfl + (wv*16+lc)*72 + lk*8);
  short8v af1 = *(const short8v*)(wfl + (wv*16+lc)*72 + 32 + lk*8);
  f32x4 acc[13];
  #pragma unroll
  for (int dt=0;dt<13;++dt) acc[dt] = (f32x4){0.f,0.f,0.f,0.f};
  #pragma unroll
  for (int dt=0;dt<13;++dt){
    short8v b0 = *(const short8v*)(zT + (dt*16+lc)*72 + lk*8);
    short8v b1 = *(const short8v*)(zT + (dt*16+lc)*72 + 32 + lk*8);
    acc[dt] = MFMA16(af0, b0, acc[dt],0,0,0);
    acc[dt] = MFMA16(af1, b1, acc[dt],0,0,0);
  }
  // ---- epilogue ----
  const float* xn = x + (size_t)n*C_*TV;
  float* outn = out + (size_t)n*C_*TV;
  #pragma unroll
  for (int dt=0;dt<13;++dt){
    const int tv = dt*16 + lc;
    if (tv < 200){
      #pragma unroll
      for (int reg=0;reg<4;++reg){
        const int o = wv*16 + lg*4 + reg;
        float z2 = fmaxf(acc[dt][reg] + bff[o], 0.f) + b2f(xan[(size_t)o*TV + tv0 + tv]);
        float z3 = bn_s[o]*z2 + bn_b[o];
        outn[(size_t)o*TV + tv0 + tv] = fmaxf(z3 + xn[(size_t)o*TV + tv0 + tv], 0.f);
      }
    }
  }
}

extern "C" void kernel_launch(void* const* d_in, const int* in_sizes, int n_in,
                              void* d_out, int out_size, void* d_ws, size_t ws_size,
                              hipStream_t stream) {
  const float* x      = (const float*)d_in[0];
  const float* A      = (const float*)d_in[1];
  const float* alphap = (const float*)d_in[2];
  const float* Wq     = (const float*)d_in[3];
  const float* bq     = (const float*)d_in[4];
  const float* Wk     = (const float*)d_in[5];
  const float* bk     = (const float*)d_in[6];
  const float* Wf     = (const float*)d_in[7];
  const float* bfp    = (const float*)d_in[8];
  const float* g_gamma= (const float*)d_in[9];
  const float* g_beta = (const float*)d_in[10];
  const float* W_sa   = (const float*)d_in[11];
  const float* b_sa   = (const float*)d_in[12];
  const float* W_ta   = (const float*)d_in[13];
  const float* b_ta   = (const float*)d_in[14];
  const float* W_fc1  = (const float*)d_in[15];
  const float* b_fc1  = (const float*)d_in[16];
  const float* W_fc2  = (const float*)d_in[17];
  const float* b_fc2  = (const float*)d_in[18];
  const float* pos_emb= (const float*)d_in[19];
  const float* Wq_h   = (const float*)d_in[20];
  const float* bq_h   = (const float*)d_in[21];
  const float* Wk_h   = (const float*)d_in[22];
  const float* bk_h   = (const float*)d_in[23];
  const float* Wv_h   = (const float*)d_in[24];
  const float* bv_h   = (const float*)d_in[25];
  const float* W_ffn  = (const float*)d_in[26];
  const float* b_ffn  = (const float*)d_in[27];
  const float* m_gamma= (const float*)d_in[28];
  const float* m_beta = (const float*)d_in[29];
  float* out = (float*)d_out;

  float* ws   = (float*)d_ws;
  float* Aad  = ws;                    // 128*3*625   = 240000
  float* seT  = Aad + 240000;          // 128*64*25   = 204800
  float* seV  = seT + 204800;          // 128*64*128  = 1048576
  float* sa   = seV + 1048576;         // 128*25      = 3200
  float* ta   = sa  + 3200;            // 128*128     = 16384
  float* ca   = ta  + 16384;           // 128*64      = 8192
  __hip_bfloat16* y1 = (__hip_bfloat16*)(ca + 8192);  // 26214400 elems (reused as oh)
  __hip_bfloat16* xa = y1 + (size_t)26214400;
  __hip_bfloat16* qb = xa + (size_t)26214400;
  __hip_bfloat16* kb = qb + (size_t)26214400;
  __hip_bfloat16* vb = kb + (size_t)26214400;
  __hip_bfloat16* oh = y1;  // reuse: y1 dead after k_xa_qkv
  float* attg = (float*)y1; // scratch before y1 is written (16*384*625*4 = 15.4MB)

  k_gcn_att1<<<dim3(NCHUNK, N_*S_), 256, 0, stream>>>(x, Wq, bq, Wk, bk, attg);
  k_gcn_att2<<<N_*S_, 256, 0, stream>>>(attg, A, alphap, Aad);
  k_gcn_y<<<dim3(T_/4, N_), 256, 0, stream>>>(x, Aad, Wf, bfp, g_gamma, g_beta, y1);
  k_seT<<<dim3(C_, N_), 256, 0, stream>>>(y1, seT);
  k_sa<<<N_, 64, 0, stream>>>(seT, W_sa, b_sa, sa);
  k_seV<<<dim3(C_, N_), 256, 0, stream>>>(y1, sa, seV);
  k_ta_ca<<<N_, 128, 0, stream>>>(seV, W_ta, b_ta, W_fc1, b_fc1, W_fc2, b_fc2, ta, ca);
  k_xa_qkv<<<dim3(T_, N_), 256, 0, stream>>>(y1, pos_emb, sa, ta, ca,
      Wq_h, bq_h, Wk_h, bk_h, Wv_h, bv_h, xa, qb, kb, vb);
  k_attn<<<dim3(2, H_, N_), 256, 0, stream>>>(qb, kb, vb, oh);
  k_out<<<dim3(T_/8, N_), 256, 0, stream>>>(oh, xa, x, W_ffn, b_ffn, m_gamma, m_beta, out);
}

// Round 9
// 790.189 us; speedup vs baseline: 6.0064x; 1.0665x over previous
//
#include <hip/hip_runtime.h>
#include <hip/hip_bf16.h>

#define N_ 128
#define C_ 64
#define T_ 128
#define V_ 25
#define S_ 3
#define IG 16
#define IH 8
#define H_ 8
#define D_ 200   // IH*V
#define CV 1600  // C_*V_
#define TV 3200  // T_*V_
#define EPSB 1e-5f
#define NCHUNK 16
#define TPC 8    // t per chunk (k_gcn_att1)

typedef __attribute__((ext_vector_type(8))) short short8v;
typedef __attribute__((ext_vector_type(4))) float f32x4;
#define MFMA16 __builtin_amdgcn_mfma_f32_16x16x32_bf16

__device__ __forceinline__ float sigm(float x){ return 1.f/(1.f+expf(-x)); }
__device__ __forceinline__ float b2f(__hip_bfloat16 b){ return __bfloat162float(b); }
__device__ __forceinline__ __hip_bfloat16 f2b(float f){ return __float2bfloat16(f); }
__device__ __forceinline__ float ubl(unsigned int u){ return __uint_as_float(u<<16); }
__device__ __forceinline__ float ubh(unsigned int u){ return __uint_as_float(u & 0xffff0000u); }
__device__ __forceinline__ unsigned short f2bu(float f){
  unsigned int u = __float_as_uint(f);
  u += 0x7fff + ((u>>16)&1);
  return (unsigned short)(u>>16);
}
__device__ __forceinline__ unsigned long long pk4bf(f32x4 v){
  unsigned long long a = f2bu(v[0]);
  unsigned long long b = f2bu(v[1]);
  unsigned long long c = f2bu(v[2]);
  unsigned long long d = f2bu(v[3]);
  return a | (b<<16) | (c<<32) | (d<<48);
}

// ---------------- K1a: MFMA adaptive graph attention partials ----------------
__global__ __launch_bounds__(256) void k_gcn_att1(
    const float* __restrict__ x,
    const float* __restrict__ Wq, const float* __restrict__ bq,
    const float* __restrict__ Wk, const float* __restrict__ bk,
    float* __restrict__ attg)
{
  const int tc = blockIdx.x, ns = blockIdx.y, n = ns / S_, s = ns % S_;
  const int tid = threadIdx.x;
  const int wv = tid>>6, l = tid&63, lc = l&15, lk = l>>4;
  __shared__ __align__(16) short wql[16*72], wkl[16*72];
  __shared__ float bql[16], bkl[16];
  __shared__ __align__(16) short xtb[4*32*72];   // [tl][v(32)][c(72)], v>=25 zeroed
  __shared__ __align__(16) char QB[32*256];      // [v][K=128 bf16], byte^=(v&7)<<4
  __shared__ __align__(16) char KB[32*256];
  for (int i=tid;i<IG*C_;i+=256){
    int ii=i>>6, c=i&63;
    wql[ii*72+c] = (short)f2bu(Wq[s*IG*C_+i]);
    wkl[ii*72+c] = (short)f2bu(Wk[s*IG*C_+i]);
  }
  if (tid<16){ bql[tid]=bq[s*IG+tid]; bkl[tid]=bk[s*IG+tid]; }
  for (int i=tid;i<4*7*72;i+=256){
    int tl=i/(7*72), r=i%(7*72);
    xtb[(tl*32+25)*72 + r] = 0;
  }
  const float* xn = x + (size_t)n*C_*T_*V_;
  const int t0 = tc*TPC;
  #pragma unroll
  for (int tg=0; tg<2; ++tg){
    __syncthreads();
    for (int i=tid;i<4*1600;i+=256){
      int tl=i/1600, r=i%1600, c=r/25, v=r%25;
      xtb[(tl*32+v)*72 + c] = (short)f2bu(xn[(size_t)c*TV + (t0+tg*4+tl)*V_ + v]);
    }
    __syncthreads();
    const int tcol = (tg*4+wv)*32;
    f32x4 z={0.f,0.f,0.f,0.f};
    f32x4 aq0=z,aq1=z,ak0=z,ak1=z;
    #pragma unroll
    for (int ks=0;ks<2;++ks){
      short8v aq = *(const short8v*)(wql + lc*72 + ks*32 + lk*8);
      short8v ak = *(const short8v*)(wkl + lc*72 + ks*32 + lk*8);
      short8v b0 = *(const short8v*)(xtb + (wv*32+lc)*72 + ks*32 + lk*8);
      short8v b1 = *(const short8v*)(xtb + (wv*32+16+lc)*72 + ks*32 + lk*8);
      aq0 = MFMA16(aq,b0,aq0,0,0,0);
      aq1 = MFMA16(aq,b1,aq1,0,0,0);
      ak0 = MFMA16(ak,b0,ak0,0,0,0);
      ak1 = MFMA16(ak,b1,ak1,0,0,0);
    }
    f32x4 q0,q1,k0,k1;
    #pragma unroll
    for (int r=0;r<4;++r){
      float bqv = bql[lk*4+r], bkv = bkl[lk*4+r];
      q0[r]=aq0[r]+bqv; q1[r]=aq1[r]+bqv;
      k0[r]=ak0[r]+bkv; k1[r]=ak1[r]+bkv;
    }
    const int sw = (lc&7)<<4;
    *(unsigned long long*)(QB + ((lc*256      + tcol + lk*8) ^ sw)) = pk4bf(q0);
    *(unsigned long long*)(QB + (((16+lc)*256 + tcol + lk*8) ^ sw)) = pk4bf(q1);
    *(unsigned long long*)(KB + ((lc*256      + tcol + lk*8) ^ sw)) = pk4bf(k0);
    *(unsigned long long*)(KB + (((16+lc)*256 + tcol + lk*8) ^ sw)) = pk4bf(k1);
  }
  __syncthreads();
  const int mt = wv>>1, nt = wv&1;
  const int sw = (lc&7)<<4;
  f32x4 acc = {0.f,0.f,0.f,0.f};
  #pragma unroll
  for (int ks=0;ks<4;++ks){
    short8v a = *(const short8v*)(QB + (((mt*16+lc)*256 + ks*64 + lk*16) ^ sw));
    short8v b = *(const short8v*)(KB + (((nt*16+lc)*256 + ks*64 + lk*16) ^ sw));
    acc = MFMA16(a,b,acc,0,0,0);
  }
  float* Ao = attg + ((size_t)tc*(N_*S_) + ns)*(V_*V_);
  #pragma unroll
  for (int reg=0;reg<4;++reg){
    int v = mt*16 + lk*4 + reg, w = nt*16 + lc;
    if (v<V_ && w<V_) Ao[v*V_+w] = acc[reg];
  }
}

// ---------------- K1b: reduce chunks + softmax(dim=-2) + Aad ----------------
__global__ __launch_bounds__(256) void k_gcn_att2(
    const float* __restrict__ attg, const float* __restrict__ A,
    const float* __restrict__ alphap, float* __restrict__ Aad)
{
  const int ns = blockIdx.x, s = ns % S_, tid = threadIdx.x;
  __shared__ float att[V_*V_];
  for (int i=tid;i<V_*V_;i+=256){
    float acc=0.f;
    #pragma unroll
    for (int tcc=0;tcc<NCHUNK;++tcc) acc += attg[((size_t)tcc*(N_*S_) + ns)*(V_*V_) + i];
    att[i]=acc;
  }
  __syncthreads();
  if (tid<V_){
    const int w=tid; const float inv=1.f/(IG*T_);
    float mx=-1e30f;
    for (int v=0;v<V_;++v) mx=fmaxf(mx, att[v*V_+w]*inv);
    float sum=0.f;
    for (int v=0;v<V_;++v){ float e=expf(att[v*V_+w]*inv-mx); att[v*V_+w]=e; sum+=e; }
    float rs=1.f/sum;
    for (int v=0;v<V_;++v) att[v*V_+w]*=rs;
  }
  __syncthreads();
  const float alpha=alphap[0];
  float* Ao = Aad + (size_t)ns*V_*V_;
  for (int i=tid;i<V_*V_;i+=256) Ao[i]=A[s*V_*V_+i]+alpha*att[i];
}

// ---------------- K2: 4-t tile MFMA graph conv + Wf + bn + residual + relu ----------------
__global__ __launch_bounds__(256) void k_gcn_y(
    const float* __restrict__ x, const float* __restrict__ Aad,
    const float* __restrict__ Wf, const float* __restrict__ bfp,
    const float* __restrict__ g_gamma, const float* __restrict__ g_beta,
    __hip_bfloat16* __restrict__ y1)
{
  const int tc=blockIdx.x, n=blockIdx.y, tid=threadIdx.x;
  const int wv=tid>>6, l=tid&63, lc=l&15, lk=l>>4;
  __shared__ __align__(16) short xtb[64*136];   // [c][t*32+v], v-pad zeroed
  __shared__ __align__(16) short AsT[3*32*40];  // [s][w][v], v-pad zeroed
  __shared__ __align__(16) short aggT[112*200]; // [tv][sc], rows 100..111 zeroed
  const float* xn = x + (size_t)n*C_*TV;
  const int tv0 = tc*100;
  for (int i=tid;i<64*100;i+=256){
    int c=i/100, tv=i%100, t=tv/25, v=tv%25;
    xtb[c*136 + t*32 + v] = (short)f2bu(xn[(size_t)c*TV + tv0 + tv]);
  }
  for (int i=tid;i<64*28;i+=256){ int c=i/28, r=i%28; xtb[c*136 + (r/7)*32 + 25 + (r%7)] = 0; }
  for (int i=tid;i<3*32*7;i+=256){ int sw_=i/7; AsT[sw_*40 + 25 + (i%7)] = 0; }
  const float* Adn = Aad + (size_t)n*S_*V_*V_;
  for (int i=tid;i<S_*V_*V_;i+=256){
    int s=i/625, r=i%625, v=r/25, w=r%25;
    AsT[(s*32+w)*40+v] = (short)f2bu(Adn[i]);
  }
  for (int i=tid;i<12*200;i+=256) aggT[100*200+i]=0;
  __syncthreads();
  {
    const int t = wv;
    for (int s=0;s<S_;++s){
      short8v b0 = *(const short8v*)(AsT + (s*32+lc)*40 + lk*8);
      short8v b1 = *(const short8v*)(AsT + (s*32+16+lc)*40 + lk*8);
      #pragma unroll
      for (int mt=0;mt<4;++mt){
        short8v a = *(const short8v*)(xtb + (mt*16+lc)*136 + t*32 + lk*8);
        f32x4 z={0.f,0.f,0.f,0.f};
        f32x4 acc0 = MFMA16(a,b0,z,0,0,0);
        f32x4 acc1 = MFMA16(a,b1,z,0,0,0);
        *(unsigned long long*)(aggT + (t*25+lc)*200 + s*64 + mt*16 + lk*4) = pk4bf(acc0);
        if (lc<9)
          *(unsigned long long*)(aggT + (t*25+16+lc)*200 + s*64 + mt*16 + lk*4) = pk4bf(acc1);
      }
    }
  }
  short8v af[6];
  #pragma unroll
  for (int ks=0;ks<6;++ks){
    const int s = ks>>1, c0 = (ks&1)*32 + lk*8;
    const float* wr = Wf + ((size_t)s*C_ + wv*16+lc)*C_ + c0;
    short8v t8;
    #pragma unroll
    for (int j=0;j<8;++j) t8[j] = (short)f2bu(wr[j]);
    af[ks]=t8;
  }
  __syncthreads();
  f32x4 acc[7];
  #pragma unroll
  for (int dt=0;dt<7;++dt) acc[dt]=(f32x4){0.f,0.f,0.f,0.f};
  #pragma unroll
  for (int dt=0;dt<7;++dt){
    #pragma unroll
    for (int ks=0;ks<6;++ks){
      short8v b = *(const short8v*)(aggT + (dt*16+lc)*200 + ks*32 + lk*8);
      acc[dt] = MFMA16(af[ks], b, acc[dt],0,0,0);
    }
  }
  const float invs = rsqrtf(1.f+EPSB);
  __hip_bfloat16* yo = y1 + (size_t)n*C_*TV;
  #pragma unroll
  for (int reg=0;reg<4;++reg){
    const int o = wv*16 + lk*4 + reg;
    const float bsum = bfp[o]+bfp[C_+o]+bfp[2*C_+o];
    const float gs = g_gamma[o]*invs, gb = g_beta[o];
    #pragma unroll
    for (int dt=0;dt<7;++dt){
      const int tv = dt*16 + lc;
      if (tv < 100){
        float val = (acc[dt][reg]+bsum)*gs + gb + xn[(size_t)o*TV + tv0 + tv];
        yo[(size_t)o*TV + tv0 + tv] = f2b(fmaxf(val,0.f));
      }
    }
  }
}

// ---------------- K3a: seT[n,c,v] = mean_t y1 ----------------
__global__ __launch_bounds__(256) void k_seT(const __hip_bfloat16* __restrict__ y1,
    float* __restrict__ seT)
{
  const int c=blockIdx.x, n=blockIdx.y, tid=threadIdx.x;
  const int v = tid&31, g = tid>>5;
  __shared__ float red[8][33];
  const __hip_bfloat16* yp = y1 + ((size_t)n*C_+c)*T_*V_;
  float s=0.f;
  if (v < V_){
    #pragma unroll 4
    for (int j=0;j<16;++j){
      int t = g + j*8;
      s += b2f(yp[t*V_+v]);
    }
  }
  red[g][v]=s;
  __syncthreads();
  if (tid < V_){
    float tot=0.f;
    #pragma unroll
    for (int g2=0;g2<8;++g2) tot += red[g2][tid];
    seT[((size_t)n*C_+c)*V_+tid]=tot*(1.f/T_);
  }
}

// ---------------- K3b: sa[n,v] spatial gate ----------------
__global__ __launch_bounds__(64) void k_sa(const float* __restrict__ seT,
    const float* __restrict__ W_sa, const float* __restrict__ b_sa,
    float* __restrict__ sa)
{
  const int n=blockIdx.x, tid=threadIdx.x;
  if (tid>=V_) return;
  const float* se = seT + (size_t)n*C_*V_;
  float acc=b_sa[0];
  for (int c=0;c<C_;++c){
    #pragma unroll
    for (int k=0;k<V_;++k){
      int vv=tid+k-12;  // pad = (V-1)/2 = 12
      if (vv>=0&&vv<V_) acc+=se[c*V_+vv]*W_sa[c*V_+k];
    }
  }
  sa[n*V_+tid]=sigm(acc);
}

// ---------------- K3c: seV[n,c,t] = mean_v y1*(1+sa) ----------------
__global__ __launch_bounds__(256) void k_seV(const __hip_bfloat16* __restrict__ y1,
    const float* __restrict__ sa, float* __restrict__ seV)
{
  const int c=blockIdx.x, n=blockIdx.y, tid=threadIdx.x;
  const int v = tid&31, g = tid>>5;
  __shared__ float sal[32];
  if (tid<32) sal[tid] = (tid<V_)? 1.f+sa[n*V_+tid] : 0.f;
  __syncthreads();
  const __hip_bfloat16* yp = y1 + ((size_t)n*C_+c)*T_*V_;
  float* svo = seV + ((size_t)n*C_+c)*T_;
  const float sv_ = sal[v];
  for (int j=0;j<16;++j){
    int t = g*16 + j;
    float val = (v<V_)? b2f(yp[t*V_+v])*sv_ : 0.f;
    #pragma unroll
    for (int off=16;off;off>>=1) val += __shfl_xor(val, off);
    if (v==0) svo[t]=val*(1.f/V_);
  }
}

// ---------------- K3d: ta[n,t] temporal gate + ca[n,c] channel gate ----------------
__global__ __launch_bounds__(128) void k_ta_ca(const float* __restrict__ seV,
    const float* __restrict__ W_ta, const float* __restrict__ b_ta,
    const float* __restrict__ W_fc1, const float* __restrict__ b_fc1,
    const float* __restrict__ W_fc2, const float* __restrict__ b_fc2,
    float* __restrict__ ta, float* __restrict__ ca)
{
  const int n=blockIdx.x, tid=threadIdx.x;
  __shared__ float tal[T_];
  __shared__ float scl[C_];
  __shared__ float h1[32];
  const float* sv = seV + (size_t)n*C_*T_;
  {
    float acc=b_ta[0];
    for (int c=0;c<C_;++c){
      #pragma unroll
      for (int k=0;k<9;++k){
        int tt=tid+k-4;
        if (tt>=0&&tt<T_) acc+=sv[c*T_+tt]*W_ta[c*9+k];
      }
    }
    float s=sigm(acc);
    tal[tid]=s; ta[n*T_+tid]=s;
  }
  __syncthreads();
  if (tid<C_){
    float acc=0.f;
    for (int t=0;t<T_;++t) acc += sv[tid*T_+t]*(1.f+tal[t]);
    scl[tid]=acc*(1.f/T_);
  }
  __syncthreads();
  if (tid<32){
    float acc=b_fc1[tid];
    for (int c=0;c<C_;++c) acc += scl[c]*W_fc1[tid*C_+c];
    h1[tid]=fmaxf(acc,0.f);
  }
  __syncthreads();
  if (tid<C_){
    float acc=b_fc2[tid];
    for (int j=0;j<32;++j) acc += h1[j]*W_fc2[tid*32+j];
    ca[n*C_+tid]=sigm(acc);
  }
}

// ---------------- K4: 4-t tile MFMA xa/gates + q/k/v projections ----------------
// grid (T_/4, N_). Weights staged once per 4 t's; wave wv owns t = tc*4+wv.
__global__ __launch_bounds__(256) void k_xa_qkv(
    const __hip_bfloat16* __restrict__ y1, const float* __restrict__ pos_emb,
    const float* __restrict__ sa, const float* __restrict__ ta, const float* __restrict__ ca,
    const float* __restrict__ Wq_h, const float* __restrict__ bq_h,
    const float* __restrict__ Wk_h, const float* __restrict__ bk_h,
    const float* __restrict__ Wv_h, const float* __restrict__ bv_h,
    __hip_bfloat16* __restrict__ xa, __hip_bfloat16* __restrict__ qb,
    __hip_bfloat16* __restrict__ kb, __hip_bfloat16* __restrict__ vb)
{
  const int tc=blockIdx.x, n=blockIdx.y, tid=threadIdx.x;
  const int wv=tid>>6, l=tid&63, lc=l&15, lk=l>>4;
  __shared__ __align__(16) short w3[192*72];      // [mu][c], mu = which*64+ho
  __shared__ __align__(16) short xalT[4][32*72];  // per t: [v][c], v>=25 zeroed
  __shared__ float bl[192];
  __shared__ float sal[32], cal[64], tgs[4];
  for (int i=tid;i<192*64;i+=256){
    int mu=i>>6, c=i&63, which=mu/C_, ho=mu%C_;
    const float* W = which==0?Wq_h:(which==1?Wk_h:Wv_h);
    w3[mu*72+c] = (short)f2bu(W[(size_t)ho*C_+c]);
  }
  if (tid<192){
    int which=tid/C_, ho=tid%C_;
    bl[tid] = (which==0?bq_h:(which==1?bk_h:bv_h))[ho];
  }
  if (tid<32) sal[tid] = (tid<V_)? 1.f+sa[n*V_+tid] : 0.f;
  if (tid>=32 && tid<96) cal[tid-32] = 1.f+ca[n*C_+tid-32];
  if (tid>=96 && tid<100) tgs[tid-96] = 1.f+ta[n*T_+tc*4+(tid-96)];
  for (int i=tid;i<4*7*72;i+=256){
    int tl=i/(7*72), r=i%(7*72);
    xalT[tl][25*72 + r] = 0;   // rows 25..31 contiguous
  }
  __syncthreads();
  const int tv0 = tc*100;
  const __hip_bfloat16* y1n = y1 + (size_t)n*C_*TV;
  __hip_bfloat16* xan = xa + (size_t)n*C_*TV;
  for (int i=tid;i<64*100;i+=256){
    int c=i/100, tv=i%100, tl=tv/25, v=tv%25;
    float val = b2f(y1n[(size_t)c*TV + tv0 + tv]) * sal[v] * tgs[tl] * cal[c]
              + pos_emb[(size_t)(tc*4+tl)*CV + c*V_ + v];
    xan[(size_t)c*TV + tv0 + tv] = f2b(val);
    xalT[tl][v*72 + c] = (short)f2bu(val);
  }
  __syncthreads();
  const int t = tc*4 + wv;    // wave wv owns this t
  short8v bf_[2][2];
  #pragma unroll
  for (int ks=0;ks<2;++ks){
    bf_[ks][0] = *(const short8v*)(&xalT[wv][lc*72      + ks*32 + lk*8]);
    bf_[ks][1] = *(const short8v*)(&xalT[wv][(16+lc)*72 + ks*32 + lk*8]);
  }
  #pragma unroll
  for (int mt=0;mt<12;++mt){
    f32x4 acc0 = {0.f,0.f,0.f,0.f}, acc1 = {0.f,0.f,0.f,0.f};
    #pragma unroll
    for (int ks=0;ks<2;++ks){
      short8v a = *(const short8v*)(w3 + (mt*16+lc)*72 + ks*32 + lk*8);
      acc0 = MFMA16(a, bf_[ks][0], acc0,0,0,0);
      acc1 = MFMA16(a, bf_[ks][1], acc1,0,0,0);
    }
    #pragma unroll
    for (int reg=0;reg<4;++reg){
      const int mu = mt*16 + lk*4 + reg;
      const int which = mt>>2;              // = mu/64, constant per unrolled mt
      const int ho = mu & 63, h = ho>>3, o = ho&7;
      __hip_bfloat16* dst = (which==0?qb:(which==1?kb:vb))
                            + (((size_t)n*H_+h)*T_+t)*D_ + o*V_;
      const float bb = bl[mu];
      dst[lc] = f2b(acc0[reg]+bb);
      if (lc < 9) dst[16+lc] = f2b(acc1[reg]+bb);
    }
  }
}

// ---------------- K5: MFMA flash causal MHA ----------------
__global__ __launch_bounds__(256) void k_attn(
    const __hip_bfloat16* __restrict__ qb, const __hip_bfloat16* __restrict__ kb,
    const __hip_bfloat16* __restrict__ vb, __hip_bfloat16* __restrict__ oh)
{
  const int bx = blockIdx.x;
  const int nh = blockIdx.z*H_ + blockIdx.y;
  const int tid = threadIdx.x;
  const int wv = tid>>6, l = tid&63;
  const int lc = l&15, lg = l>>4;
  __shared__ __align__(16) char KlB[32*512];      // [key][d(256sh)] bf16, byte^=(key&7)<<4
  __shared__ __align__(16) short VT[208*40];      // [d][key] bf16
  __shared__ __align__(16) short Pl[64*40];       // [qloc][key] bf16 (per-wave slices)
  const __hip_bfloat16* qg_ = qb + (size_t)nh*T_*D_;
  const __hip_bfloat16* kg_ = kb + (size_t)nh*T_*D_;
  const __hip_bfloat16* vg_ = vb + (size_t)nh*T_*D_;
  __hip_bfloat16* og_ = oh + (size_t)nh*T_*D_;
  const float scale = 0.0707106781f;  // 1/sqrt(200)

  for (int i=tid;i<32*12;i+=256){
    int key=i/12, j=i%12;
    *(unsigned int*)(KlB + ((key*512 + 400 + j*4) ^ ((key&7)<<4))) = 0u;
  }
  for (int i=tid;i<8*40;i+=256) VT[200*40 + i] = 0;

  const int qrow = bx*64 + wv*16 + lc;
  short8v qf[7];
  {
    const short8v* qs8 = (const short8v*)(qg_ + (size_t)qrow*D_);
    #pragma unroll
    for (int ks=0;ks<7;++ks) qf[ks] = qs8[ks*4 + lg];
  }
  f32x4 oacc[13];
  #pragma unroll
  for (int i=0;i<13;++i) oacc[i] = (f32x4){0.f,0.f,0.f,0.f};
  float m[4], lsm[4];
  #pragma unroll
  for (int r=0;r<4;++r){ m[r]=-1e30f; lsm[r]=0.f; }

  const int ntiles = (bx==0)? 2 : 4;
  for (int kt=0; kt<ntiles; ++kt){
    const int j0 = kt*32;
    __syncthreads();
    {
      const short8v* ks8 = (const short8v*)(kg_ + (size_t)j0*D_);
      for (int i=tid;i<32*25;i+=256){
        int row=i/25, w=i%25;
        *(short8v*)(KlB + ((row*512 + w*16) ^ ((row&7)<<4))) = ks8[i];
      }
      const short8v* vs8 = (const short8v*)(vg_ + (size_t)j0*D_);
      for (int i=tid;i<32*25;i+=256){
        int row=i&31, w4=i>>5;
        short8v u = vs8[row*25 + w4];
        #pragma unroll
        for (int j=0;j<8;++j) VT[(w4*8+j)*40 + row] = u[j];
      }
    }
    __syncthreads();
    const bool active = (j0 <= bx*64 + wv*16 + 15);
    if (active){
      f32x4 s0 = {0.f,0.f,0.f,0.f}, s1 = {0.f,0.f,0.f,0.f};
      #pragma unroll
      for (int ks=0;ks<7;++ks){
        short8v b0 = *(const short8v*)(KlB + ((lc*512      + ks*64 + lg*16) ^ ((lc&7)<<4)));
        short8v b1 = *(const short8v*)(KlB + (((16+lc)*512 + ks*64 + lg*16) ^ ((lc&7)<<4)));
        s0 = MFMA16(qf[ks], b0, s0,0,0,0);
        s1 = MFMA16(qf[ks], b1, s1,0,0,0);
      }
      float fr[4];
      #pragma unroll
      for (int r=0;r<4;++r){
        const int qg = bx*64 + wv*16 + lg*4 + r;
        float v0 = (j0+lc    <= qg) ? s0[r]*scale : -1e30f;
        float v1 = (j0+16+lc <= qg) ? s1[r]*scale : -1e30f;
        float mx = fmaxf(v0,v1);
        #pragma unroll
        for (int off=1;off<16;off<<=1) mx = fmaxf(mx, __shfl_xor(mx, off));
        float mn = fmaxf(m[r], mx);
        fr[r] = __expf(m[r]-mn);
        float p0 = __expf(v0-mn), p1 = __expf(v1-mn);
        float ts = p0+p1;
        #pragma unroll
        for (int off=1;off<16;off<<=1) ts += __shfl_xor(ts, off);
        lsm[r] = lsm[r]*fr[r] + ts;
        m[r] = mn;
        Pl[(wv*16 + lg*4 + r)*40 + lc]      = (short)f2bu(p0);
        Pl[(wv*16 + lg*4 + r)*40 + 16 + lc] = (short)f2bu(p1);
      }
      #pragma unroll
      for (int dt=0;dt<13;++dt){
        #pragma unroll
        for (int r=0;r<4;++r) oacc[dt][r] *= fr[r];
      }
      short8v pa = *(const short8v*)(Pl + (wv*16+lc)*40 + lg*8);
      #pragma unroll
      for (int dt=0;dt<13;++dt){
        short8v b = *(const short8v*)(VT + (dt*16+lc)*40 + lg*8);
        oacc[dt] = MFMA16(pa, b, oacc[dt],0,0,0);
      }
    }
  }
  float rl[4];
  #pragma unroll
  for (int r=0;r<4;++r) rl[r] = 1.f/lsm[r];
  #pragma unroll
  for (int dt=0;dt<13;++dt){
    const int d = dt*16 + lc;
    if (d < D_){
      #pragma unroll
      for (int r=0;r<4;++r){
        const int q = bx*64 + wv*16 + lg*4 + r;
        og_[(size_t)q*D_ + d] = f2b(oacc[dt][r]*rl[r]);
      }
    }
  }
}

// ---------------- K7: 8-t tile MFMA out kernel ----------------
__global__ __launch_bounds__(256) void k_out(
    const __hip_bfloat16* __restrict__ oh, const __hip_bfloat16* __restrict__ xa,
    const float* __restrict__ x, const float* __restrict__ W_ffn,
    const float* __restrict__ b_ffn, const float* __restrict__ m_gamma,
    const float* __restrict__ m_beta, float* __restrict__ out)
{
  const int tc = blockIdx.x, n = blockIdx.y, tid = threadIdx.x;
  const int wv = tid>>6, l = tid&63, lc = l&15, lg = l>>4;
  __shared__ __align__(16) short wfl[64*72];   // W_ffn bf16 [o][c]
  __shared__ __align__(16) short zT[208*72];   // z^T bf16 [tv][c], rows 200..207 zeroed
  __shared__ float bn_s[64], bn_b[64], bff[64];
  const float invs = rsqrtf(1.f+EPSB);
  for (int i=tid;i<64*64;i+=256){
    int o=i>>6, c=i&63;
    wfl[o*72+c] = (short)f2bu(W_ffn[i]);
  }
  if (tid<64){ bn_s[tid]=m_gamma[tid]*invs; bn_b[tid]=m_beta[tid]; bff[tid]=b_ffn[tid]; }
  for (int i=tid;i<8*72;i+=256) zT[200*72+i]=0;
  __syncthreads();
  const int tv0 = tc*200;
  const __hip_bfloat16* xan = xa + (size_t)n*C_*TV;
  for (int i=tid;i<64*200;i+=256){
    int c=i/200, tv=i%200;
    int t = tc*8 + tv/25, v = tv%25;
    float xav = b2f(xan[(size_t)c*TV + tv0 + tv]);
    int h=c>>3, oi=c&7;
    float ohv = b2f(oh[(((size_t)n*H_+h)*T_+t)*D_ + oi*V_ + v]);
    zT[tv*72 + c] = (short)f2bu(bn_s[c]*ohv + bn_b[c] + xav);
  }
  __syncthreads();
  const int lk = lg;
  short8v af0 = *(const short8v*)(wfl + (wv*16+lc)*72 + lk*8);
  short8v af1 = *(const short8v*)(wfl + (wv*16+lc)*72 + 32 + lk*8);
  f32x4 acc[13];
  #pragma unroll
  for (int dt=0;dt<13;++dt) acc[dt] = (f32x4){0.f,0.f,0.f,0.f};
  #pragma unroll
  for (int dt=0;dt<13;++dt){
    short8v b0 = *(const short8v*)(zT + (dt*16+lc)*72 + lk*8);
    short8v b1 = *(const short8v*)(zT + (dt*16+lc)*72 + 32 + lk*8);
    acc[dt] = MFMA16(af0, b0, acc[dt],0,0,0);
    acc[dt] = MFMA16(af1, b1, acc[dt],0,0,0);
  }
  const float* xn = x + (size_t)n*C_*TV;
  float* outn = out + (size_t)n*C_*TV;
  #pragma unroll
  for (int dt=0;dt<13;++dt){
    const int tv = dt*16 + lc;
    if (tv < 200){
      #pragma unroll
      for (int reg=0;reg<4;++reg){
        const int o = wv*16 + lg*4 + reg;
        float z2 = fmaxf(acc[dt][reg] + bff[o], 0.f) + b2f(xan[(size_t)o*TV + tv0 + tv]);
        float z3 = bn_s[o]*z2 + bn_b[o];
        outn[(size_t)o*TV + tv0 + tv] = fmaxf(z3 + xn[(size_t)o*TV + tv0 + tv], 0.f);
      }
    }
  }
}

extern "C" void kernel_launch(void* const* d_in, const int* in_sizes, int n_in,
                              void* d_out, int out_size, void* d_ws, size_t ws_size,
                              hipStream_t stream) {
  const float* x      = (const float*)d_in[0];
  const float* A      = (const float*)d_in[1];
  const float* alphap = (const float*)d_in[2];
  const float* Wq     = (const float*)d_in[3];
  const float* bq     = (const float*)d_in[4];
  const float* Wk     = (const float*)d_in[5];
  const float* bk     = (const float*)d_in[6];
  const float* Wf     = (const float*)d_in[7];
  const float* bfp    = (const float*)d_in[8];
  const float* g_gamma= (const float*)d_in[9];
  const float* g_beta = (const float*)d_in[10];
  const float* W_sa   = (const float*)d_in[11];
  const float* b_sa   = (const float*)d_in[12];
  const float* W_ta   = (const float*)d_in[13];
  const float* b_ta   = (const float*)d_in[14];
  const float* W_fc1  = (const float*)d_in[15];
  const float* b_fc1  = (const float*)d_in[16];
  const float* W_fc2  = (const float*)d_in[17];
  const float* b_fc2  = (const float*)d_in[18];
  const float* pos_emb= (const float*)d_in[19];
  const float* Wq_h   = (const float*)d_in[20];
  const float* bq_h   = (const float*)d_in[21];
  const float* Wk_h   = (const float*)d_in[22];
  const float* bk_h   = (const float*)d_in[23];
  const float* Wv_h   = (const float*)d_in[24];
  const float* bv_h   = (const float*)d_in[25];
  const float* W_ffn  = (const float*)d_in[26];
  const float* b_ffn  = (const float*)d_in[27];
  const float* m_gamma= (const float*)d_in[28];
  const float* m_beta = (const float*)d_in[29];
  float* out = (float*)d_out;

  float* ws   = (float*)d_ws;
  float* Aad  = ws;                    // 128*3*625   = 240000
  float* seT  = Aad + 240000;          // 128*64*25   = 204800
  float* seV  = seT + 204800;          // 128*64*128  = 1048576
  float* sa   = seV + 1048576;         // 128*25      = 3200
  float* ta   = sa  + 3200;            // 128*128     = 16384
  float* ca   = ta  + 16384;           // 128*64      = 8192
  __hip_bfloat16* y1 = (__hip_bfloat16*)(ca + 8192);  // 26214400 elems (reused as oh)
  __hip_bfloat16* xa = y1 + (size_t)26214400;
  __hip_bfloat16* qb = xa + (size_t)26214400;
  __hip_bfloat16* kb = qb + (size_t)26214400;
  __hip_bfloat16* vb = kb + (size_t)26214400;
  __hip_bfloat16* oh = y1;  // reuse: y1 dead after k_xa_qkv
  float* attg = (float*)y1; // scratch before y1 is written (16*384*625*4 = 15.4MB)

  k_gcn_att1<<<dim3(NCHUNK, N_*S_), 256, 0, stream>>>(x, Wq, bq, Wk, bk, attg);
  k_gcn_att2<<<N_*S_, 256, 0, stream>>>(attg, A, alphap, Aad);
  k_gcn_y<<<dim3(T_/4, N_), 256, 0, stream>>>(x, Aad, Wf, bfp, g_gamma, g_beta, y1);
  k_seT<<<dim3(C_, N_), 256, 0, stream>>>(y1, seT);
  k_sa<<<N_, 64, 0, stream>>>(seT, W_sa, b_sa, sa);
  k_seV<<<dim3(C_, N_), 256, 0, stream>>>(y1, sa, seV);
  k_ta_ca<<<N_, 128, 0, stream>>>(seV, W_ta, b_ta, W_fc1, b_fc1, W_fc2, b_fc2, ta, ca);
  k_xa_qkv<<<dim3(T_/4, N_), 256, 0, stream>>>(y1, pos_emb, sa, ta, ca,
      Wq_h, bq_h, Wk_h, bk_h, Wv_h, bv_h, xa, qb, kb, vb);
  k_attn<<<dim3(2, H_, N_), 256, 0, stream>>>(qb, kb, vb, oh);
  k_out<<<dim3(T_/8, N_), 256, 0, stream>>>(oh, xa, x, W_ffn, b_ffn, m_gamma, m_beta, out);
}

// Round 10
// 769.414 us; speedup vs baseline: 6.1685x; 1.0270x over previous
//
#include <hip/hip_runtime.h>
#include <hip/hip_bf16.h>

#define N_ 128
#define C_ 64
#define T_ 128
#define V_ 25
#define S_ 3
#define IG 16
#define IH 8
#define H_ 8
#define D_ 200   // IH*V
#define CV 1600  // C_*V_
#define TV 3200  // T_*V_
#define EPSB 1e-5f
#define NCHUNK 16
#define TPC 8    // t per chunk (k_gcn_att1)

typedef __attribute__((ext_vector_type(8))) short short8v;
typedef __attribute__((ext_vector_type(4))) float f32x4;
#define MFMA16 __builtin_amdgcn_mfma_f32_16x16x32_bf16

__device__ __forceinline__ float sigm(float x){ return 1.f/(1.f+expf(-x)); }
__device__ __forceinline__ float b2f(__hip_bfloat16 b){ return __bfloat162float(b); }
__device__ __forceinline__ __hip_bfloat16 f2b(float f){ return __float2bfloat16(f); }
__device__ __forceinline__ float ubl(unsigned int u){ return __uint_as_float(u<<16); }
__device__ __forceinline__ float ubh(unsigned int u){ return __uint_as_float(u & 0xffff0000u); }
__device__ __forceinline__ unsigned short f2bu(float f){
  unsigned int u = __float_as_uint(f);
  u += 0x7fff + ((u>>16)&1);
  return (unsigned short)(u>>16);
}
__device__ __forceinline__ unsigned long long pk4bf(f32x4 v){
  unsigned long long a = f2bu(v[0]);
  unsigned long long b = f2bu(v[1]);
  unsigned long long c = f2bu(v[2]);
  unsigned long long d = f2bu(v[3]);
  return a | (b<<16) | (c<<32) | (d<<48);
}

// ---------------- K1a: MFMA adaptive graph attention partials ----------------
__global__ __launch_bounds__(256) void k_gcn_att1(
    const float* __restrict__ x,
    const float* __restrict__ Wq, const float* __restrict__ bq,
    const float* __restrict__ Wk, const float* __restrict__ bk,
    float* __restrict__ attg)
{
  const int tc = blockIdx.x, ns = blockIdx.y, n = ns / S_, s = ns % S_;
  const int tid = threadIdx.x;
  const int wv = tid>>6, l = tid&63, lc = l&15, lk = l>>4;
  __shared__ __align__(16) short wql[16*72], wkl[16*72];
  __shared__ float bql[16], bkl[16];
  __shared__ __align__(16) short xtb[4*32*72];   // [tl][v(32)][c(72)], v>=25 zeroed
  __shared__ __align__(16) char QB[32*256];      // [v][K=128 bf16], byte^=(v&7)<<4
  __shared__ __align__(16) char KB[32*256];
  for (int i=tid;i<IG*C_;i+=256){
    int ii=i>>6, c=i&63;
    wql[ii*72+c] = (short)f2bu(Wq[s*IG*C_+i]);
    wkl[ii*72+c] = (short)f2bu(Wk[s*IG*C_+i]);
  }
  if (tid<16){ bql[tid]=bq[s*IG+tid]; bkl[tid]=bk[s*IG+tid]; }
  for (int i=tid;i<4*7*72;i+=256){
    int tl=i/(7*72), r=i%(7*72);
    xtb[(tl*32+25)*72 + r] = 0;
  }
  const float* xn = x + (size_t)n*C_*T_*V_;
  const int t0 = tc*TPC;
  #pragma unroll
  for (int tg=0; tg<2; ++tg){
    __syncthreads();
    for (int i=tid;i<4*1600;i+=256){
      int tl=i/1600, r=i%1600, c=r/25, v=r%25;
      xtb[(tl*32+v)*72 + c] = (short)f2bu(xn[(size_t)c*TV + (t0+tg*4+tl)*V_ + v]);
    }
    __syncthreads();
    const int tcol = (tg*4+wv)*32;
    f32x4 z={0.f,0.f,0.f,0.f};
    f32x4 aq0=z,aq1=z,ak0=z,ak1=z;
    #pragma unroll
    for (int ks=0;ks<2;++ks){
      short8v aq = *(const short8v*)(wql + lc*72 + ks*32 + lk*8);
      short8v ak = *(const short8v*)(wkl + lc*72 + ks*32 + lk*8);
      short8v b0 = *(const short8v*)(xtb + (wv*32+lc)*72 + ks*32 + lk*8);
      short8v b1 = *(const short8v*)(xtb + (wv*32+16+lc)*72 + ks*32 + lk*8);
      aq0 = MFMA16(aq,b0,aq0,0,0,0);
      aq1 = MFMA16(aq,b1,aq1,0,0,0);
      ak0 = MFMA16(ak,b0,ak0,0,0,0);
      ak1 = MFMA16(ak,b1,ak1,0,0,0);
    }
    f32x4 q0,q1,k0,k1;
    #pragma unroll
    for (int r=0;r<4;++r){
      float bqv = bql[lk*4+r], bkv = bkl[lk*4+r];
      q0[r]=aq0[r]+bqv; q1[r]=aq1[r]+bqv;
      k0[r]=ak0[r]+bkv; k1[r]=ak1[r]+bkv;
    }
    const int sw = (lc&7)<<4;
    *(unsigned long long*)(QB + ((lc*256      + tcol + lk*8) ^ sw)) = pk4bf(q0);
    *(unsigned long long*)(QB + (((16+lc)*256 + tcol + lk*8) ^ sw)) = pk4bf(q1);
    *(unsigned long long*)(KB + ((lc*256      + tcol + lk*8) ^ sw)) = pk4bf(k0);
    *(unsigned long long*)(KB + (((16+lc)*256 + tcol + lk*8) ^ sw)) = pk4bf(k1);
  }
  __syncthreads();
  const int mt = wv>>1, nt = wv&1;
  const int sw = (lc&7)<<4;
  f32x4 acc = {0.f,0.f,0.f,0.f};
  #pragma unroll
  for (int ks=0;ks<4;++ks){
    short8v a = *(const short8v*)(QB + (((mt*16+lc)*256 + ks*64 + lk*16) ^ sw));
    short8v b = *(const short8v*)(KB + (((nt*16+lc)*256 + ks*64 + lk*16) ^ sw));
    acc = MFMA16(a,b,acc,0,0,0);
  }
  float* Ao = attg + ((size_t)tc*(N_*S_) + ns)*(V_*V_);
  #pragma unroll
  for (int reg=0;reg<4;++reg){
    int v = mt*16 + lk*4 + reg, w = nt*16 + lc;
    if (v<V_ && w<V_) Ao[v*V_+w] = acc[reg];
  }
}

// ---------------- K1b: reduce chunks + softmax(dim=-2) + Aad ----------------
__global__ __launch_bounds__(256) void k_gcn_att2(
    const float* __restrict__ attg, const float* __restrict__ A,
    const float* __restrict__ alphap, float* __restrict__ Aad)
{
  const int ns = blockIdx.x, s = ns % S_, tid = threadIdx.x;
  __shared__ float att[V_*V_];
  for (int i=tid;i<V_*V_;i+=256){
    float acc=0.f;
    #pragma unroll
    for (int tcc=0;tcc<NCHUNK;++tcc) acc += attg[((size_t)tcc*(N_*S_) + ns)*(V_*V_) + i];
    att[i]=acc;
  }
  __syncthreads();
  if (tid<V_){
    const int w=tid; const float inv=1.f/(IG*T_);
    float mx=-1e30f;
    for (int v=0;v<V_;++v) mx=fmaxf(mx, att[v*V_+w]*inv);
    float sum=0.f;
    for (int v=0;v<V_;++v){ float e=expf(att[v*V_+w]*inv-mx); att[v*V_+w]=e; sum+=e; }
    float rs=1.f/sum;
    for (int v=0;v<V_;++v) att[v*V_+w]*=rs;
  }
  __syncthreads();
  const float alpha=alphap[0];
  float* Ao = Aad + (size_t)ns*V_*V_;
  for (int i=tid;i<V_*V_;i+=256) Ao[i]=A[s*V_*V_+i]+alpha*att[i];
}

// ---------------- K2: 4-t tile MFMA graph conv + Wf + bn + residual + relu ----------------
__global__ __launch_bounds__(256) void k_gcn_y(
    const float* __restrict__ x, const float* __restrict__ Aad,
    const float* __restrict__ Wf, const float* __restrict__ bfp,
    const float* __restrict__ g_gamma, const float* __restrict__ g_beta,
    __hip_bfloat16* __restrict__ y1)
{
  const int tc=blockIdx.x, n=blockIdx.y, tid=threadIdx.x;
  const int wv=tid>>6, l=tid&63, lc=l&15, lk=l>>4;
  __shared__ __align__(16) short xtb[64*136];   // [c][t*32+v], v-pad zeroed
  __shared__ __align__(16) short AsT[3*32*40];  // [s][w][v], v-pad zeroed
  __shared__ __align__(16) short aggT[112*200]; // [tv][sc], rows 100..111 zeroed
  const float* xn = x + (size_t)n*C_*TV;
  const int tv0 = tc*100;
  // stage x: float4 vectorized (alignment: (c*3200+tc*100+4k)*4 % 16 == 0)
  for (int i=tid;i<64*25;i+=256){
    int c=i/25, a=i%25, tv4=a*4;
    float4 xv4 = *(const float4*)(xn + (size_t)c*TV + tv0 + tv4);
    float xv[4] = {xv4.x, xv4.y, xv4.z, xv4.w};
    #pragma unroll
    for (int j=0;j<4;++j){
      int tv=tv4+j, t=tv/25, v=tv-t*25;
      xtb[c*136 + t*32 + v] = (short)f2bu(xv[j]);
    }
  }
  for (int i=tid;i<64*28;i+=256){ int c=i/28, r=i%28; xtb[c*136 + (r/7)*32 + 25 + (r%7)] = 0; }
  for (int i=tid;i<3*32*7;i+=256){ int sw_=i/7; AsT[sw_*40 + 25 + (i%7)] = 0; }
  const float* Adn = Aad + (size_t)n*S_*V_*V_;
  for (int i=tid;i<S_*V_*V_;i+=256){
    int s=i/625, r=i%625, v=r/25, w=r%25;
    AsT[(s*32+w)*40+v] = (short)f2bu(Adn[i]);
  }
  for (int i=tid;i<12*200;i+=256) aggT[100*200+i]=0;
  __syncthreads();
  {
    const int t = wv;
    for (int s=0;s<S_;++s){
      short8v b0 = *(const short8v*)(AsT + (s*32+lc)*40 + lk*8);
      short8v b1 = *(const short8v*)(AsT + (s*32+16+lc)*40 + lk*8);
      #pragma unroll
      for (int mt=0;mt<4;++mt){
        short8v a = *(const short8v*)(xtb + (mt*16+lc)*136 + t*32 + lk*8);
        f32x4 z={0.f,0.f,0.f,0.f};
        f32x4 acc0 = MFMA16(a,b0,z,0,0,0);
        f32x4 acc1 = MFMA16(a,b1,z,0,0,0);
        *(unsigned long long*)(aggT + (t*25+lc)*200 + s*64 + mt*16 + lk*4) = pk4bf(acc0);
        if (lc<9)
          *(unsigned long long*)(aggT + (t*25+16+lc)*200 + s*64 + mt*16 + lk*4) = pk4bf(acc1);
      }
    }
  }
  short8v af[6];
  #pragma unroll
  for (int ks=0;ks<6;++ks){
    const int s = ks>>1, c0 = (ks&1)*32 + lk*8;
    const float* wr = Wf + ((size_t)s*C_ + wv*16+lc)*C_ + c0;
    short8v t8;
    #pragma unroll
    for (int j=0;j<8;++j) t8[j] = (short)f2bu(wr[j]);
    af[ks]=t8;
  }
  __syncthreads();
  f32x4 acc[7];
  #pragma unroll
  for (int dt=0;dt<7;++dt) acc[dt]=(f32x4){0.f,0.f,0.f,0.f};
  #pragma unroll
  for (int dt=0;dt<7;++dt){
    #pragma unroll
    for (int ks=0;ks<6;++ks){
      short8v b = *(const short8v*)(aggT + (dt*16+lc)*200 + ks*32 + lk*8);
      acc[dt] = MFMA16(af[ks], b, acc[dt],0,0,0);
    }
  }
  const float invs = rsqrtf(1.f+EPSB);
  __hip_bfloat16* yo = y1 + (size_t)n*C_*TV;
  #pragma unroll
  for (int reg=0;reg<4;++reg){
    const int o = wv*16 + lk*4 + reg;
    const float bsum = bfp[o]+bfp[C_+o]+bfp[2*C_+o];
    const float gs = g_gamma[o]*invs, gb = g_beta[o];
    #pragma unroll
    for (int dt=0;dt<7;++dt){
      const int tv = dt*16 + lc;
      if (tv < 100){
        float val = (acc[dt][reg]+bsum)*gs + gb + xn[(size_t)o*TV + tv0 + tv];
        yo[(size_t)o*TV + tv0 + tv] = f2b(fmaxf(val,0.f));
      }
    }
  }
}

// ---------------- K3a: seT[n,c,v] = mean_t y1 ----------------
__global__ __launch_bounds__(256) void k_seT(const __hip_bfloat16* __restrict__ y1,
    float* __restrict__ seT)
{
  const int c=blockIdx.x, n=blockIdx.y, tid=threadIdx.x;
  const int v = tid&31, g = tid>>5;
  __shared__ float red[8][33];
  const __hip_bfloat16* yp = y1 + ((size_t)n*C_+c)*T_*V_;
  float s=0.f;
  if (v < V_){
    #pragma unroll 4
    for (int j=0;j<16;++j){
      int t = g + j*8;
      s += b2f(yp[t*V_+v]);
    }
  }
  red[g][v]=s;
  __syncthreads();
  if (tid < V_){
    float tot=0.f;
    #pragma unroll
    for (int g2=0;g2<8;++g2) tot += red[g2][tid];
    seT[((size_t)n*C_+c)*V_+tid]=tot*(1.f/T_);
  }
}

// ---------------- K3b: sa[n,v] spatial gate ----------------
__global__ __launch_bounds__(64) void k_sa(const float* __restrict__ seT,
    const float* __restrict__ W_sa, const float* __restrict__ b_sa,
    float* __restrict__ sa)
{
  const int n=blockIdx.x, tid=threadIdx.x;
  if (tid>=V_) return;
  const float* se = seT + (size_t)n*C_*V_;
  float acc=b_sa[0];
  for (int c=0;c<C_;++c){
    #pragma unroll
    for (int k=0;k<V_;++k){
      int vv=tid+k-12;  // pad = (V-1)/2 = 12
      if (vv>=0&&vv<V_) acc+=se[c*V_+vv]*W_sa[c*V_+k];
    }
  }
  sa[n*V_+tid]=sigm(acc);
}

// ---------------- K3c: seV[n,c,t] = mean_v y1*(1+sa) ----------------
__global__ __launch_bounds__(256) void k_seV(const __hip_bfloat16* __restrict__ y1,
    const float* __restrict__ sa, float* __restrict__ seV)
{
  const int c=blockIdx.x, n=blockIdx.y, tid=threadIdx.x;
  const int v = tid&31, g = tid>>5;
  __shared__ float sal[32];
  if (tid<32) sal[tid] = (tid<V_)? 1.f+sa[n*V_+tid] : 0.f;
  __syncthreads();
  const __hip_bfloat16* yp = y1 + ((size_t)n*C_+c)*T_*V_;
  float* svo = seV + ((size_t)n*C_+c)*T_;
  const float sv_ = sal[v];
  for (int j=0;j<16;++j){
    int t = g*16 + j;
    float val = (v<V_)? b2f(yp[t*V_+v])*sv_ : 0.f;
    #pragma unroll
    for (int off=16;off;off>>=1) val += __shfl_xor(val, off);
    if (v==0) svo[t]=val*(1.f/V_);
  }
}

// ---------------- K3d: ta[n,t] temporal gate + ca[n,c] channel gate ----------------
__global__ __launch_bounds__(128) void k_ta_ca(const float* __restrict__ seV,
    const float* __restrict__ W_ta, const float* __restrict__ b_ta,
    const float* __restrict__ W_fc1, const float* __restrict__ b_fc1,
    const float* __restrict__ W_fc2, const float* __restrict__ b_fc2,
    float* __restrict__ ta, float* __restrict__ ca)
{
  const int n=blockIdx.x, tid=threadIdx.x;
  __shared__ float tal[T_];
  __shared__ float scl[C_];
  __shared__ float h1[32];
  const float* sv = seV + (size_t)n*C_*T_;
  {
    float acc=b_ta[0];
    for (int c=0;c<C_;++c){
      #pragma unroll
      for (int k=0;k<9;++k){
        int tt=tid+k-4;
        if (tt>=0&&tt<T_) acc+=sv[c*T_+tt]*W_ta[c*9+k];
      }
    }
    float s=sigm(acc);
    tal[tid]=s; ta[n*T_+tid]=s;
  }
  __syncthreads();
  if (tid<C_){
    float acc=0.f;
    for (int t=0;t<T_;++t) acc += sv[tid*T_+t]*(1.f+tal[t]);
    scl[tid]=acc*(1.f/T_);
  }
  __syncthreads();
  if (tid<32){
    float acc=b_fc1[tid];
    for (int c=0;c<C_;++c) acc += scl[c]*W_fc1[tid*C_+c];
    h1[tid]=fmaxf(acc,0.f);
  }
  __syncthreads();
  if (tid<C_){
    float acc=b_fc2[tid];
    for (int j=0;j<32;++j) acc += h1[j]*W_fc2[tid*32+j];
    ca[n*C_+tid]=sigm(acc);
  }
}

// ---------------- K4: 4-t tile MFMA xa/gates + q/k/v projections ----------------
__global__ __launch_bounds__(256) void k_xa_qkv(
    const __hip_bfloat16* __restrict__ y1, const float* __restrict__ pos_emb,
    const float* __restrict__ sa, const float* __restrict__ ta, const float* __restrict__ ca,
    const float* __restrict__ Wq_h, const float* __restrict__ bq_h,
    const float* __restrict__ Wk_h, const float* __restrict__ bk_h,
    const float* __restrict__ Wv_h, const float* __restrict__ bv_h,
    __hip_bfloat16* __restrict__ xa, __hip_bfloat16* __restrict__ qb,
    __hip_bfloat16* __restrict__ kb, __hip_bfloat16* __restrict__ vb)
{
  const int tc=blockIdx.x, n=blockIdx.y, tid=threadIdx.x;
  const int wv=tid>>6, l=tid&63, lc=l&15, lk=l>>4;
  __shared__ __align__(16) short w3[192*72];      // [mu][c], mu = which*64+ho
  __shared__ __align__(16) short xalT[4][32*72];  // per t: [v][c], v>=25 zeroed
  __shared__ float bl[192];
  __shared__ float sal[32], cal[64], tgs[4];
  for (int i=tid;i<192*64;i+=256){
    int mu=i>>6, c=i&63, which=mu/C_, ho=mu%C_;
    const float* W = which==0?Wq_h:(which==1?Wk_h:Wv_h);
    w3[mu*72+c] = (short)f2bu(W[(size_t)ho*C_+c]);
  }
  if (tid<192){
    int which=tid/C_, ho=tid%C_;
    bl[tid] = (which==0?bq_h:(which==1?bk_h:bv_h))[ho];
  }
  if (tid<32) sal[tid] = (tid<V_)? 1.f+sa[n*V_+tid] : 0.f;
  if (tid>=32 && tid<96) cal[tid-32] = 1.f+ca[n*C_+tid-32];
  if (tid>=96 && tid<100) tgs[tid-96] = 1.f+ta[n*T_+tc*4+(tid-96)];
  for (int i=tid;i<4*7*72;i+=256){
    int tl=i/(7*72), r=i%(7*72);
    xalT[tl][25*72 + r] = 0;   // rows 25..31 contiguous
  }
  __syncthreads();
  const int tv0 = tc*100;
  const __hip_bfloat16* y1n = y1 + (size_t)n*C_*TV;
  __hip_bfloat16* xan = xa + (size_t)n*C_*TV;
  // vectorized: y1 uint2 read (4 bf16), xa packed 8B write
  for (int i=tid;i<64*25;i+=256){
    int c=i/25, a=i%25, tv4=a*4;
    const unsigned int* ys = (const unsigned int*)(y1n + (size_t)c*TV + tv0 + tv4);
    unsigned int u0=ys[0], u1=ys[1];
    float yv[4] = {ubl(u0),ubh(u0),ubl(u1),ubh(u1)};
    const float calc = cal[c];
    unsigned long long pack = 0ull;
    #pragma unroll
    for (int j=0;j<4;++j){
      int tv=tv4+j, tl=tv/25, v=tv-tl*25;
      float val = yv[j]*sal[v]*tgs[tl]*calc + pos_emb[(size_t)(tc*4+tl)*CV + c*V_ + v];
      unsigned short b = f2bu(val);
      pack |= (unsigned long long)b << (16*j);
      xalT[tl][v*72 + c] = (short)b;
    }
    *(unsigned long long*)(xan + (size_t)c*TV + tv0 + tv4) = pack;
  }
  __syncthreads();
  const int t = tc*4 + wv;    // wave wv owns this t
  short8v bf_[2][2];
  #pragma unroll
  for (int ks=0;ks<2;++ks){
    bf_[ks][0] = *(const short8v*)(&xalT[wv][lc*72      + ks*32 + lk*8]);
    bf_[ks][1] = *(const short8v*)(&xalT[wv][(16+lc)*72 + ks*32 + lk*8]);
  }
  #pragma unroll
  for (int mt=0;mt<12;++mt){
    f32x4 acc0 = {0.f,0.f,0.f,0.f}, acc1 = {0.f,0.f,0.f,0.f};
    #pragma unroll
    for (int ks=0;ks<2;++ks){
      short8v a = *(const short8v*)(w3 + (mt*16+lc)*72 + ks*32 + lk*8);
      acc0 = MFMA16(a, bf_[ks][0], acc0,0,0,0);
      acc1 = MFMA16(a, bf_[ks][1], acc1,0,0,0);
    }
    #pragma unroll
    for (int reg=0;reg<4;++reg){
      const int mu = mt*16 + lk*4 + reg;
      const int which = mt>>2;              // = mu/64, constant per unrolled mt
      const int ho = mu & 63, h = ho>>3, o = ho&7;
      __hip_bfloat16* dst = (which==0?qb:(which==1?kb:vb))
                            + (((size_t)n*H_+h)*T_+t)*D_ + o*V_;
      const float bb = bl[mu];
      dst[lc] = f2b(acc0[reg]+bb);
      if (lc < 9) dst[16+lc] = f2b(acc1[reg]+bb);
    }
  }
}

// ---------------- K5: MFMA flash causal MHA ----------------
__global__ __launch_bounds__(256) void k_attn(
    const __hip_bfloat16* __restrict__ qb, const __hip_bfloat16* __restrict__ kb,
    const __hip_bfloat16* __restrict__ vb, __hip_bfloat16* __restrict__ oh)
{
  const int bx = blockIdx.x;
  const int nh = blockIdx.z*H_ + blockIdx.y;
  const int tid = threadIdx.x;
  const int wv = tid>>6, l = tid&63;
  const int lc = l&15, lg = l>>4;
  __shared__ __align__(16) char KlB[32*512];      // [key][d(256sh)] bf16, byte^=(key&7)<<4
  __shared__ __align__(16) short VT[208*40];      // [d][key] bf16
  __shared__ __align__(16) short Pl[64*40];       // [qloc][key] bf16 (per-wave slices)
  const __hip_bfloat16* qg_ = qb + (size_t)nh*T_*D_;
  const __hip_bfloat16* kg_ = kb + (size_t)nh*T_*D_;
  const __hip_bfloat16* vg_ = vb + (size_t)nh*T_*D_;
  __hip_bfloat16* og_ = oh + (size_t)nh*T_*D_;
  const float scale = 0.0707106781f;  // 1/sqrt(200)

  for (int i=tid;i<32*12;i+=256){
    int key=i/12, j=i%12;
    *(unsigned int*)(KlB + ((key*512 + 400 + j*4) ^ ((key&7)<<4))) = 0u;
  }
  for (int i=tid;i<8*40;i+=256) VT[200*40 + i] = 0;

  const int qrow = bx*64 + wv*16 + lc;
  short8v qf[7];
  {
    const short8v* qs8 = (const short8v*)(qg_ + (size_t)qrow*D_);
    #pragma unroll
    for (int ks=0;ks<7;++ks) qf[ks] = qs8[ks*4 + lg];
  }
  f32x4 oacc[13];
  #pragma unroll
  for (int i=0;i<13;++i) oacc[i] = (f32x4){0.f,0.f,0.f,0.f};
  float m[4], lsm[4];
  #pragma unroll
  for (int r=0;r<4;++r){ m[r]=-1e30f; lsm[r]=0.f; }

  const int ntiles = (bx==0)? 2 : 4;
  for (int kt=0; kt<ntiles; ++kt){
    const int j0 = kt*32;
    __syncthreads();
    {
      const short8v* ks8 = (const short8v*)(kg_ + (size_t)j0*D_);
      for (int i=tid;i<32*25;i+=256){
        int row=i/25, w=i%25;
        *(short8v*)(KlB + ((row*512 + w*16) ^ ((row&7)<<4))) = ks8[i];
      }
      const short8v* vs8 = (const short8v*)(vg_ + (size_t)j0*D_);
      for (int i=tid;i<32*25;i+=256){
        int row=i&31, w4=i>>5;
        short8v u = vs8[row*25 + w4];
        #pragma unroll
        for (int j=0;j<8;++j) VT[(w4*8+j)*40 + row] = u[j];
      }
    }
    __syncthreads();
    const bool active = (j0 <= bx*64 + wv*16 + 15);
    if (active){
      f32x4 s0 = {0.f,0.f,0.f,0.f}, s1 = {0.f,0.f,0.f,0.f};
      #pragma unroll
      for (int ks=0;ks<7;++ks){
        short8v b0 = *(const short8v*)(KlB + ((lc*512      + ks*64 + lg*16) ^ ((lc&7)<<4)));
        short8v b1 = *(const short8v*)(KlB + (((16+lc)*512 + ks*64 + lg*16) ^ ((lc&7)<<4)));
        s0 = MFMA16(qf[ks], b0, s0,0,0,0);
        s1 = MFMA16(qf[ks], b1, s1,0,0,0);
      }
      float fr[4];
      #pragma unroll
      for (int r=0;r<4;++r){
        const int qg = bx*64 + wv*16 + lg*4 + r;
        float v0 = (j0+lc    <= qg) ? s0[r]*scale : -1e30f;
        float v1 = (j0+16+lc <= qg) ? s1[r]*scale : -1e30f;
        float mx = fmaxf(v0,v1);
        #pragma unroll
        for (int off=1;off<16;off<<=1) mx = fmaxf(mx, __shfl_xor(mx, off));
        float mn = fmaxf(m[r], mx);
        fr[r] = __expf(m[r]-mn);
        float p0 = __expf(v0-mn), p1 = __expf(v1-mn);
        float ts = p0+p1;
        #pragma unroll
        for (int off=1;off<16;off<<=1) ts += __shfl_xor(ts, off);
        lsm[r] = lsm[r]*fr[r] + ts;
        m[r] = mn;
        Pl[(wv*16 + lg*4 + r)*40 + lc]      = (short)f2bu(p0);
        Pl[(wv*16 + lg*4 + r)*40 + 16 + lc] = (short)f2bu(p1);
      }
      #pragma unroll
      for (int dt=0;dt<13;++dt){
        #pragma unroll
        for (int r=0;r<4;++r) oacc[dt][r] *= fr[r];
      }
      short8v pa = *(const short8v*)(Pl + (wv*16+lc)*40 + lg*8);
      #pragma unroll
      for (int dt=0;dt<13;++dt){
        short8v b = *(const short8v*)(VT + (dt*16+lc)*40 + lg*8);
        oacc[dt] = MFMA16(pa, b, oacc[dt],0,0,0);
      }
    }
  }
  float rl[4];
  #pragma unroll
  for (int r=0;r<4;++r) rl[r] = 1.f/lsm[r];
  #pragma unroll
  for (int dt=0;dt<13;++dt){
    const int d = dt*16 + lc;
    if (d < D_){
      #pragma unroll
      for (int r=0;r<4;++r){
        const int q = bx*64 + wv*16 + lg*4 + r;
        og_[(size_t)q*D_ + d] = f2b(oacc[dt][r]*rl[r]);
      }
    }
  }
}

// ---------------- K7: 8-t tile MFMA out kernel ----------------
__global__ __launch_bounds__(256) void k_out(
    const __hip_bfloat16* __restrict__ oh, const __hip_bfloat16* __restrict__ xa,
    const float* __restrict__ x, const float* __restrict__ W_ffn,
    const float* __restrict__ b_ffn, const float* __restrict__ m_gamma,
    const float* __restrict__ m_beta, float* __restrict__ out)
{
  const int tc = blockIdx.x, n = blockIdx.y, tid = threadIdx.x;
  const int wv = tid>>6, l = tid&63, lc = l&15, lg = l>>4;
  __shared__ __align__(16) short wfl[64*72];   // W_ffn bf16 [o][c]
  __shared__ __align__(16) short zT[208*72];   // z^T bf16 [tv][c], rows 200..207 zeroed
  __shared__ float bn_s[64], bn_b[64], bff[64];
  const float invs = rsqrtf(1.f+EPSB);
  for (int i=tid;i<64*64;i+=256){
    int o=i>>6, c=i&63;
    wfl[o*72+c] = (short)f2bu(W_ffn[i]);
  }
  if (tid<64){ bn_s[tid]=m_gamma[tid]*invs; bn_b[tid]=m_beta[tid]; bff[tid]=b_ffn[tid]; }
  for (int i=tid;i<8*72;i+=256) zT[200*72+i]=0;
  __syncthreads();
  const int tv0 = tc*200;
  const __hip_bfloat16* xan = xa + (size_t)n*C_*TV;
  // ---- assemble z^T: xa read vectorized uint2 (4 bf16), oh scalar ----
  for (int i=tid;i<64*50;i+=256){
    int c=i/50, a=i%50, tv4=a*4;
    const unsigned int* xs = (const unsigned int*)(xan + (size_t)c*TV + tv0 + tv4);
    unsigned int u0 = xs[0], u1 = xs[1];
    float xv[4] = {ubl(u0),ubh(u0),ubl(u1),ubh(u1)};
    int h=c>>3, oi=c&7;
    const __hip_bfloat16* ohn = oh + (((size_t)n*H_+h)*T_ + tc*8)*D_ + oi*V_;
    const float s_=bn_s[c], b_=bn_b[c];
    #pragma unroll
    for (int j=0;j<4;++j){
      int tv=tv4+j, t=tv/25, v=tv-t*25;
      float ohv = b2f(ohn[(size_t)t*D_ + v]);
      zT[tv*72 + c] = (short)f2bu(s_*ohv + b_ + xv[j]);
    }
  }
  __syncthreads();
  const int lk = lg;
  short8v af0 = *(const short8v*)(wfl + (wv*16+lc)*72 + lk*8);
  short8v af1 = *(const short8v*)(wfl + (wv*16+lc)*72 + 32 + lk*8);
  f32x4 acc[13];
  #pragma unroll
  for (int dt=0;dt<13;++dt) acc[dt] = (f32x4){0.f,0.f,0.f,0.f};
  #pragma unroll
  for (int dt=0;dt<13;++dt){
    short8v b0 = *(const short8v*)(zT + (dt*16+lc)*72 + lk*8);
    short8v b1 = *(const short8v*)(zT + (dt*16+lc)*72 + 32 + lk*8);
    acc[dt] = MFMA16(af0, b0, acc[dt],0,0,0);
    acc[dt] = MFMA16(af1, b1, acc[dt],0,0,0);
  }
  const float* xn = x + (size_t)n*C_*TV;
  float* outn = out + (size_t)n*C_*TV;
  #pragma unroll
  for (int dt=0;dt<13;++dt){
    const int tv = dt*16 + lc;
    if (tv < 200){
      #pragma unroll
      for (int reg=0;reg<4;++reg){
        const int o = wv*16 + lg*4 + reg;
        float z2 = fmaxf(acc[dt][reg] + bff[o], 0.f) + b2f(xan[(size_t)o*TV + tv0 + tv]);
        float z3 = bn_s[o]*z2 + bn_b[o];
        outn[(size_t)o*TV + tv0 + tv] = fmaxf(z3 + xn[(size_t)o*TV + tv0 + tv], 0.f);
      }
    }
  }
}

extern "C" void kernel_launch(void* const* d_in, const int* in_sizes, int n_in,
                              void* d_out, int out_size, void* d_ws, size_t ws_size,
                              hipStream_t stream) {
  const float* x      = (const float*)d_in[0];
  const float* A      = (const float*)d_in[1];
  const float* alphap = (const float*)d_in[2];
  const float* Wq     = (const float*)d_in[3];
  const float* bq     = (const float*)d_in[4];
  const float* Wk     = (const float*)d_in[5];
  const float* bk     = (const float*)d_in[6];
  const float* Wf     = (const float*)d_in[7];
  const float* bfp    = (const float*)d_in[8];
  const float* g_gamma= (const float*)d_in[9];
  const float* g_beta = (const float*)d_in[10];
  const float* W_sa   = (const float*)d_in[11];
  const float* b_sa   = (const float*)d_in[12];
  const float* W_ta   = (const float*)d_in[13];
  const float* b_ta   = (const float*)d_in[14];
  const float* W_fc1  = (const float*)d_in[15];
  const float* b_fc1  = (const float*)d_in[16];
  const float* W_fc2  = (const float*)d_in[17];
  const float* b_fc2  = (const float*)d_in[18];
  const float* pos_emb= (const float*)d_in[19];
  const float* Wq_h   = (const float*)d_in[20];
  const float* bq_h   = (const float*)d_in[21];
  const float* Wk_h   = (const float*)d_in[22];
  const float* bk_h   = (const float*)d_in[23];
  const float* Wv_h   = (const float*)d_in[24];
  const float* bv_h   = (const float*)d_in[25];
  const float* W_ffn  = (const float*)d_in[26];
  const float* b_ffn  = (const float*)d_in[27];
  const float* m_gamma= (const float*)d_in[28];
  const float* m_beta = (const float*)d_in[29];
  float* out = (float*)d_out;

  float* ws   = (float*)d_ws;
  float* Aad  = ws;                    // 128*3*625   = 240000
  float* seT  = Aad + 240000;          // 128*64*25   = 204800
  float* seV  = seT + 204800;          // 128*64*128  = 1048576
  float* sa   = seV + 1048576;         // 128*25      = 3200
  float* ta   = sa  + 3200;            // 128*128     = 16384
  float* ca   = ta  + 16384;           // 128*64      = 8192
  __hip_bfloat16* y1 = (__hip_bfloat16*)(ca + 8192);  // 26214400 elems (reused as oh)
  __hip_bfloat16* xa = y1 + (size_t)26214400;
  __hip_bfloat16* qb = xa + (size_t)26214400;
  __hip_bfloat16* kb = qb + (size_t)26214400;
  __hip_bfloat16* vb = kb + (size_t)26214400;
  __hip_bfloat16* oh = y1;  // reuse: y1 dead after k_xa_qkv
  float* attg = (float*)y1; // scratch before y1 is written (16*384*625*4 = 15.4MB)

  k_gcn_att1<<<dim3(NCHUNK, N_*S_), 256, 0, stream>>>(x, Wq, bq, Wk, bk, attg);
  k_gcn_att2<<<N_*S_, 256, 0, stream>>>(attg, A, alphap, Aad);
  k_gcn_y<<<dim3(T_/4, N_), 256, 0, stream>>>(x, Aad, Wf, bfp, g_gamma, g_beta, y1);
  k_seT<<<dim3(C_, N_), 256, 0, stream>>>(y1, seT);
  k_sa<<<N_, 64, 0, stream>>>(seT, W_sa, b_sa, sa);
  k_seV<<<dim3(C_, N_), 256, 0, stream>>>(y1, sa, seV);
  k_ta_ca<<<N_, 128, 0, stream>>>(seV, W_ta, b_ta, W_fc1, b_fc1, W_fc2, b_fc2, ta, ca);
  k_xa_qkv<<<dim3(T_/4, N_), 256, 0, stream>>>(y1, pos_emb, sa, ta, ca,
      Wq_h, bq_h, Wk_h, bk_h, Wv_h, bv_h, xa, qb, kb, vb);
  k_attn<<<dim3(2, H_, N_), 256, 0, stream>>>(qb, kb, vb, oh);
  k_out<<<dim3(T_/8, N_), 256, 0, stream>>>(oh, xa, x, W_ffn, b_ffn, m_gamma, m_beta, out);
}